// Round 5
// baseline (299.241 us; speedup 1.0000x reference)
//
#include <hip/hip_runtime.h>
#include <hip/hip_bf16.h>

// ---------------------------------------------------------------------------
// MambaConvBlock fused pipeline. Round 5: conv occupancy fix (M=32 blocks).
// Sizes: B=8, CIN=64, COUT=128, H=W=64, L=4096, T=32768,
//        DINNER=256, DSTATE=16, DTRANK=8, DCONV=4.
// ---------------------------------------------------------------------------

typedef __attribute__((ext_vector_type(8))) short bf16x8;
typedef __attribute__((ext_vector_type(4))) float f32x4;

#define DEV __device__ __forceinline__

DEV float siluf(float v) {
  return v * __builtin_amdgcn_rcpf(1.f + __expf(-v));
}

DEV unsigned short f2bf(float f) {
  __hip_bfloat16 h = __float2bfloat16(f);
  return *reinterpret_cast<unsigned short*>(&h);
}

constexpr int NC = 128;  // chunks per batch
constexpr int CL = 32;   // chunk length (NC*CL = 4096)

// ---------------- pre-pass: NCHW fp32 -> NHWC bf16 --------------------------
__global__ __launch_bounds__(256) void nchw2nhwc_bf16(
    const float* __restrict__ X, unsigned short* __restrict__ Xb)
{
  __shared__ float t[64][65];
  const int by = blockIdx.x;            // b*64 + y
  const int b = by >> 6, y = by & 63;
  const int tid = threadIdx.x;
  for (int i = tid; i < 4096; i += 256) {
    int c = i >> 6, xx = i & 63;
    t[c][xx] = X[(((size_t)b * 64 + c) * 64 + y) * 64 + xx];
  }
  __syncthreads();
  for (int i = tid; i < 4096; i += 256) {
    int xx = i >> 6, c = i & 63;
    Xb[(((size_t)b * 64 + y) * 64 + xx) * 64 + c] = f2bf(t[c][xx]);
  }
}

// ---------------- pre-pass: conv weights -> bf16 [co][tap][ci] --------------
template<int CI>
__global__ void convw_prep(const float* __restrict__ W,
                           unsigned short* __restrict__ Wb)
{
  int idx = blockIdx.x * 256 + threadIdx.x;
  if (idx >= 128 * 9 * CI) return;
  int co = idx / (9 * CI), r = idx % (9 * CI);
  int t = r / CI, ci = r % CI;
  Wb[idx] = f2bf(W[((size_t)co * CI + ci) * 9 + t]);
}

__global__ void f32_to_bf16(const float* __restrict__ A,
                            unsigned short* __restrict__ B, int n)
{
  int i = blockIdx.x * 256 + threadIdx.x;
  if (i < n) B[i] = f2bf(A[i]);
}

// ---------------- conv3x3 + BN + ReLU as implicit-GEMM MFMA -----------------
// Block: 4 waves; M=32 (half image row), N=128 (wave n0 = wid*32).
// Grid (64 rows, 2 halves, 8 batch) = 1024 blocks -> 4096 waves (4/SIMD).
template<int CI>
__global__ __launch_bounds__(256) void conv_mfma(
    const unsigned short* __restrict__ Xb,   // [b][64][64][CI] bf16
    const unsigned short* __restrict__ Wb,   // [128][9][CI]    bf16
    const float* __restrict__ bc,
    const float* __restrict__ bg, const float* __restrict__ bb,
    const float* __restrict__ bm, const float* __restrict__ bv,
    unsigned short* __restrict__ Y)          // [b][y][x][128]  bf16
{
  const int lane = threadIdx.x & 63;
  const int wid  = threadIdx.x >> 6;
  const int n0 = wid * 32;
  const int y = blockIdx.x;
  const int x0 = blockIdx.y * 32;
  const int b = blockIdx.z;
  const int lr = lane & 15, lk = (lane >> 4) * 8;

  f32x4 acc[2][2];
  #pragma unroll
  for (int i = 0; i < 2; ++i)
    #pragma unroll
    for (int j = 0; j < 2; ++j) acc[i][j] = f32x4{0.f, 0.f, 0.f, 0.f};

  #pragma unroll
  for (int dy = -1; dy <= 1; ++dy) {
    int yy = y + dy;
    if (yy < 0 || yy >= 64) continue;
    const unsigned short* arow = Xb + ((size_t)(b * 64 + yy) * 64) * CI;
    #pragma unroll
    for (int dx = -1; dx <= 1; ++dx) {
      const int tap = (dy + 1) * 3 + (dx + 1);
      #pragma unroll
      for (int kk = 0; kk < CI / 32; ++kk) {
        const int ci0 = kk * 32 + lk;
        bf16x8 bfr[2];
        #pragma unroll
        for (int nf = 0; nf < 2; ++nf)
          bfr[nf] = *reinterpret_cast<const bf16x8*>(
              Wb + (size_t)(n0 + nf * 16 + lr) * (9 * CI) + tap * CI + ci0);
        #pragma unroll
        for (int mf = 0; mf < 2; ++mf) {
          int px = x0 + mf * 16 + lr + dx;
          bf16x8 afr = {0, 0, 0, 0, 0, 0, 0, 0};
          if ((unsigned)px < 64u)
            afr = *reinterpret_cast<const bf16x8*>(arow + (size_t)px * CI + ci0);
          #pragma unroll
          for (int nf = 0; nf < 2; ++nf)
            acc[mf][nf] = __builtin_amdgcn_mfma_f32_16x16x32_bf16(
                afr, bfr[nf], acc[mf][nf], 0, 0, 0);
        }
      }
    }
  }

  #pragma unroll
  for (int nf = 0; nf < 2; ++nf) {
    int n = n0 + nf * 16 + lr;
    float aS = bg[n] * rsqrtf(bv[n] + 1e-5f);
    float aB = (bc[n] - bm[n]) * aS + bb[n];
    #pragma unroll
    for (int mf = 0; mf < 2; ++mf)
      #pragma unroll
      for (int i = 0; i < 4; ++i) {
        int m = x0 + mf * 16 + (lane >> 4) * 4 + i;
        float v = fmaxf(acc[mf][nf][i] * aS + aB, 0.f);
        Y[((size_t)(b * 4096 + y * 64 + m)) * 128 + n] = f2bf(v);
      }
  }
}

// ---------------- bf16 MFMA GEMM: C[M,N] = A[M,K] @ W[N,K]^T ----------------
template<int KDIM, int EPI>
__global__ __launch_bounds__(256) void gemm_mfma(
    const unsigned short* __restrict__ A,   // [M][KDIM] bf16
    const unsigned short* __restrict__ Wn,  // [N][KDIM] bf16
    float* __restrict__ C0, float* __restrict__ C1)
{
  const int lane = threadIdx.x & 63;
  const int wid  = threadIdx.x >> 6;
  const int m0 = blockIdx.x * 64;
  const int n0 = blockIdx.y * 128 + wid * 32;
  const int lr = lane & 15, lk = (lane >> 4) * 8;

  f32x4 acc[4][2];
  #pragma unroll
  for (int i = 0; i < 4; ++i)
    #pragma unroll
    for (int j = 0; j < 2; ++j) acc[i][j] = f32x4{0.f, 0.f, 0.f, 0.f};

  const unsigned short* Ab = A + (size_t)m0 * KDIM;
  #pragma unroll 4
  for (int k0 = 0; k0 < KDIM; k0 += 32) {
    const int kc = k0 + lk;
    bf16x8 bfr[2];
    #pragma unroll
    for (int nf = 0; nf < 2; ++nf)
      bfr[nf] = *reinterpret_cast<const bf16x8*>(
          Wn + (size_t)(n0 + nf * 16 + lr) * KDIM + kc);
    #pragma unroll
    for (int mf = 0; mf < 4; ++mf) {
      bf16x8 afr = *reinterpret_cast<const bf16x8*>(
          Ab + (size_t)(mf * 16 + lr) * KDIM + kc);
      #pragma unroll
      for (int nf = 0; nf < 2; ++nf)
        acc[mf][nf] = __builtin_amdgcn_mfma_f32_16x16x32_bf16(
            afr, bfr[nf], acc[mf][nf], 0, 0, 0);
    }
  }

  #pragma unroll
  for (int nf = 0; nf < 2; ++nf) {
    int n = n0 + nf * 16 + lr;
    #pragma unroll
    for (int mf = 0; mf < 4; ++mf)
      #pragma unroll
      for (int i = 0; i < 4; ++i) {
        int m = m0 + mf * 16 + (lane >> 4) * 4 + i;
        float v = acc[mf][nf][i];
        if (EPI == 0) {
          if (n < 256) C0[(size_t)m * 256 + n] = v;
          else         C1[(size_t)m * 256 + (n - 256)] = v;
        } else {
          C0[(size_t)m * 128 + n] = v;
        }
      }
  }
}

// ---------------- fp32 GEMM (x_proj, N=40) ----------------------------------
__global__ __launch_bounds__(256) void gemm_nt(
    const float* __restrict__ A, const float* __restrict__ W,
    float* __restrict__ C, int M, int N, int K)
{
  __shared__ float As[16][68];
  __shared__ float Bs[16][68];
  const int m0 = blockIdx.x * 64, n0 = blockIdx.y * 64;
  const int tid = threadIdx.x;
  const int tx = tid & 15, ty = tid >> 4;
  const int lr = tid >> 2;
  const int lk = (tid & 3) * 4;
  float acc[4][4] = {};

  for (int k0 = 0; k0 < K; k0 += 16) {
    float4 av = *reinterpret_cast<const float4*>(&A[(size_t)(m0 + lr) * K + k0 + lk]);
    float4 wv = make_float4(0.f, 0.f, 0.f, 0.f);
    if (n0 + lr < N)
      wv = *reinterpret_cast<const float4*>(&W[(size_t)(n0 + lr) * K + k0 + lk]);
    As[lk + 0][lr] = av.x; As[lk + 1][lr] = av.y;
    As[lk + 2][lr] = av.z; As[lk + 3][lr] = av.w;
    Bs[lk + 0][lr] = wv.x; Bs[lk + 1][lr] = wv.y;
    Bs[lk + 2][lr] = wv.z; Bs[lk + 3][lr] = wv.w;
    __syncthreads();
    #pragma unroll
    for (int k = 0; k < 16; ++k) {
      float4 a4 = *reinterpret_cast<const float4*>(&As[k][ty * 4]);
      float4 b4 = *reinterpret_cast<const float4*>(&Bs[k][tx * 4]);
      float avv[4] = {a4.x, a4.y, a4.z, a4.w};
      float bvv[4] = {b4.x, b4.y, b4.z, b4.w};
      #pragma unroll
      for (int i = 0; i < 4; ++i)
        #pragma unroll
        for (int j = 0; j < 4; ++j)
          acc[i][j] = fmaf(avv[i], bvv[j], acc[i][j]);
    }
    __syncthreads();
  }
  #pragma unroll
  for (int i = 0; i < 4; ++i) {
    int m = m0 + ty * 4 + i;
    #pragma unroll
    for (int j = 0; j < 4; ++j) {
      int n = n0 + tx * 4 + j;
      if (n < N) C[(size_t)m * N + n] = acc[i][j];
    }
  }
}

// ---------------- depthwise causal conv1d (DCONV=4) + silu, float4 ----------
__global__ __launch_bounds__(256) void conv1d_silu(
    const float* __restrict__ xm,   // (T,256)
    const float* __restrict__ w,    // (256,4)
    const float* __restrict__ bias, // (256)
    float* __restrict__ out)        // (T,256)
{
  __shared__ float ws4[4][256];
  __shared__ float bsh[256];
  for (int i = threadIdx.x; i < 1024; i += 256)
    ws4[i >> 8][i & 255] = w[(i & 255) * 4 + (i >> 8)];
  bsh[threadIdx.x] = bias[threadIdx.x];
  __syncthreads();
  const int total = 8 * 4096 * 64;
  for (int idx = blockIdx.x * 256 + threadIdx.x; idx < total;
       idx += gridDim.x * 256) {
    int d4 = idx & 63, t = idx >> 6, l = t & 4095;
    int d = d4 * 4;
    float4 acc = *reinterpret_cast<const float4*>(&bsh[d]);
    #pragma unroll
    for (int j = 0; j < 4; ++j) {
      if (l - 3 + j >= 0) {
        float4 xv = *reinterpret_cast<const float4*>(&xm[(size_t)(t - 3 + j) * 256 + d]);
        float4 wv = *reinterpret_cast<const float4*>(&ws4[j][d]);
        acc.x = fmaf(xv.x, wv.x, acc.x);
        acc.y = fmaf(xv.y, wv.y, acc.y);
        acc.z = fmaf(xv.z, wv.z, acc.z);
        acc.w = fmaf(xv.w, wv.w, acc.w);
      }
    }
    acc.x = siluf(acc.x); acc.y = siluf(acc.y);
    acc.z = siluf(acc.z); acc.w = siluf(acc.w);
    *reinterpret_cast<float4*>(&out[(size_t)t * 256 + d]) = acc;
  }
}

// ---------------- chunked selective scan ------------------------------------
__global__ __launch_bounds__(256) void scan_pass1(
    const float* __restrict__ xssm, const float* __restrict__ xdb,
    const float* __restrict__ dtw, const float* __restrict__ dtb,
    const float* __restrict__ A_log,
    float* __restrict__ Q, float* __restrict__ S)
{
  __shared__ __align__(16) float sh[CL][40];
  const int c = blockIdx.x, b = blockIdx.y;
  const int d = threadIdx.x;
  {
    const float4* src = reinterpret_cast<const float4*>(
        &xdb[((size_t)b * 4096 + c * CL) * 40]);
    float4* dst = reinterpret_cast<float4*>(&sh[0][0]);
    for (int i = threadIdx.x; i < CL * 10; i += 256) dst[i] = src[i];
  }
  float4 w0 = *reinterpret_cast<const float4*>(&dtw[d * 8]);
  float4 w1 = *reinterpret_cast<const float4*>(&dtw[d * 8 + 4]);
  const float bdt = dtb[d];
  float Aneg[16], h[16];
  #pragma unroll
  for (int s = 0; s < 16; ++s) {
    Aneg[s] = -__expf(A_log[d * 16 + s]);
    h[s] = 0.f;
  }
  __syncthreads();

  float sdt = 0.f;
  const size_t xbase = ((size_t)b * 4096 + (size_t)c * CL) * 256 + d;
  for (int l = 0; l < CL; ++l) {
    const float4* row = reinterpret_cast<const float4*>(sh[l]);
    float4 r0 = row[0], r1 = row[1];
    float acc = bdt;
    acc = fmaf(r0.x, w0.x, acc); acc = fmaf(r0.y, w0.y, acc);
    acc = fmaf(r0.z, w0.z, acc); acc = fmaf(r0.w, w0.w, acc);
    acc = fmaf(r1.x, w1.x, acc); acc = fmaf(r1.y, w1.y, acc);
    acc = fmaf(r1.z, w1.z, acc); acc = fmaf(r1.w, w1.w, acc);
    float dt = (acc > 20.f) ? acc : __logf(1.f + __expf(acc));
    sdt += dt;
    float xv = xssm[xbase + (size_t)l * 256];
    float dtx = dt * xv;
    #pragma unroll
    for (int q = 0; q < 4; ++q) {
      float4 Bq = row[2 + q];
      float bb4[4] = {Bq.x, Bq.y, Bq.z, Bq.w};
      #pragma unroll
      for (int j = 0; j < 4; ++j) {
        int s = q * 4 + j;
        float dA = __expf(dt * Aneg[s]);
        h[s] = fmaf(dA, h[s], dtx * bb4[j]);
      }
    }
  }
  float4* q4 = reinterpret_cast<float4*>(
      &Q[(((size_t)b * NC + c) * 256 + d) * 16]);
  #pragma unroll
  for (int q = 0; q < 4; ++q)
    q4[q] = make_float4(h[q * 4], h[q * 4 + 1], h[q * 4 + 2], h[q * 4 + 3]);
  S[((size_t)b * NC + c) * 256 + d] = sdt;
}

__global__ __launch_bounds__(256) void scan_combine(
    float* __restrict__ Q, const float* __restrict__ S,
    const float* __restrict__ A_log)
{
  int g = blockIdx.x * 256 + threadIdx.x;   // 32768 total
  int b = g >> 12, d = (g >> 4) & 255, s = g & 15;
  float Aneg = -__expf(A_log[d * 16 + s]);
  float h = 0.f;
  for (int c = 0; c < NC; ++c) {
    size_t qi = (((size_t)b * NC + c) * 256 + d) * 16 + s;
    float q  = Q[qi];
    float sd = S[((size_t)b * NC + c) * 256 + d];
    Q[qi] = h;
    h = fmaf(__expf(Aneg * sd), h, q);
  }
}

__global__ __launch_bounds__(256) void scan_pass2(
    const float* __restrict__ xssm, const float* __restrict__ xdb,
    const float* __restrict__ zb,
    const float* __restrict__ dtw, const float* __restrict__ dtb,
    const float* __restrict__ A_log, const float* __restrict__ Dp,
    const float* __restrict__ Hstart, unsigned short* __restrict__ ybf)
{
  __shared__ __align__(16) float sh[CL][40];
  const int c = blockIdx.x, b = blockIdx.y;
  const int d = threadIdx.x;
  {
    const float4* src = reinterpret_cast<const float4*>(
        &xdb[((size_t)b * 4096 + c * CL) * 40]);
    float4* dst = reinterpret_cast<float4*>(&sh[0][0]);
    for (int i = threadIdx.x; i < CL * 10; i += 256) dst[i] = src[i];
  }
  float4 w0 = *reinterpret_cast<const float4*>(&dtw[d * 8]);
  float4 w1 = *reinterpret_cast<const float4*>(&dtw[d * 8 + 4]);
  const float bdt = dtb[d];
  const float Dd = Dp[d];
  float Aneg[16], h[16];
  const float4* hs4 = reinterpret_cast<const float4*>(
      &Hstart[(((size_t)b * NC + c) * 256 + d) * 16]);
  #pragma unroll
  for (int q = 0; q < 4; ++q) {
    float4 hv = hs4[q];
    h[q * 4 + 0] = hv.x; h[q * 4 + 1] = hv.y;
    h[q * 4 + 2] = hv.z; h[q * 4 + 3] = hv.w;
  }
  #pragma unroll
  for (int s = 0; s < 16; ++s) Aneg[s] = -__expf(A_log[d * 16 + s]);
  __syncthreads();

  const size_t xbase = ((size_t)b * 4096 + (size_t)c * CL) * 256 + d;
  for (int l = 0; l < CL; ++l) {
    const float4* row = reinterpret_cast<const float4*>(sh[l]);
    float4 r0 = row[0], r1 = row[1];
    float acc = bdt;
    acc = fmaf(r0.x, w0.x, acc); acc = fmaf(r0.y, w0.y, acc);
    acc = fmaf(r0.z, w0.z, acc); acc = fmaf(r0.w, w0.w, acc);
    acc = fmaf(r1.x, w1.x, acc); acc = fmaf(r1.y, w1.y, acc);
    acc = fmaf(r1.z, w1.z, acc); acc = fmaf(r1.w, w1.w, acc);
    float dt = (acc > 20.f) ? acc : __logf(1.f + __expf(acc));
    float xv = xssm[xbase + (size_t)l * 256];
    float zv = zb[xbase + (size_t)l * 256];
    float dtx = dt * xv;
    float y = 0.f;
    #pragma unroll
    for (int q = 0; q < 4; ++q) {
      float4 Bq = row[2 + q], Cq = row[6 + q];
      float bb4[4] = {Bq.x, Bq.y, Bq.z, Bq.w};
      float cc4[4] = {Cq.x, Cq.y, Cq.z, Cq.w};
      #pragma unroll
      for (int j = 0; j < 4; ++j) {
        int s = q * 4 + j;
        float dA = __expf(dt * Aneg[s]);
        h[s] = fmaf(dA, h[s], dtx * bb4[j]);
        y = fmaf(h[s], cc4[j], y);
      }
    }
    y = (y + Dd * xv) * siluf(zv);
    ybf[xbase + (size_t)l * 256] = f2bf(y);
  }
}

// ---------------- LayerNorm(128) + transpose to NCHW ------------------------
__global__ __launch_bounds__(256) void ln_transpose(
    const float* __restrict__ X,
    const float* __restrict__ g, const float* __restrict__ b,
    float* __restrict__ out)
{
  __shared__ float buf[64][129];
  const int t0 = blockIdx.x * 64;
  const int bb = t0 >> 12, l0 = t0 & 4095;
  const int tid = threadIdx.x;
  for (int idx = tid; idx < 64 * 128; idx += 256)
    buf[idx >> 7][idx & 127] = X[(size_t)t0 * 128 + idx];
  __syncthreads();
  const int tt = tid >> 2, q = tid & 3;
  float s = 0.f, sq = 0.f;
  #pragma unroll
  for (int i = 0; i < 32; ++i) {
    float v = buf[tt][q * 32 + i];
    s += v; sq += v * v;
  }
  s  += __shfl_xor(s, 1);  s  += __shfl_xor(s, 2);
  sq += __shfl_xor(sq, 1); sq += __shfl_xor(sq, 2);
  float mu = s * (1.f / 128.f);
  float var = sq * (1.f / 128.f) - mu * mu;
  float rstd = rsqrtf(fmaxf(var, 0.f) + 1e-5f);
  #pragma unroll
  for (int i = 0; i < 32; ++i) {
    int c = q * 32 + i;
    buf[tt][c] = (buf[tt][c] - mu) * rstd * g[c] + b[c];
  }
  __syncthreads();
  for (int idx = tid; idx < 64 * 128; idx += 256) {
    int c = idx >> 6, t2 = idx & 63;
    out[((size_t)bb * 128 + c) * 4096 + l0 + t2] = buf[t2][c];
  }
}

// ---------------------------------------------------------------------------
extern "C" void kernel_launch(void* const* d_in, const int* in_sizes, int n_in,
                              void* d_out, int out_size, void* d_ws, size_t ws_size,
                              hipStream_t stream) {
  const float* x        = (const float*)d_in[0];
  const float* conv1_w  = (const float*)d_in[1];
  const float* conv1_b  = (const float*)d_in[2];
  const float* bn1_g    = (const float*)d_in[3];
  const float* bn1_b    = (const float*)d_in[4];
  const float* bn1_m    = (const float*)d_in[5];
  const float* bn1_v    = (const float*)d_in[6];
  const float* conv2_w  = (const float*)d_in[7];
  const float* conv2_b  = (const float*)d_in[8];
  const float* bn2_g    = (const float*)d_in[9];
  const float* bn2_b    = (const float*)d_in[10];
  const float* bn2_m    = (const float*)d_in[11];
  const float* bn2_v    = (const float*)d_in[12];
  const float* in_proj_w  = (const float*)d_in[13];  // (512,128)
  const float* conv1d_w   = (const float*)d_in[14];  // (256,1,4)
  const float* conv1d_b   = (const float*)d_in[15];
  const float* x_proj_w   = (const float*)d_in[16];  // (40,256)
  const float* dt_proj_w  = (const float*)d_in[17];  // (256,8)
  const float* dt_proj_b  = (const float*)d_in[18];
  const float* A_log      = (const float*)d_in[19];  // (256,16)
  const float* Dp         = (const float*)d_in[20];  // (256)
  const float* out_proj_w = (const float*)d_in[21];  // (128,256)
  const float* ln_g       = (const float*)d_in[22];
  const float* ln_b       = (const float*)d_in[23];
  float* out = (float*)d_out;

  float* ws_f = (float*)d_ws;
  // workspace (float units), lifetime-reuse; peak ~31.1M f = 124.4 MB
  unsigned short* xb   = (unsigned short*)ws_f;
  float*          xm   = ws_f;
  unsigned short* ybf  = (unsigned short*)ws_f;
  float*          outs = ws_f + 4194304;
  float*          zb   = ws_f + 8388608;
  float*          xssm = ws_f + 16777216;
  unsigned short* seqb = (unsigned short*)(ws_f + 25165824);
  unsigned short* h1   = (unsigned short*)(ws_f + 27262976);
  float*          Qbuf = ws_f + 25165824;   // 4,194,304 f = B*NC*256*16
  float*          xdb  = ws_f + 29360128;   // 1,310,720 f
  float*          Sbuf = ws_f + 30670848;   //   262,144 f
  unsigned short* wb1  = (unsigned short*)(ws_f + 30932992);
  unsigned short* wb2  = (unsigned short*)(ws_f + 30969856);
  unsigned short* win  = (unsigned short*)(ws_f + 31043584);
  unsigned short* wout = (unsigned short*)(ws_f + 31076352);

  // pre-passes
  nchw2nhwc_bf16<<<512, 256, 0, stream>>>(x, xb);
  convw_prep<64><<<(73728 + 255) / 256, 256, 0, stream>>>(conv1_w, wb1);
  convw_prep<128><<<(147456 + 255) / 256, 256, 0, stream>>>(conv2_w, wb2);
  f32_to_bf16<<<256, 256, 0, stream>>>(in_proj_w, win, 65536);
  f32_to_bf16<<<128, 256, 0, stream>>>(out_proj_w, wout, 32768);

  // convs (MFMA, BN+ReLU fused, bf16 NHWC out), M=32 blocks for occupancy
  conv_mfma<64><<<dim3(64, 2, 8), 256, 0, stream>>>(
      xb, wb1, conv1_b, bn1_g, bn1_b, bn1_m, bn1_v, h1);
  conv_mfma<128><<<dim3(64, 2, 8), 256, 0, stream>>>(
      h1, wb2, conv2_b, bn2_g, bn2_b, bn2_m, bn2_v, seqb);

  // in_proj (one GEMM, N=512 -> xm | z)
  gemm_mfma<128, 0><<<dim3(512, 4), 256, 0, stream>>>(seqb, win, xm, zb);

  conv1d_silu<<<2048, 256, 0, stream>>>(xm, conv1d_w, conv1d_b, xssm);
  gemm_nt<<<dim3(512, 1), 256, 0, stream>>>(xssm, x_proj_w, xdb, 32768, 40, 256);

  scan_pass1<<<dim3(NC, 8), 256, 0, stream>>>(
      xssm, xdb, dt_proj_w, dt_proj_b, A_log, Qbuf, Sbuf);
  scan_combine<<<128, 256, 0, stream>>>(Qbuf, Sbuf, A_log);
  scan_pass2<<<dim3(NC, 8), 256, 0, stream>>>(
      xssm, xdb, zb, dt_proj_w, dt_proj_b, A_log, Dp, Qbuf, ybf);

  // out_proj (MFMA) + LN/transpose
  gemm_mfma<256, 1><<<dim3(512, 1), 256, 0, stream>>>(ybf, wout, outs, nullptr);
  ln_transpose<<<512, 256, 0, stream>>>(outs, ln_g, ln_b, out);
}

// Round 6
// 282.070 us; speedup vs baseline: 1.0609x; 1.0609x over previous
//
#include <hip/hip_runtime.h>
#include <hip/hip_bf16.h>

// ---------------------------------------------------------------------------
// MambaConvBlock fused pipeline. Round 6: branchless padded-NHWC conv
// (K-contiguous implicit GEMM, M=64/wave, deep unroll).
// Sizes: B=8, CIN=64, COUT=128, H=W=64, L=4096, T=32768,
//        DINNER=256, DSTATE=16, DTRANK=8, DCONV=4.
// ---------------------------------------------------------------------------

typedef __attribute__((ext_vector_type(8))) short bf16x8;
typedef __attribute__((ext_vector_type(4))) float f32x4;

#define DEV __device__ __forceinline__

DEV float siluf(float v) {
  return v * __builtin_amdgcn_rcpf(1.f + __expf(-v));
}

DEV unsigned short f2bf(float f) {
  __hip_bfloat16 h = __float2bfloat16(f);
  return *reinterpret_cast<unsigned short*>(&h);
}

constexpr int NC = 128;  // chunks per batch
constexpr int CL = 32;   // chunk length (NC*CL = 4096)

// ---------------- pre-pass: NCHW fp32 -> padded NHWC bf16 -------------------
// Writes interior of [b][66][66][64]; border pre-zeroed by hipMemsetAsync.
__global__ __launch_bounds__(256) void nchw2nhwc_bf16(
    const float* __restrict__ X, unsigned short* __restrict__ Xb)
{
  __shared__ float t[64][65];
  const int by = blockIdx.x;            // b*64 + y
  const int b = by >> 6, y = by & 63;
  const int tid = threadIdx.x;
  for (int i = tid; i < 4096; i += 256) {
    int c = i >> 6, xx = i & 63;
    t[c][xx] = X[(((size_t)b * 64 + c) * 64 + y) * 64 + xx];
  }
  __syncthreads();
  for (int i = tid; i < 4096; i += 256) {
    int xx = i >> 6, c = i & 63;
    Xb[(((size_t)(b * 66 + y + 1) * 66) + xx + 1) * 64 + c] = f2bf(t[c][xx]);
  }
}

// ---------------- pre-pass: conv weights -> bf16 [co][dy][dx][ci] -----------
template<int CI>
__global__ void convw_prep(const float* __restrict__ W,
                           unsigned short* __restrict__ Wb)
{
  int idx = blockIdx.x * 256 + threadIdx.x;
  if (idx >= 128 * 9 * CI) return;
  int co = idx / (9 * CI), r = idx % (9 * CI);
  int t = r / CI, ci = r % CI;
  Wb[idx] = f2bf(W[((size_t)co * CI + ci) * 9 + t]);
}

__global__ void f32_to_bf16(const float* __restrict__ A,
                            unsigned short* __restrict__ B, int n)
{
  int i = blockIdx.x * 256 + threadIdx.x;
  if (i < n) B[i] = f2bf(A[i]);
}

// ---------------- conv3x3 + BN + ReLU: branchless implicit GEMM -------------
// Input padded [b][66][66][CI]; for fixed dy the (dx,ci) reduction is
// CONTIGUOUS: A(px) spans [px*CI, (px+3)*CI) in the padded row.
// Block: 4 waves; M=64 (full row, mf=4), N=128 (wave n0=wid*32, nf=2).
// K-loop: 3 dy x (3*CI/32) kk, fully unrolled, no branches.
// PADOUT=1 -> write padded [b][66][66][128] interior; else [b][4096][128].
template<int CI, int PADOUT>
__global__ __launch_bounds__(256, 2) void conv_mfma(
    const unsigned short* __restrict__ Xp,   // [b][66][66][CI] bf16 padded
    const unsigned short* __restrict__ Wb,   // [128][9][CI]    bf16
    const float* __restrict__ bc,
    const float* __restrict__ bg, const float* __restrict__ bb,
    const float* __restrict__ bm, const float* __restrict__ bv,
    unsigned short* __restrict__ Y)
{
  const int lane = threadIdx.x & 63;
  const int wid  = threadIdx.x >> 6;
  const int n0 = wid * 32;
  const int y = blockIdx.x, b = blockIdx.y;
  const int lr = lane & 15, lk = (lane >> 4) * 8;

  f32x4 acc[4][2];
  #pragma unroll
  for (int i = 0; i < 4; ++i)
    #pragma unroll
    for (int j = 0; j < 2; ++j) acc[i][j] = f32x4{0.f, 0.f, 0.f, 0.f};

  #pragma unroll
  for (int dy = 0; dy < 3; ++dy) {
    // padded input row (y+dy) corresponds to original row y-1+dy
    const unsigned short* arow = Xp + (size_t)((b * 66 + y + dy) * 66) * CI;
    #pragma unroll
    for (int kk = 0; kk < 3 * CI / 32; ++kk) {
      const int kofs = kk * 32 + lk;
      bf16x8 bfr[2];
      #pragma unroll
      for (int nf = 0; nf < 2; ++nf)
        bfr[nf] = *reinterpret_cast<const bf16x8*>(
            Wb + (size_t)(n0 + nf * 16 + lr) * (9 * CI) + dy * 3 * CI + kofs);
      #pragma unroll
      for (int mf = 0; mf < 4; ++mf) {
        bf16x8 afr = *reinterpret_cast<const bf16x8*>(
            arow + (size_t)(mf * 16 + lr) * CI + kofs);
        #pragma unroll
        for (int nf = 0; nf < 2; ++nf)
          acc[mf][nf] = __builtin_amdgcn_mfma_f32_16x16x32_bf16(
              afr, bfr[nf], acc[mf][nf], 0, 0, 0);
      }
    }
  }

  #pragma unroll
  for (int nf = 0; nf < 2; ++nf) {
    int n = n0 + nf * 16 + lr;
    float aS = bg[n] * rsqrtf(bv[n] + 1e-5f);
    float aB = (bc[n] - bm[n]) * aS + bb[n];
    #pragma unroll
    for (int mf = 0; mf < 4; ++mf)
      #pragma unroll
      for (int i = 0; i < 4; ++i) {
        int m = mf * 16 + (lane >> 4) * 4 + i;
        float v = fmaxf(acc[mf][nf][i] * aS + aB, 0.f);
        if (PADOUT)
          Y[((size_t)(b * 66 + y + 1) * 66 + m + 1) * 128 + n] = f2bf(v);
        else
          Y[((size_t)(b * 4096 + y * 64 + m)) * 128 + n] = f2bf(v);
      }
  }
}

// ---------------- bf16 MFMA GEMM: C[M,N] = A[M,K] @ W[N,K]^T ----------------
template<int KDIM, int EPI>
__global__ __launch_bounds__(256) void gemm_mfma(
    const unsigned short* __restrict__ A,   // [M][KDIM] bf16
    const unsigned short* __restrict__ Wn,  // [N][KDIM] bf16
    float* __restrict__ C0, float* __restrict__ C1)
{
  const int lane = threadIdx.x & 63;
  const int wid  = threadIdx.x >> 6;
  const int m0 = blockIdx.x * 64;
  const int n0 = blockIdx.y * 128 + wid * 32;
  const int lr = lane & 15, lk = (lane >> 4) * 8;

  f32x4 acc[4][2];
  #pragma unroll
  for (int i = 0; i < 4; ++i)
    #pragma unroll
    for (int j = 0; j < 2; ++j) acc[i][j] = f32x4{0.f, 0.f, 0.f, 0.f};

  const unsigned short* Ab = A + (size_t)m0 * KDIM;
  #pragma unroll 4
  for (int k0 = 0; k0 < KDIM; k0 += 32) {
    const int kc = k0 + lk;
    bf16x8 bfr[2];
    #pragma unroll
    for (int nf = 0; nf < 2; ++nf)
      bfr[nf] = *reinterpret_cast<const bf16x8*>(
          Wn + (size_t)(n0 + nf * 16 + lr) * KDIM + kc);
    #pragma unroll
    for (int mf = 0; mf < 4; ++mf) {
      bf16x8 afr = *reinterpret_cast<const bf16x8*>(
          Ab + (size_t)(mf * 16 + lr) * KDIM + kc);
      #pragma unroll
      for (int nf = 0; nf < 2; ++nf)
        acc[mf][nf] = __builtin_amdgcn_mfma_f32_16x16x32_bf16(
            afr, bfr[nf], acc[mf][nf], 0, 0, 0);
    }
  }

  #pragma unroll
  for (int nf = 0; nf < 2; ++nf) {
    int n = n0 + nf * 16 + lr;
    #pragma unroll
    for (int mf = 0; mf < 4; ++mf)
      #pragma unroll
      for (int i = 0; i < 4; ++i) {
        int m = m0 + mf * 16 + (lane >> 4) * 4 + i;
        float v = acc[mf][nf][i];
        if (EPI == 0) {
          if (n < 256) C0[(size_t)m * 256 + n] = v;
          else         C1[(size_t)m * 256 + (n - 256)] = v;
        } else {
          C0[(size_t)m * 128 + n] = v;
        }
      }
  }
}

// ---------------- fp32 GEMM (x_proj, N=40) ----------------------------------
__global__ __launch_bounds__(256) void gemm_nt(
    const float* __restrict__ A, const float* __restrict__ W,
    float* __restrict__ C, int M, int N, int K)
{
  __shared__ float As[16][68];
  __shared__ float Bs[16][68];
  const int m0 = blockIdx.x * 64, n0 = blockIdx.y * 64;
  const int tid = threadIdx.x;
  const int tx = tid & 15, ty = tid >> 4;
  const int lr = tid >> 2;
  const int lk = (tid & 3) * 4;
  float acc[4][4] = {};

  for (int k0 = 0; k0 < K; k0 += 16) {
    float4 av = *reinterpret_cast<const float4*>(&A[(size_t)(m0 + lr) * K + k0 + lk]);
    float4 wv = make_float4(0.f, 0.f, 0.f, 0.f);
    if (n0 + lr < N)
      wv = *reinterpret_cast<const float4*>(&W[(size_t)(n0 + lr) * K + k0 + lk]);
    As[lk + 0][lr] = av.x; As[lk + 1][lr] = av.y;
    As[lk + 2][lr] = av.z; As[lk + 3][lr] = av.w;
    Bs[lk + 0][lr] = wv.x; Bs[lk + 1][lr] = wv.y;
    Bs[lk + 2][lr] = wv.z; Bs[lk + 3][lr] = wv.w;
    __syncthreads();
    #pragma unroll
    for (int k = 0; k < 16; ++k) {
      float4 a4 = *reinterpret_cast<const float4*>(&As[k][ty * 4]);
      float4 b4 = *reinterpret_cast<const float4*>(&Bs[k][tx * 4]);
      float avv[4] = {a4.x, a4.y, a4.z, a4.w};
      float bvv[4] = {b4.x, b4.y, b4.z, b4.w};
      #pragma unroll
      for (int i = 0; i < 4; ++i)
        #pragma unroll
        for (int j = 0; j < 4; ++j)
          acc[i][j] = fmaf(avv[i], bvv[j], acc[i][j]);
    }
    __syncthreads();
  }
  #pragma unroll
  for (int i = 0; i < 4; ++i) {
    int m = m0 + ty * 4 + i;
    #pragma unroll
    for (int j = 0; j < 4; ++j) {
      int n = n0 + tx * 4 + j;
      if (n < N) C[(size_t)m * N + n] = acc[i][j];
    }
  }
}

// ---------------- depthwise causal conv1d (DCONV=4) + silu, float4 ----------
__global__ __launch_bounds__(256) void conv1d_silu(
    const float* __restrict__ xm,   // (T,256)
    const float* __restrict__ w,    // (256,4)
    const float* __restrict__ bias, // (256)
    float* __restrict__ out)        // (T,256)
{
  __shared__ float ws4[4][256];
  __shared__ float bsh[256];
  for (int i = threadIdx.x; i < 1024; i += 256)
    ws4[i >> 8][i & 255] = w[(i & 255) * 4 + (i >> 8)];
  bsh[threadIdx.x] = bias[threadIdx.x];
  __syncthreads();
  const int total = 8 * 4096 * 64;
  for (int idx = blockIdx.x * 256 + threadIdx.x; idx < total;
       idx += gridDim.x * 256) {
    int d4 = idx & 63, t = idx >> 6, l = t & 4095;
    int d = d4 * 4;
    float4 acc = *reinterpret_cast<const float4*>(&bsh[d]);
    #pragma unroll
    for (int j = 0; j < 4; ++j) {
      if (l - 3 + j >= 0) {
        float4 xv = *reinterpret_cast<const float4*>(&xm[(size_t)(t - 3 + j) * 256 + d]);
        float4 wv = *reinterpret_cast<const float4*>(&ws4[j][d]);
        acc.x = fmaf(xv.x, wv.x, acc.x);
        acc.y = fmaf(xv.y, wv.y, acc.y);
        acc.z = fmaf(xv.z, wv.z, acc.z);
        acc.w = fmaf(xv.w, wv.w, acc.w);
      }
    }
    acc.x = siluf(acc.x); acc.y = siluf(acc.y);
    acc.z = siluf(acc.z); acc.w = siluf(acc.w);
    *reinterpret_cast<float4*>(&out[(size_t)t * 256 + d]) = acc;
  }
}

// ---------------- chunked selective scan ------------------------------------
__global__ __launch_bounds__(256) void scan_pass1(
    const float* __restrict__ xssm, const float* __restrict__ xdb,
    const float* __restrict__ dtw, const float* __restrict__ dtb,
    const float* __restrict__ A_log,
    float* __restrict__ Q, float* __restrict__ S)
{
  __shared__ __align__(16) float sh[CL][40];
  const int c = blockIdx.x, b = blockIdx.y;
  const int d = threadIdx.x;
  {
    const float4* src = reinterpret_cast<const float4*>(
        &xdb[((size_t)b * 4096 + c * CL) * 40]);
    float4* dst = reinterpret_cast<float4*>(&sh[0][0]);
    for (int i = threadIdx.x; i < CL * 10; i += 256) dst[i] = src[i];
  }
  float4 w0 = *reinterpret_cast<const float4*>(&dtw[d * 8]);
  float4 w1 = *reinterpret_cast<const float4*>(&dtw[d * 8 + 4]);
  const float bdt = dtb[d];
  float Aneg[16], h[16];
  #pragma unroll
  for (int s = 0; s < 16; ++s) {
    Aneg[s] = -__expf(A_log[d * 16 + s]);
    h[s] = 0.f;
  }
  __syncthreads();

  float sdt = 0.f;
  const size_t xbase = ((size_t)b * 4096 + (size_t)c * CL) * 256 + d;
  for (int l = 0; l < CL; ++l) {
    const float4* row = reinterpret_cast<const float4*>(sh[l]);
    float4 r0 = row[0], r1 = row[1];
    float acc = bdt;
    acc = fmaf(r0.x, w0.x, acc); acc = fmaf(r0.y, w0.y, acc);
    acc = fmaf(r0.z, w0.z, acc); acc = fmaf(r0.w, w0.w, acc);
    acc = fmaf(r1.x, w1.x, acc); acc = fmaf(r1.y, w1.y, acc);
    acc = fmaf(r1.z, w1.z, acc); acc = fmaf(r1.w, w1.w, acc);
    float dt = (acc > 20.f) ? acc : __logf(1.f + __expf(acc));
    sdt += dt;
    float xv = xssm[xbase + (size_t)l * 256];
    float dtx = dt * xv;
    #pragma unroll
    for (int q = 0; q < 4; ++q) {
      float4 Bq = row[2 + q];
      float bb4[4] = {Bq.x, Bq.y, Bq.z, Bq.w};
      #pragma unroll
      for (int j = 0; j < 4; ++j) {
        int s = q * 4 + j;
        float dA = __expf(dt * Aneg[s]);
        h[s] = fmaf(dA, h[s], dtx * bb4[j]);
      }
    }
  }
  float4* q4 = reinterpret_cast<float4*>(
      &Q[(((size_t)b * NC + c) * 256 + d) * 16]);
  #pragma unroll
  for (int q = 0; q < 4; ++q)
    q4[q] = make_float4(h[q * 4], h[q * 4 + 1], h[q * 4 + 2], h[q * 4 + 3]);
  S[((size_t)b * NC + c) * 256 + d] = sdt;
}

__global__ __launch_bounds__(256) void scan_combine(
    float* __restrict__ Q, const float* __restrict__ S,
    const float* __restrict__ A_log)
{
  int g = blockIdx.x * 256 + threadIdx.x;   // 32768 total
  int b = g >> 12, d = (g >> 4) & 255, s = g & 15;
  float Aneg = -__expf(A_log[d * 16 + s]);
  float h = 0.f;
  for (int c = 0; c < NC; ++c) {
    size_t qi = (((size_t)b * NC + c) * 256 + d) * 16 + s;
    float q  = Q[qi];
    float sd = S[((size_t)b * NC + c) * 256 + d];
    Q[qi] = h;
    h = fmaf(__expf(Aneg * sd), h, q);
  }
}

__global__ __launch_bounds__(256) void scan_pass2(
    const float* __restrict__ xssm, const float* __restrict__ xdb,
    const float* __restrict__ zb,
    const float* __restrict__ dtw, const float* __restrict__ dtb,
    const float* __restrict__ A_log, const float* __restrict__ Dp,
    const float* __restrict__ Hstart, unsigned short* __restrict__ ybf)
{
  __shared__ __align__(16) float sh[CL][40];
  const int c = blockIdx.x, b = blockIdx.y;
  const int d = threadIdx.x;
  {
    const float4* src = reinterpret_cast<const float4*>(
        &xdb[((size_t)b * 4096 + c * CL) * 40]);
    float4* dst = reinterpret_cast<float4*>(&sh[0][0]);
    for (int i = threadIdx.x; i < CL * 10; i += 256) dst[i] = src[i];
  }
  float4 w0 = *reinterpret_cast<const float4*>(&dtw[d * 8]);
  float4 w1 = *reinterpret_cast<const float4*>(&dtw[d * 8 + 4]);
  const float bdt = dtb[d];
  const float Dd = Dp[d];
  float Aneg[16], h[16];
  const float4* hs4 = reinterpret_cast<const float4*>(
      &Hstart[(((size_t)b * NC + c) * 256 + d) * 16]);
  #pragma unroll
  for (int q = 0; q < 4; ++q) {
    float4 hv = hs4[q];
    h[q * 4 + 0] = hv.x; h[q * 4 + 1] = hv.y;
    h[q * 4 + 2] = hv.z; h[q * 4 + 3] = hv.w;
  }
  #pragma unroll
  for (int s = 0; s < 16; ++s) Aneg[s] = -__expf(A_log[d * 16 + s]);
  __syncthreads();

  const size_t xbase = ((size_t)b * 4096 + (size_t)c * CL) * 256 + d;
  for (int l = 0; l < CL; ++l) {
    const float4* row = reinterpret_cast<const float4*>(sh[l]);
    float4 r0 = row[0], r1 = row[1];
    float acc = bdt;
    acc = fmaf(r0.x, w0.x, acc); acc = fmaf(r0.y, w0.y, acc);
    acc = fmaf(r0.z, w0.z, acc); acc = fmaf(r0.w, w0.w, acc);
    acc = fmaf(r1.x, w1.x, acc); acc = fmaf(r1.y, w1.y, acc);
    acc = fmaf(r1.z, w1.z, acc); acc = fmaf(r1.w, w1.w, acc);
    float dt = (acc > 20.f) ? acc : __logf(1.f + __expf(acc));
    float xv = xssm[xbase + (size_t)l * 256];
    float zv = zb[xbase + (size_t)l * 256];
    float dtx = dt * xv;
    float y = 0.f;
    #pragma unroll
    for (int q = 0; q < 4; ++q) {
      float4 Bq = row[2 + q], Cq = row[6 + q];
      float bb4[4] = {Bq.x, Bq.y, Bq.z, Bq.w};
      float cc4[4] = {Cq.x, Cq.y, Cq.z, Cq.w};
      #pragma unroll
      for (int j = 0; j < 4; ++j) {
        int s = q * 4 + j;
        float dA = __expf(dt * Aneg[s]);
        h[s] = fmaf(dA, h[s], dtx * bb4[j]);
        y = fmaf(h[s], cc4[j], y);
      }
    }
    y = (y + Dd * xv) * siluf(zv);
    ybf[xbase + (size_t)l * 256] = f2bf(y);
  }
}

// ---------------- LayerNorm(128) + transpose to NCHW ------------------------
__global__ __launch_bounds__(256) void ln_transpose(
    const float* __restrict__ X,
    const float* __restrict__ g, const float* __restrict__ b,
    float* __restrict__ out)
{
  __shared__ float buf[64][129];
  const int t0 = blockIdx.x * 64;
  const int bb = t0 >> 12, l0 = t0 & 4095;
  const int tid = threadIdx.x;
  for (int idx = tid; idx < 64 * 128; idx += 256)
    buf[idx >> 7][idx & 127] = X[(size_t)t0 * 128 + idx];
  __syncthreads();
  const int tt = tid >> 2, q = tid & 3;
  float s = 0.f, sq = 0.f;
  #pragma unroll
  for (int i = 0; i < 32; ++i) {
    float v = buf[tt][q * 32 + i];
    s += v; sq += v * v;
  }
  s  += __shfl_xor(s, 1);  s  += __shfl_xor(s, 2);
  sq += __shfl_xor(sq, 1); sq += __shfl_xor(sq, 2);
  float mu = s * (1.f / 128.f);
  float var = sq * (1.f / 128.f) - mu * mu;
  float rstd = rsqrtf(fmaxf(var, 0.f) + 1e-5f);
  #pragma unroll
  for (int i = 0; i < 32; ++i) {
    int c = q * 32 + i;
    buf[tt][c] = (buf[tt][c] - mu) * rstd * g[c] + b[c];
  }
  __syncthreads();
  for (int idx = tid; idx < 64 * 128; idx += 256) {
    int c = idx >> 6, t2 = idx & 63;
    out[((size_t)bb * 128 + c) * 4096 + l0 + t2] = buf[t2][c];
  }
}

// ---------------------------------------------------------------------------
extern "C" void kernel_launch(void* const* d_in, const int* in_sizes, int n_in,
                              void* d_out, int out_size, void* d_ws, size_t ws_size,
                              hipStream_t stream) {
  const float* x        = (const float*)d_in[0];
  const float* conv1_w  = (const float*)d_in[1];
  const float* conv1_b  = (const float*)d_in[2];
  const float* bn1_g    = (const float*)d_in[3];
  const float* bn1_b    = (const float*)d_in[4];
  const float* bn1_m    = (const float*)d_in[5];
  const float* bn1_v    = (const float*)d_in[6];
  const float* conv2_w  = (const float*)d_in[7];
  const float* conv2_b  = (const float*)d_in[8];
  const float* bn2_g    = (const float*)d_in[9];
  const float* bn2_b    = (const float*)d_in[10];
  const float* bn2_m    = (const float*)d_in[11];
  const float* bn2_v    = (const float*)d_in[12];
  const float* in_proj_w  = (const float*)d_in[13];  // (512,128)
  const float* conv1d_w   = (const float*)d_in[14];  // (256,1,4)
  const float* conv1d_b   = (const float*)d_in[15];
  const float* x_proj_w   = (const float*)d_in[16];  // (40,256)
  const float* dt_proj_w  = (const float*)d_in[17];  // (256,8)
  const float* dt_proj_b  = (const float*)d_in[18];
  const float* A_log      = (const float*)d_in[19];  // (256,16)
  const float* Dp         = (const float*)d_in[20];  // (256)
  const float* out_proj_w = (const float*)d_in[21];  // (128,256)
  const float* ln_g       = (const float*)d_in[22];
  const float* ln_b       = (const float*)d_in[23];
  float* out = (float*)d_out;

  float* ws_f = (float*)d_ws;
  // workspace (float units), lifetime-reuse; peak 29,652,992 f = 118.6 MB
  // R1 [0, 8388608): xbp(pre) -> xm -> [ybf | xdb | Sbuf] -> [ybf | outs]
  unsigned short* xbp  = (unsigned short*)ws_f;          // [8][66][66][64] bf16
  float*          xm   = ws_f;                           // T*256 f
  unsigned short* ybf  = (unsigned short*)ws_f;          // T*256 bf16
  float*          xdb  = ws_f + 4194304;                 // T*40 f
  float*          Sbuf = ws_f + 5505024;                 // B*NC*256 f
  float*          outs = ws_f + 4194304;                 // T*128 f (after xdb dead)
  // R2, R3
  float*          zb   = ws_f + 8388608;
  float*          xssm = ws_f + 16777216;
  // R4 [25165824, 29360128): h1p+seqb (conv phase) -> Qbuf (scan phase)
  unsigned short* h1p  = (unsigned short*)(ws_f + 25165824);  // [8][66][66][128]
  unsigned short* seqb = (unsigned short*)(ws_f + 27396096);  // [T][128]
  float*          Qbuf = ws_f + 25165824;                     // B*NC*256*16 f
  // weights
  unsigned short* wb1  = (unsigned short*)(ws_f + 29493248);
  unsigned short* wb2  = (unsigned short*)(ws_f + 29530112);
  unsigned short* win  = (unsigned short*)(ws_f + 29603840);
  unsigned short* wout = (unsigned short*)(ws_f + 29636608);

  // zero padded borders (whole buffers; interior overwritten next)
  hipMemsetAsync(xbp, 0, (size_t)8 * 66 * 66 * 64 * 2, stream);
  hipMemsetAsync(h1p, 0, (size_t)8 * 66 * 66 * 128 * 2, stream);

  // pre-passes
  nchw2nhwc_bf16<<<512, 256, 0, stream>>>(x, xbp);
  convw_prep<64><<<(73728 + 255) / 256, 256, 0, stream>>>(conv1_w, wb1);
  convw_prep<128><<<(147456 + 255) / 256, 256, 0, stream>>>(conv2_w, wb2);
  f32_to_bf16<<<256, 256, 0, stream>>>(in_proj_w, win, 65536);
  f32_to_bf16<<<128, 256, 0, stream>>>(out_proj_w, wout, 32768);

  // convs (branchless MFMA implicit GEMM on padded NHWC)
  conv_mfma<64, 1><<<dim3(64, 8), 256, 0, stream>>>(
      xbp, wb1, conv1_b, bn1_g, bn1_b, bn1_m, bn1_v, h1p);
  conv_mfma<128, 0><<<dim3(64, 8), 256, 0, stream>>>(
      h1p, wb2, conv2_b, bn2_g, bn2_b, bn2_m, bn2_v, seqb);

  // in_proj (one GEMM, N=512 -> xm | z)
  gemm_mfma<128, 0><<<dim3(512, 4), 256, 0, stream>>>(seqb, win, xm, zb);

  conv1d_silu<<<2048, 256, 0, stream>>>(xm, conv1d_w, conv1d_b, xssm);
  gemm_nt<<<dim3(512, 1), 256, 0, stream>>>(xssm, x_proj_w, xdb, 32768, 40, 256);

  scan_pass1<<<dim3(NC, 8), 256, 0, stream>>>(
      xssm, xdb, dt_proj_w, dt_proj_b, A_log, Qbuf, Sbuf);
  scan_combine<<<128, 256, 0, stream>>>(Qbuf, Sbuf, A_log);
  scan_pass2<<<dim3(NC, 8), 256, 0, stream>>>(
      xssm, xdb, zb, dt_proj_w, dt_proj_b, A_log, Dp, Qbuf, ybf);

  // out_proj (MFMA) + LN/transpose
  gemm_mfma<256, 1><<<dim3(512, 1), 256, 0, stream>>>(ybf, wout, outs, nullptr);
  ln_transpose<<<512, 256, 0, stream>>>(outs, ln_g, ln_b, out);
}

// Round 7
// 234.319 us; speedup vs baseline: 1.2771x; 1.2038x over previous
//
#include <hip/hip_runtime.h>
#include <hip/hip_bf16.h>

// ---------------------------------------------------------------------------
// MambaConvBlock fused pipeline. Round 7: m97-style LDS-staged MFMA for
// convs and GEMMs (global_load_lds dbuf, shared A across waves).
// Sizes: B=8, CIN=64, COUT=128, H=W=64, L=4096, T=32768,
//        DINNER=256, DSTATE=16, DTRANK=8, DCONV=4.
// ---------------------------------------------------------------------------

typedef __attribute__((ext_vector_type(8))) short bf16x8;
typedef __attribute__((ext_vector_type(4))) float f32x4;

#define DEV __device__ __forceinline__

DEV float siluf(float v) {
  return v * __builtin_amdgcn_rcpf(1.f + __expf(-v));
}

DEV unsigned short f2bf(float f) {
  __hip_bfloat16 h = __float2bfloat16(f);
  return *reinterpret_cast<unsigned short*>(&h);
}

// async global->LDS, 16B per lane; lds dest = uniform base + lane*16
DEV void gll16(const void* g, void* l) {
  __builtin_amdgcn_global_load_lds(
      (const __attribute__((address_space(1))) void*)g,
      (__attribute__((address_space(3))) void*)l, 16, 0, 0);
}

constexpr int NC = 128;  // scan chunks per batch
constexpr int CL = 32;   // scan chunk length

// ---------------- pre-pass: NCHW fp32 -> padded NHWC bf16 -------------------
__global__ __launch_bounds__(256) void nchw2nhwc_bf16(
    const float* __restrict__ X, unsigned short* __restrict__ Xb)
{
  __shared__ float t[64][65];
  const int by = blockIdx.x;            // b*64 + y
  const int b = by >> 6, y = by & 63;
  const int tid = threadIdx.x;
  for (int i = tid; i < 4096; i += 256) {
    int c = i >> 6, xx = i & 63;
    t[c][xx] = X[(((size_t)b * 64 + c) * 64 + y) * 64 + xx];
  }
  __syncthreads();
  for (int i = tid; i < 4096; i += 256) {
    int xx = i >> 6, c = i & 63;
    Xb[(((size_t)(b * 66 + y + 1) * 66) + xx + 1) * 64 + c] = f2bf(t[c][xx]);
  }
}

// ---------------- pre-pass: conv weights -> bf16 [co][dy][dx][ci] -----------
template<int CI>
__global__ void convw_prep(const float* __restrict__ W,
                           unsigned short* __restrict__ Wb)
{
  int idx = blockIdx.x * 256 + threadIdx.x;
  if (idx >= 128 * 9 * CI) return;
  int co = idx / (9 * CI), r = idx % (9 * CI);
  int t = r / CI, ci = r % CI;
  Wb[idx] = f2bf(W[((size_t)co * CI + ci) * 9 + t]);
}

__global__ void f32_to_bf16(const float* __restrict__ A,
                            unsigned short* __restrict__ B, int n)
{
  int i = blockIdx.x * 256 + threadIdx.x;
  if (i < n) B[i] = f2bf(A[i]);
}

// ---------------- conv3x3 + BN + ReLU: LDS-staged implicit GEMM -------------
// Input padded [b][66][66][CI]. Block: 4 waves, M=64 (row y), N=128.
// K chunks of 64 bf16 (NCH = 9*CI/64), A-tile [64 tok][64 k] staged to LDS
// via global_load_lds (layout [kg 8][row 64] x16B), double-buffered, shared
// by all 4 waves. One __syncthreads per chunk.
template<int CI, int PADOUT>
__global__ __launch_bounds__(256) void conv_mfma(
    const unsigned short* __restrict__ Xp,   // [b][66][66][CI] bf16 padded
    const unsigned short* __restrict__ Wb,   // [128][9*CI]     bf16
    const float* __restrict__ bc,
    const float* __restrict__ bg, const float* __restrict__ bb,
    const float* __restrict__ bm, const float* __restrict__ bv,
    unsigned short* __restrict__ Y)
{
  constexpr int KC  = 3 * CI / 64;   // chunks per dy
  constexpr int NCH = 3 * KC;        // total chunks
  __shared__ bf16x8 ldsA[2][512];    // 2 x 8KB

  const int lane = threadIdx.x & 63;
  const int wid  = threadIdx.x >> 6;
  const int n0 = wid * 32;
  const int y = blockIdx.x, b = blockIdx.y;
  const int lr = lane & 15, kq = lane >> 4, lk = kq * 8;

  auto stage = [&](int buf, int c) {
    const int dy = c / KC, kc = c - dy * KC;
    const unsigned short* g = Xp
        + (size_t)((b * 66 + y + dy) * 66) * CI
        + (size_t)lane * CI + kc * 64 + wid * 16;
    gll16(g,     &ldsA[buf][(wid * 2) * 64]);
    gll16(g + 8, &ldsA[buf][(wid * 2 + 1) * 64]);
  };

  f32x4 acc[4][2];
  #pragma unroll
  for (int i = 0; i < 4; ++i)
    #pragma unroll
    for (int j = 0; j < 2; ++j) acc[i][j] = f32x4{0.f, 0.f, 0.f, 0.f};

  stage(0, 0);
  __syncthreads();

  #pragma unroll
  for (int c = 0; c < NCH; ++c) {
    if (c + 1 < NCH) stage((c + 1) & 1, c + 1);
    const int dy = c / KC, kc = c - dy * KC;
    bf16x8 bw[2][2];
    #pragma unroll
    for (int t = 0; t < 2; ++t)
      #pragma unroll
      for (int nf = 0; nf < 2; ++nf)
        bw[t][nf] = *reinterpret_cast<const bf16x8*>(
            Wb + (size_t)(n0 + nf * 16 + lr) * (9 * CI)
               + dy * 3 * CI + kc * 64 + t * 32 + lk);
    const bf16x8* Ab = ldsA[c & 1];
    #pragma unroll
    for (int t = 0; t < 2; ++t)
      #pragma unroll
      for (int mf = 0; mf < 4; ++mf) {
        bf16x8 afr = Ab[(t * 4 + kq) * 64 + mf * 16 + lr];
        #pragma unroll
        for (int nf = 0; nf < 2; ++nf)
          acc[mf][nf] = __builtin_amdgcn_mfma_f32_16x16x32_bf16(
              afr, bw[t][nf], acc[mf][nf], 0, 0, 0);
      }
    __syncthreads();
  }

  #pragma unroll
  for (int nf = 0; nf < 2; ++nf) {
    int n = n0 + nf * 16 + lr;
    float aS = bg[n] * rsqrtf(bv[n] + 1e-5f);
    float aB = (bc[n] - bm[n]) * aS + bb[n];
    #pragma unroll
    for (int mf = 0; mf < 4; ++mf)
      #pragma unroll
      for (int i = 0; i < 4; ++i) {
        int m = mf * 16 + kq * 4 + i;
        float v = fmaxf(acc[mf][nf][i] * aS + aB, 0.f);
        if (PADOUT)
          Y[((size_t)(b * 66 + y + 1) * 66 + m + 1) * 128 + n] = f2bf(v);
        else
          Y[((size_t)(b * 4096 + y * 64 + m)) * 128 + n] = f2bf(v);
      }
  }
}

// ---------------- bf16 MFMA GEMM, LDS-staged A ------------------------------
// C[M,N] = A[M,K] @ W[N,K]^T. Block 4 waves, tile M=64 x N=128.
// B fully preloaded to regs (K<=256); A chunks staged like conv.
template<int KDIM, int EPI>
__global__ __launch_bounds__(256) void gemm_mfma(
    const unsigned short* __restrict__ A,   // [M][KDIM] bf16
    const unsigned short* __restrict__ Wn,  // [N][KDIM] bf16
    float* __restrict__ C0, float* __restrict__ C1)
{
  constexpr int NCH = KDIM / 64;
  __shared__ bf16x8 ldsA[2][512];

  const int lane = threadIdx.x & 63;
  const int wid  = threadIdx.x >> 6;
  const int m0 = blockIdx.x * 64;
  const int n0 = blockIdx.y * 128 + wid * 32;
  const int lr = lane & 15, kq = lane >> 4, lk = kq * 8;

  // preload all B fragments
  bf16x8 bw[NCH][2][2];
  #pragma unroll
  for (int c = 0; c < NCH; ++c)
    #pragma unroll
    for (int t = 0; t < 2; ++t)
      #pragma unroll
      for (int nf = 0; nf < 2; ++nf)
        bw[c][t][nf] = *reinterpret_cast<const bf16x8*>(
            Wn + (size_t)(n0 + nf * 16 + lr) * KDIM + c * 64 + t * 32 + lk);

  auto stage = [&](int buf, int c) {
    const unsigned short* g = A + (size_t)(m0 + lane) * KDIM + c * 64 + wid * 16;
    gll16(g,     &ldsA[buf][(wid * 2) * 64]);
    gll16(g + 8, &ldsA[buf][(wid * 2 + 1) * 64]);
  };

  f32x4 acc[4][2];
  #pragma unroll
  for (int i = 0; i < 4; ++i)
    #pragma unroll
    for (int j = 0; j < 2; ++j) acc[i][j] = f32x4{0.f, 0.f, 0.f, 0.f};

  stage(0, 0);
  __syncthreads();

  #pragma unroll
  for (int c = 0; c < NCH; ++c) {
    if (c + 1 < NCH) stage((c + 1) & 1, c + 1);
    const bf16x8* Ab = ldsA[c & 1];
    #pragma unroll
    for (int t = 0; t < 2; ++t)
      #pragma unroll
      for (int mf = 0; mf < 4; ++mf) {
        bf16x8 afr = Ab[(t * 4 + kq) * 64 + mf * 16 + lr];
        #pragma unroll
        for (int nf = 0; nf < 2; ++nf)
          acc[mf][nf] = __builtin_amdgcn_mfma_f32_16x16x32_bf16(
              afr, bw[c][t][nf], acc[mf][nf], 0, 0, 0);
      }
    __syncthreads();
  }

  #pragma unroll
  for (int nf = 0; nf < 2; ++nf) {
    int n = n0 + nf * 16 + lr;
    #pragma unroll
    for (int mf = 0; mf < 4; ++mf)
      #pragma unroll
      for (int i = 0; i < 4; ++i) {
        int m = m0 + mf * 16 + kq * 4 + i;
        float v = acc[mf][nf][i];
        if (EPI == 0) {
          if (n < 256) C0[(size_t)m * 256 + n] = v;
          else         C1[(size_t)m * 256 + (n - 256)] = v;
        } else {
          C0[(size_t)m * 128 + n] = v;
        }
      }
  }
}

// ---------------- fp32 GEMM (x_proj, N=40) ----------------------------------
__global__ __launch_bounds__(256) void gemm_nt(
    const float* __restrict__ A, const float* __restrict__ W,
    float* __restrict__ C, int M, int N, int K)
{
  __shared__ float As[16][68];
  __shared__ float Bs[16][68];
  const int m0 = blockIdx.x * 64, n0 = blockIdx.y * 64;
  const int tid = threadIdx.x;
  const int tx = tid & 15, ty = tid >> 4;
  const int lr = tid >> 2;
  const int lk = (tid & 3) * 4;
  float acc[4][4] = {};

  for (int k0 = 0; k0 < K; k0 += 16) {
    float4 av = *reinterpret_cast<const float4*>(&A[(size_t)(m0 + lr) * K + k0 + lk]);
    float4 wv = make_float4(0.f, 0.f, 0.f, 0.f);
    if (n0 + lr < N)
      wv = *reinterpret_cast<const float4*>(&W[(size_t)(n0 + lr) * K + k0 + lk]);
    As[lk + 0][lr] = av.x; As[lk + 1][lr] = av.y;
    As[lk + 2][lr] = av.z; As[lk + 3][lr] = av.w;
    Bs[lk + 0][lr] = wv.x; Bs[lk + 1][lr] = wv.y;
    Bs[lk + 2][lr] = wv.z; Bs[lk + 3][lr] = wv.w;
    __syncthreads();
    #pragma unroll
    for (int k = 0; k < 16; ++k) {
      float4 a4 = *reinterpret_cast<const float4*>(&As[k][ty * 4]);
      float4 b4 = *reinterpret_cast<const float4*>(&Bs[k][tx * 4]);
      float avv[4] = {a4.x, a4.y, a4.z, a4.w};
      float bvv[4] = {b4.x, b4.y, b4.z, b4.w};
      #pragma unroll
      for (int i = 0; i < 4; ++i)
        #pragma unroll
        for (int j = 0; j < 4; ++j)
          acc[i][j] = fmaf(avv[i], bvv[j], acc[i][j]);
    }
    __syncthreads();
  }
  #pragma unroll
  for (int i = 0; i < 4; ++i) {
    int m = m0 + ty * 4 + i;
    #pragma unroll
    for (int j = 0; j < 4; ++j) {
      int n = n0 + tx * 4 + j;
      if (n < N) C[(size_t)m * N + n] = acc[i][j];
    }
  }
}

// ---------------- depthwise causal conv1d (DCONV=4) + silu, float4 ----------
__global__ __launch_bounds__(256) void conv1d_silu(
    const float* __restrict__ xm,   // (T,256)
    const float* __restrict__ w,    // (256,4)
    const float* __restrict__ bias, // (256)
    float* __restrict__ out)        // (T,256)
{
  __shared__ float ws4[4][256];
  __shared__ float bsh[256];
  for (int i = threadIdx.x; i < 1024; i += 256)
    ws4[i >> 8][i & 255] = w[(i & 255) * 4 + (i >> 8)];
  bsh[threadIdx.x] = bias[threadIdx.x];
  __syncthreads();
  const int total = 8 * 4096 * 64;
  for (int idx = blockIdx.x * 256 + threadIdx.x; idx < total;
       idx += gridDim.x * 256) {
    int d4 = idx & 63, t = idx >> 6, l = t & 4095;
    int d = d4 * 4;
    float4 acc = *reinterpret_cast<const float4*>(&bsh[d]);
    #pragma unroll
    for (int j = 0; j < 4; ++j) {
      if (l - 3 + j >= 0) {
        float4 xv = *reinterpret_cast<const float4*>(&xm[(size_t)(t - 3 + j) * 256 + d]);
        float4 wv = *reinterpret_cast<const float4*>(&ws4[j][d]);
        acc.x = fmaf(xv.x, wv.x, acc.x);
        acc.y = fmaf(xv.y, wv.y, acc.y);
        acc.z = fmaf(xv.z, wv.z, acc.z);
        acc.w = fmaf(xv.w, wv.w, acc.w);
      }
    }
    acc.x = siluf(acc.x); acc.y = siluf(acc.y);
    acc.z = siluf(acc.z); acc.w = siluf(acc.w);
    *reinterpret_cast<float4*>(&out[(size_t)t * 256 + d]) = acc;
  }
}

// ---------------- chunked selective scan ------------------------------------
__global__ __launch_bounds__(256) void scan_pass1(
    const float* __restrict__ xssm, const float* __restrict__ xdb,
    const float* __restrict__ dtw, const float* __restrict__ dtb,
    const float* __restrict__ A_log,
    float* __restrict__ Q, float* __restrict__ S)
{
  __shared__ __align__(16) float sh[CL][40];
  const int c = blockIdx.x, b = blockIdx.y;
  const int d = threadIdx.x;
  {
    const float4* src = reinterpret_cast<const float4*>(
        &xdb[((size_t)b * 4096 + c * CL) * 40]);
    float4* dst = reinterpret_cast<float4*>(&sh[0][0]);
    for (int i = threadIdx.x; i < CL * 10; i += 256) dst[i] = src[i];
  }
  float4 w0 = *reinterpret_cast<const float4*>(&dtw[d * 8]);
  float4 w1 = *reinterpret_cast<const float4*>(&dtw[d * 8 + 4]);
  const float bdt = dtb[d];
  float Aneg[16], h[16];
  #pragma unroll
  for (int s = 0; s < 16; ++s) {
    Aneg[s] = -__expf(A_log[d * 16 + s]);
    h[s] = 0.f;
  }
  __syncthreads();

  float sdt = 0.f;
  const size_t xbase = ((size_t)b * 4096 + (size_t)c * CL) * 256 + d;
  for (int l = 0; l < CL; ++l) {
    const float4* row = reinterpret_cast<const float4*>(sh[l]);
    float4 r0 = row[0], r1 = row[1];
    float acc = bdt;
    acc = fmaf(r0.x, w0.x, acc); acc = fmaf(r0.y, w0.y, acc);
    acc = fmaf(r0.z, w0.z, acc); acc = fmaf(r0.w, w0.w, acc);
    acc = fmaf(r1.x, w1.x, acc); acc = fmaf(r1.y, w1.y, acc);
    acc = fmaf(r1.z, w1.z, acc); acc = fmaf(r1.w, w1.w, acc);
    float dt = (acc > 20.f) ? acc : __logf(1.f + __expf(acc));
    sdt += dt;
    float xv = xssm[xbase + (size_t)l * 256];
    float dtx = dt * xv;
    #pragma unroll
    for (int q = 0; q < 4; ++q) {
      float4 Bq = row[2 + q];
      float bb4[4] = {Bq.x, Bq.y, Bq.z, Bq.w};
      #pragma unroll
      for (int j = 0; j < 4; ++j) {
        int s = q * 4 + j;
        float dA = __expf(dt * Aneg[s]);
        h[s] = fmaf(dA, h[s], dtx * bb4[j]);
      }
    }
  }
  float4* q4 = reinterpret_cast<float4*>(
      &Q[(((size_t)b * NC + c) * 256 + d) * 16]);
  #pragma unroll
  for (int q = 0; q < 4; ++q)
    q4[q] = make_float4(h[q * 4], h[q * 4 + 1], h[q * 4 + 2], h[q * 4 + 3]);
  S[((size_t)b * NC + c) * 256 + d] = sdt;
}

__global__ __launch_bounds__(256) void scan_combine(
    float* __restrict__ Q, const float* __restrict__ S,
    const float* __restrict__ A_log)
{
  int g = blockIdx.x * 256 + threadIdx.x;   // 32768 total
  int b = g >> 12, d = (g >> 4) & 255, s = g & 15;
  float Aneg = -__expf(A_log[d * 16 + s]);
  float h = 0.f;
  for (int c = 0; c < NC; ++c) {
    size_t qi = (((size_t)b * NC + c) * 256 + d) * 16 + s;
    float q  = Q[qi];
    float sd = S[((size_t)b * NC + c) * 256 + d];
    Q[qi] = h;
    h = fmaf(__expf(Aneg * sd), h, q);
  }
}

__global__ __launch_bounds__(256) void scan_pass2(
    const float* __restrict__ xssm, const float* __restrict__ xdb,
    const float* __restrict__ zb,
    const float* __restrict__ dtw, const float* __restrict__ dtb,
    const float* __restrict__ A_log, const float* __restrict__ Dp,
    const float* __restrict__ Hstart, unsigned short* __restrict__ ybf)
{
  __shared__ __align__(16) float sh[CL][40];
  const int c = blockIdx.x, b = blockIdx.y;
  const int d = threadIdx.x;
  {
    const float4* src = reinterpret_cast<const float4*>(
        &xdb[((size_t)b * 4096 + c * CL) * 40]);
    float4* dst = reinterpret_cast<float4*>(&sh[0][0]);
    for (int i = threadIdx.x; i < CL * 10; i += 256) dst[i] = src[i];
  }
  float4 w0 = *reinterpret_cast<const float4*>(&dtw[d * 8]);
  float4 w1 = *reinterpret_cast<const float4*>(&dtw[d * 8 + 4]);
  const float bdt = dtb[d];
  const float Dd = Dp[d];
  float Aneg[16], h[16];
  const float4* hs4 = reinterpret_cast<const float4*>(
      &Hstart[(((size_t)b * NC + c) * 256 + d) * 16]);
  #pragma unroll
  for (int q = 0; q < 4; ++q) {
    float4 hv = hs4[q];
    h[q * 4 + 0] = hv.x; h[q * 4 + 1] = hv.y;
    h[q * 4 + 2] = hv.z; h[q * 4 + 3] = hv.w;
  }
  #pragma unroll
  for (int s = 0; s < 16; ++s) Aneg[s] = -__expf(A_log[d * 16 + s]);
  __syncthreads();

  const size_t xbase = ((size_t)b * 4096 + (size_t)c * CL) * 256 + d;
  for (int l = 0; l < CL; ++l) {
    const float4* row = reinterpret_cast<const float4*>(sh[l]);
    float4 r0 = row[0], r1 = row[1];
    float acc = bdt;
    acc = fmaf(r0.x, w0.x, acc); acc = fmaf(r0.y, w0.y, acc);
    acc = fmaf(r0.z, w0.z, acc); acc = fmaf(r0.w, w0.w, acc);
    acc = fmaf(r1.x, w1.x, acc); acc = fmaf(r1.y, w1.y, acc);
    acc = fmaf(r1.z, w1.z, acc); acc = fmaf(r1.w, w1.w, acc);
    float dt = (acc > 20.f) ? acc : __logf(1.f + __expf(acc));
    float xv = xssm[xbase + (size_t)l * 256];
    float zv = zb[xbase + (size_t)l * 256];
    float dtx = dt * xv;
    float y = 0.f;
    #pragma unroll
    for (int q = 0; q < 4; ++q) {
      float4 Bq = row[2 + q], Cq = row[6 + q];
      float bb4[4] = {Bq.x, Bq.y, Bq.z, Bq.w};
      float cc4[4] = {Cq.x, Cq.y, Cq.z, Cq.w};
      #pragma unroll
      for (int j = 0; j < 4; ++j) {
        int s = q * 4 + j;
        float dA = __expf(dt * Aneg[s]);
        h[s] = fmaf(dA, h[s], dtx * bb4[j]);
        y = fmaf(h[s], cc4[j], y);
      }
    }
    y = (y + Dd * xv) * siluf(zv);
    ybf[xbase + (size_t)l * 256] = f2bf(y);
  }
}

// ---------------- LayerNorm(128) + transpose to NCHW ------------------------
__global__ __launch_bounds__(256) void ln_transpose(
    const float* __restrict__ X,
    const float* __restrict__ g, const float* __restrict__ b,
    float* __restrict__ out)
{
  __shared__ float buf[64][129];
  const int t0 = blockIdx.x * 64;
  const int bb = t0 >> 12, l0 = t0 & 4095;
  const int tid = threadIdx.x;
  for (int idx = tid; idx < 64 * 128; idx += 256)
    buf[idx >> 7][idx & 127] = X[(size_t)t0 * 128 + idx];
  __syncthreads();
  const int tt = tid >> 2, q = tid & 3;
  float s = 0.f, sq = 0.f;
  #pragma unroll
  for (int i = 0; i < 32; ++i) {
    float v = buf[tt][q * 32 + i];
    s += v; sq += v * v;
  }
  s  += __shfl_xor(s, 1);  s  += __shfl_xor(s, 2);
  sq += __shfl_xor(sq, 1); sq += __shfl_xor(sq, 2);
  float mu = s * (1.f / 128.f);
  float var = sq * (1.f / 128.f) - mu * mu;
  float rstd = rsqrtf(fmaxf(var, 0.f) + 1e-5f);
  #pragma unroll
  for (int i = 0; i < 32; ++i) {
    int c = q * 32 + i;
    buf[tt][c] = (buf[tt][c] - mu) * rstd * g[c] + b[c];
  }
  __syncthreads();
  for (int idx = tid; idx < 64 * 128; idx += 256) {
    int c = idx >> 6, t2 = idx & 63;
    out[((size_t)bb * 128 + c) * 4096 + l0 + t2] = buf[t2][c];
  }
}

// ---------------------------------------------------------------------------
extern "C" void kernel_launch(void* const* d_in, const int* in_sizes, int n_in,
                              void* d_out, int out_size, void* d_ws, size_t ws_size,
                              hipStream_t stream) {
  const float* x        = (const float*)d_in[0];
  const float* conv1_w  = (const float*)d_in[1];
  const float* conv1_b  = (const float*)d_in[2];
  const float* bn1_g    = (const float*)d_in[3];
  const float* bn1_b    = (const float*)d_in[4];
  const float* bn1_m    = (const float*)d_in[5];
  const float* bn1_v    = (const float*)d_in[6];
  const float* conv2_w  = (const float*)d_in[7];
  const float* conv2_b  = (const float*)d_in[8];
  const float* bn2_g    = (const float*)d_in[9];
  const float* bn2_b    = (const float*)d_in[10];
  const float* bn2_m    = (const float*)d_in[11];
  const float* bn2_v    = (const float*)d_in[12];
  const float* in_proj_w  = (const float*)d_in[13];  // (512,128)
  const float* conv1d_w   = (const float*)d_in[14];  // (256,1,4)
  const float* conv1d_b   = (const float*)d_in[15];
  const float* x_proj_w   = (const float*)d_in[16];  // (40,256)
  const float* dt_proj_w  = (const float*)d_in[17];  // (256,8)
  const float* dt_proj_b  = (const float*)d_in[18];
  const float* A_log      = (const float*)d_in[19];  // (256,16)
  const float* Dp         = (const float*)d_in[20];  // (256)
  const float* out_proj_w = (const float*)d_in[21];  // (128,256)
  const float* ln_g       = (const float*)d_in[22];
  const float* ln_b       = (const float*)d_in[23];
  float* out = (float*)d_out;

  float* ws_f = (float*)d_ws;
  // workspace (float units), lifetime-reuse; peak ~118.6 MB
  unsigned short* xbp  = (unsigned short*)ws_f;          // [8][66][66][64] bf16
  float*          xm   = ws_f;                           // T*256 f
  unsigned short* ybf  = (unsigned short*)ws_f;          // T*256 bf16
  float*          xdb  = ws_f + 4194304;                 // T*40 f
  float*          Sbuf = ws_f + 5505024;                 // B*NC*256 f
  float*          outs = ws_f + 4194304;                 // T*128 f (after xdb dead)
  float*          zb   = ws_f + 8388608;
  float*          xssm = ws_f + 16777216;
  unsigned short* h1p  = (unsigned short*)(ws_f + 25165824);  // [8][66][66][128]
  unsigned short* seqb = (unsigned short*)(ws_f + 27396096);  // [T][128]
  float*          Qbuf = ws_f + 25165824;                     // B*NC*256*16 f
  unsigned short* wb1  = (unsigned short*)(ws_f + 29493248);
  unsigned short* wb2  = (unsigned short*)(ws_f + 29530112);
  unsigned short* win  = (unsigned short*)(ws_f + 29603840);
  unsigned short* wout = (unsigned short*)(ws_f + 29636608);

  // zero padded borders (whole buffers; interior overwritten next)
  hipMemsetAsync(xbp, 0, (size_t)8 * 66 * 66 * 64 * 2, stream);
  hipMemsetAsync(h1p, 0, (size_t)8 * 66 * 66 * 128 * 2, stream);

  // pre-passes
  nchw2nhwc_bf16<<<512, 256, 0, stream>>>(x, xbp);
  convw_prep<64><<<(73728 + 255) / 256, 256, 0, stream>>>(conv1_w, wb1);
  convw_prep<128><<<(147456 + 255) / 256, 256, 0, stream>>>(conv2_w, wb2);
  f32_to_bf16<<<256, 256, 0, stream>>>(in_proj_w, win, 65536);
  f32_to_bf16<<<128, 256, 0, stream>>>(out_proj_w, wout, 32768);

  // convs (LDS-staged MFMA implicit GEMM on padded NHWC)
  conv_mfma<64, 1><<<dim3(64, 8), 256, 0, stream>>>(
      xbp, wb1, conv1_b, bn1_g, bn1_b, bn1_m, bn1_v, h1p);
  conv_mfma<128, 0><<<dim3(64, 8), 256, 0, stream>>>(
      h1p, wb2, conv2_b, bn2_g, bn2_b, bn2_m, bn2_v, seqb);

  // in_proj (one GEMM, N=512 -> xm | z)
  gemm_mfma<128, 0><<<dim3(512, 4), 256, 0, stream>>>(seqb, win, xm, zb);

  conv1d_silu<<<2048, 256, 0, stream>>>(xm, conv1d_w, conv1d_b, xssm);
  gemm_nt<<<dim3(512, 1), 256, 0, stream>>>(xssm, x_proj_w, xdb, 32768, 40, 256);

  scan_pass1<<<dim3(NC, 8), 256, 0, stream>>>(
      xssm, xdb, dt_proj_w, dt_proj_b, A_log, Qbuf, Sbuf);
  scan_combine<<<128, 256, 0, stream>>>(Qbuf, Sbuf, A_log);
  scan_pass2<<<dim3(NC, 8), 256, 0, stream>>>(
      xssm, xdb, zb, dt_proj_w, dt_proj_b, A_log, Dp, Qbuf, ybf);

  // out_proj (MFMA) + LN/transpose
  gemm_mfma<256, 1><<<dim3(512, 1), 256, 0, stream>>>(ybf, wout, outs, nullptr);
  ln_transpose<<<512, 256, 0, stream>>>(outs, ln_g, ln_b, out);
}

// Round 8
// 218.926 us; speedup vs baseline: 1.3669x; 1.0703x over previous
//
#include <hip/hip_runtime.h>
#include <hip/hip_bf16.h>

// ---------------------------------------------------------------------------
// MambaConvBlock fused pipeline. Round 8: bf16 intermediates (xssm, z),
// x_proj -> MFMA, scan exp2 + split-y + prefetch.
// Sizes: B=8, CIN=64, COUT=128, H=W=64, L=4096, T=32768,
//        DINNER=256, DSTATE=16, DTRANK=8, DCONV=4.
// ---------------------------------------------------------------------------

typedef __attribute__((ext_vector_type(8))) short bf16x8;
typedef __attribute__((ext_vector_type(4))) float f32x4;

#define DEV __device__ __forceinline__

constexpr float LOG2E = 1.44269504088896f;

DEV float siluf(float v) {
  return v * __builtin_amdgcn_rcpf(1.f + __expf(-v));
}

DEV unsigned short f2bf(float f) {
  __hip_bfloat16 h = __float2bfloat16(f);
  return *reinterpret_cast<unsigned short*>(&h);
}

DEV float bf2f(unsigned short u) {
  unsigned int x = (unsigned int)u << 16;
  return __builtin_bit_cast(float, x);
}

// async global->LDS, 16B per lane; lds dest = uniform base + lane*16
DEV void gll16(const void* g, void* l) {
  __builtin_amdgcn_global_load_lds(
      (const __attribute__((address_space(1))) void*)g,
      (__attribute__((address_space(3))) void*)l, 16, 0, 0);
}

constexpr int NC = 128;  // scan chunks per batch
constexpr int CL = 32;   // scan chunk length

// ---------------- pre-pass: NCHW fp32 -> padded NHWC bf16 -------------------
__global__ __launch_bounds__(256) void nchw2nhwc_bf16(
    const float* __restrict__ X, unsigned short* __restrict__ Xb)
{
  __shared__ float t[64][65];
  const int by = blockIdx.x;            // b*64 + y
  const int b = by >> 6, y = by & 63;
  const int tid = threadIdx.x;
  for (int i = tid; i < 4096; i += 256) {
    int c = i >> 6, xx = i & 63;
    t[c][xx] = X[(((size_t)b * 64 + c) * 64 + y) * 64 + xx];
  }
  __syncthreads();
  for (int i = tid; i < 4096; i += 256) {
    int xx = i >> 6, c = i & 63;
    Xb[(((size_t)(b * 66 + y + 1) * 66) + xx + 1) * 64 + c] = f2bf(t[c][xx]);
  }
}

// ---------------- pre-pass: conv weights -> bf16 [co][dy][dx][ci] -----------
template<int CI>
__global__ void convw_prep(const float* __restrict__ W,
                           unsigned short* __restrict__ Wb)
{
  int idx = blockIdx.x * 256 + threadIdx.x;
  if (idx >= 128 * 9 * CI) return;
  int co = idx / (9 * CI), r = idx % (9 * CI);
  int t = r / CI, ci = r % CI;
  Wb[idx] = f2bf(W[((size_t)co * CI + ci) * 9 + t]);
}

__global__ void f32_to_bf16(const float* __restrict__ A,
                            unsigned short* __restrict__ B, int n)
{
  int i = blockIdx.x * 256 + threadIdx.x;
  if (i < n) B[i] = f2bf(A[i]);
}

// x_proj weights: (40,256) f32 -> padded (128,256) bf16, zero rows >=40
__global__ void xprojw_prep(const float* __restrict__ W,
                            unsigned short* __restrict__ Wb)
{
  int idx = blockIdx.x * 256 + threadIdx.x;   // 128*256
  if (idx >= 128 * 256) return;
  int r = idx >> 8, c = idx & 255;
  Wb[idx] = (r < 40) ? f2bf(W[r * 256 + c]) : (unsigned short)0;
}

// ---------------- conv3x3 + BN + ReLU: LDS-staged implicit GEMM -------------
template<int CI, int PADOUT>
__global__ __launch_bounds__(256) void conv_mfma(
    const unsigned short* __restrict__ Xp,   // [b][66][66][CI] bf16 padded
    const unsigned short* __restrict__ Wb,   // [128][9*CI]     bf16
    const float* __restrict__ bc,
    const float* __restrict__ bg, const float* __restrict__ bb,
    const float* __restrict__ bm, const float* __restrict__ bv,
    unsigned short* __restrict__ Y)
{
  constexpr int KC  = 3 * CI / 64;   // chunks per dy
  constexpr int NCH = 3 * KC;        // total chunks
  __shared__ bf16x8 ldsA[2][512];    // 2 x 8KB

  const int lane = threadIdx.x & 63;
  const int wid  = threadIdx.x >> 6;
  const int n0 = wid * 32;
  const int y = blockIdx.x, b = blockIdx.y;
  const int lr = lane & 15, kq = lane >> 4, lk = kq * 8;

  auto stage = [&](int buf, int c) {
    const int dy = c / KC, kc = c - dy * KC;
    const unsigned short* g = Xp
        + (size_t)((b * 66 + y + dy) * 66) * CI
        + (size_t)lane * CI + kc * 64 + wid * 16;
    gll16(g,     &ldsA[buf][(wid * 2) * 64]);
    gll16(g + 8, &ldsA[buf][(wid * 2 + 1) * 64]);
  };

  f32x4 acc[4][2];
  #pragma unroll
  for (int i = 0; i < 4; ++i)
    #pragma unroll
    for (int j = 0; j < 2; ++j) acc[i][j] = f32x4{0.f, 0.f, 0.f, 0.f};

  stage(0, 0);
  __syncthreads();

  #pragma unroll
  for (int c = 0; c < NCH; ++c) {
    if (c + 1 < NCH) stage((c + 1) & 1, c + 1);
    const int dy = c / KC, kc = c - dy * KC;
    bf16x8 bw[2][2];
    #pragma unroll
    for (int t = 0; t < 2; ++t)
      #pragma unroll
      for (int nf = 0; nf < 2; ++nf)
        bw[t][nf] = *reinterpret_cast<const bf16x8*>(
            Wb + (size_t)(n0 + nf * 16 + lr) * (9 * CI)
               + dy * 3 * CI + kc * 64 + t * 32 + lk);
    const bf16x8* Ab = ldsA[c & 1];
    #pragma unroll
    for (int t = 0; t < 2; ++t)
      #pragma unroll
      for (int mf = 0; mf < 4; ++mf) {
        bf16x8 afr = Ab[(t * 4 + kq) * 64 + mf * 16 + lr];
        #pragma unroll
        for (int nf = 0; nf < 2; ++nf)
          acc[mf][nf] = __builtin_amdgcn_mfma_f32_16x16x32_bf16(
              afr, bw[t][nf], acc[mf][nf], 0, 0, 0);
      }
    __syncthreads();
  }

  #pragma unroll
  for (int nf = 0; nf < 2; ++nf) {
    int n = n0 + nf * 16 + lr;
    float aS = bg[n] * rsqrtf(bv[n] + 1e-5f);
    float aB = (bc[n] - bm[n]) * aS + bb[n];
    #pragma unroll
    for (int mf = 0; mf < 4; ++mf)
      #pragma unroll
      for (int i = 0; i < 4; ++i) {
        int m = mf * 16 + kq * 4 + i;
        float v = fmaxf(acc[mf][nf][i] * aS + aB, 0.f);
        if (PADOUT)
          Y[((size_t)(b * 66 + y + 1) * 66 + m + 1) * 128 + n] = f2bf(v);
        else
          Y[((size_t)(b * 4096 + y * 64 + m)) * 128 + n] = f2bf(v);
      }
  }
}

// ---------------- bf16 MFMA GEMM, LDS-staged A ------------------------------
// EPI 0: in_proj  -> C0 fp32 [m][256] (xm), C1b bf16 [m][256] (z)
// EPI 1: out_proj -> C0 fp32 [m][128]
// EPI 2: x_proj   -> C0 fp32 [m][40], mask n<40
template<int KDIM, int EPI>
__global__ __launch_bounds__(256) void gemm_mfma(
    const unsigned short* __restrict__ A,   // [M][KDIM] bf16
    const unsigned short* __restrict__ Wn,  // [N][KDIM] bf16
    float* __restrict__ C0, unsigned short* __restrict__ C1b)
{
  constexpr int NCH = KDIM / 64;
  __shared__ bf16x8 ldsA[2][512];

  const int lane = threadIdx.x & 63;
  const int wid  = threadIdx.x >> 6;
  const int m0 = blockIdx.x * 64;
  const int n0 = blockIdx.y * 128 + wid * 32;
  const int lr = lane & 15, kq = lane >> 4, lk = kq * 8;

  bf16x8 bw[NCH][2][2];
  #pragma unroll
  for (int c = 0; c < NCH; ++c)
    #pragma unroll
    for (int t = 0; t < 2; ++t)
      #pragma unroll
      for (int nf = 0; nf < 2; ++nf)
        bw[c][t][nf] = *reinterpret_cast<const bf16x8*>(
            Wn + (size_t)(n0 + nf * 16 + lr) * KDIM + c * 64 + t * 32 + lk);

  auto stage = [&](int buf, int c) {
    const unsigned short* g = A + (size_t)(m0 + lane) * KDIM + c * 64 + wid * 16;
    gll16(g,     &ldsA[buf][(wid * 2) * 64]);
    gll16(g + 8, &ldsA[buf][(wid * 2 + 1) * 64]);
  };

  f32x4 acc[4][2];
  #pragma unroll
  for (int i = 0; i < 4; ++i)
    #pragma unroll
    for (int j = 0; j < 2; ++j) acc[i][j] = f32x4{0.f, 0.f, 0.f, 0.f};

  stage(0, 0);
  __syncthreads();

  #pragma unroll
  for (int c = 0; c < NCH; ++c) {
    if (c + 1 < NCH) stage((c + 1) & 1, c + 1);
    const bf16x8* Ab = ldsA[c & 1];
    #pragma unroll
    for (int t = 0; t < 2; ++t)
      #pragma unroll
      for (int mf = 0; mf < 4; ++mf) {
        bf16x8 afr = Ab[(t * 4 + kq) * 64 + mf * 16 + lr];
        #pragma unroll
        for (int nf = 0; nf < 2; ++nf)
          acc[mf][nf] = __builtin_amdgcn_mfma_f32_16x16x32_bf16(
              afr, bw[c][t][nf], acc[mf][nf], 0, 0, 0);
      }
    __syncthreads();
  }

  #pragma unroll
  for (int nf = 0; nf < 2; ++nf) {
    int n = n0 + nf * 16 + lr;
    #pragma unroll
    for (int mf = 0; mf < 4; ++mf)
      #pragma unroll
      for (int i = 0; i < 4; ++i) {
        int m = m0 + mf * 16 + kq * 4 + i;
        float v = acc[mf][nf][i];
        if (EPI == 0) {
          if (n < 256) C0[(size_t)m * 256 + n] = v;
          else         C1b[(size_t)m * 256 + (n - 256)] = f2bf(v);
        } else if (EPI == 1) {
          C0[(size_t)m * 128 + n] = v;
        } else {
          if (n < 40) C0[(size_t)m * 40 + n] = v;
        }
      }
  }
}

// ---------------- depthwise causal conv1d (DCONV=4) + silu ------------------
// reads xm fp32, writes xssm bf16
__global__ __launch_bounds__(256) void conv1d_silu(
    const float* __restrict__ xm,        // (T,256) f32
    const float* __restrict__ w,         // (256,4)
    const float* __restrict__ bias,      // (256)
    unsigned short* __restrict__ out)    // (T,256) bf16
{
  __shared__ float ws4[4][256];
  __shared__ float bsh[256];
  for (int i = threadIdx.x; i < 1024; i += 256)
    ws4[i >> 8][i & 255] = w[(i & 255) * 4 + (i >> 8)];
  bsh[threadIdx.x] = bias[threadIdx.x];
  __syncthreads();
  const int total = 8 * 4096 * 64;
  for (int idx = blockIdx.x * 256 + threadIdx.x; idx < total;
       idx += gridDim.x * 256) {
    int d4 = idx & 63, t = idx >> 6, l = t & 4095;
    int d = d4 * 4;
    float4 acc = *reinterpret_cast<const float4*>(&bsh[d]);
    #pragma unroll
    for (int j = 0; j < 4; ++j) {
      if (l - 3 + j >= 0) {
        float4 xv = *reinterpret_cast<const float4*>(&xm[(size_t)(t - 3 + j) * 256 + d]);
        float4 wv = *reinterpret_cast<const float4*>(&ws4[j][d]);
        acc.x = fmaf(xv.x, wv.x, acc.x);
        acc.y = fmaf(xv.y, wv.y, acc.y);
        acc.z = fmaf(xv.z, wv.z, acc.z);
        acc.w = fmaf(xv.w, wv.w, acc.w);
      }
    }
    ushort4 o;
    o.x = f2bf(siluf(acc.x)); o.y = f2bf(siluf(acc.y));
    o.z = f2bf(siluf(acc.z)); o.w = f2bf(siluf(acc.w));
    *reinterpret_cast<ushort4*>(&out[(size_t)t * 256 + d]) = o;
  }
}

// ---------------- chunked selective scan ------------------------------------
__global__ __launch_bounds__(256) void scan_pass1(
    const unsigned short* __restrict__ xssm, const float* __restrict__ xdb,
    const float* __restrict__ dtw, const float* __restrict__ dtb,
    const float* __restrict__ A_log,
    float* __restrict__ Q, float* __restrict__ S)
{
  __shared__ __align__(16) float sh[CL][40];
  const int c = blockIdx.x, b = blockIdx.y;
  const int d = threadIdx.x;
  {
    const float4* src = reinterpret_cast<const float4*>(
        &xdb[((size_t)b * 4096 + c * CL) * 40]);
    float4* dst = reinterpret_cast<float4*>(&sh[0][0]);
    for (int i = threadIdx.x; i < CL * 10; i += 256) dst[i] = src[i];
  }
  float4 w0 = *reinterpret_cast<const float4*>(&dtw[d * 8]);
  float4 w1 = *reinterpret_cast<const float4*>(&dtw[d * 8 + 4]);
  const float bdt = dtb[d];
  float An2[16], h[16];
  #pragma unroll
  for (int s = 0; s < 16; ++s) {
    An2[s] = -__expf(A_log[d * 16 + s]) * LOG2E;
    h[s] = 0.f;
  }
  __syncthreads();

  float sdt = 0.f;
  const size_t xbase = ((size_t)b * 4096 + (size_t)c * CL) * 256 + d;
  unsigned short xu = xssm[xbase];
  for (int l = 0; l < CL; ++l) {
    unsigned short xun = (l + 1 < CL) ? xssm[xbase + (size_t)(l + 1) * 256]
                                      : (unsigned short)0;
    const float4* row = reinterpret_cast<const float4*>(sh[l]);
    float4 r0 = row[0], r1 = row[1];
    float acc = bdt;
    acc = fmaf(r0.x, w0.x, acc); acc = fmaf(r0.y, w0.y, acc);
    acc = fmaf(r0.z, w0.z, acc); acc = fmaf(r0.w, w0.w, acc);
    acc = fmaf(r1.x, w1.x, acc); acc = fmaf(r1.y, w1.y, acc);
    acc = fmaf(r1.z, w1.z, acc); acc = fmaf(r1.w, w1.w, acc);
    float dt = (acc > 20.f) ? acc : __logf(1.f + __expf(acc));
    sdt += dt;
    float dtx = dt * bf2f(xu);
    #pragma unroll
    for (int q = 0; q < 4; ++q) {
      float4 Bq = row[2 + q];
      float bb4[4] = {Bq.x, Bq.y, Bq.z, Bq.w};
      #pragma unroll
      for (int j = 0; j < 4; ++j) {
        int s = q * 4 + j;
        float dA = __builtin_amdgcn_exp2f(dt * An2[s]);
        h[s] = fmaf(dA, h[s], dtx * bb4[j]);
      }
    }
    xu = xun;
  }
  float4* q4 = reinterpret_cast<float4*>(
      &Q[(((size_t)b * NC + c) * 256 + d) * 16]);
  #pragma unroll
  for (int q = 0; q < 4; ++q)
    q4[q] = make_float4(h[q * 4], h[q * 4 + 1], h[q * 4 + 2], h[q * 4 + 3]);
  S[((size_t)b * NC + c) * 256 + d] = sdt;
}

__global__ __launch_bounds__(256) void scan_combine(
    float* __restrict__ Q, const float* __restrict__ S,
    const float* __restrict__ A_log)
{
  int g = blockIdx.x * 256 + threadIdx.x;   // 32768 total
  int b = g >> 12, d = (g >> 4) & 255, s = g & 15;
  float Aneg = -__expf(A_log[d * 16 + s]);
  float h = 0.f;
  for (int c = 0; c < NC; ++c) {
    size_t qi = (((size_t)b * NC + c) * 256 + d) * 16 + s;
    float q  = Q[qi];
    float sd = S[((size_t)b * NC + c) * 256 + d];
    Q[qi] = h;
    h = fmaf(__expf(Aneg * sd), h, q);
  }
}

__global__ __launch_bounds__(256) void scan_pass2(
    const unsigned short* __restrict__ xssm, const float* __restrict__ xdb,
    const unsigned short* __restrict__ zb,
    const float* __restrict__ dtw, const float* __restrict__ dtb,
    const float* __restrict__ A_log, const float* __restrict__ Dp,
    const float* __restrict__ Hstart, unsigned short* __restrict__ ybf)
{
  __shared__ __align__(16) float sh[CL][40];
  const int c = blockIdx.x, b = blockIdx.y;
  const int d = threadIdx.x;
  {
    const float4* src = reinterpret_cast<const float4*>(
        &xdb[((size_t)b * 4096 + c * CL) * 40]);
    float4* dst = reinterpret_cast<float4*>(&sh[0][0]);
    for (int i = threadIdx.x; i < CL * 10; i += 256) dst[i] = src[i];
  }
  float4 w0 = *reinterpret_cast<const float4*>(&dtw[d * 8]);
  float4 w1 = *reinterpret_cast<const float4*>(&dtw[d * 8 + 4]);
  const float bdt = dtb[d];
  const float Dd = Dp[d];
  float An2[16], h[16];
  const float4* hs4 = reinterpret_cast<const float4*>(
      &Hstart[(((size_t)b * NC + c) * 256 + d) * 16]);
  #pragma unroll
  for (int q = 0; q < 4; ++q) {
    float4 hv = hs4[q];
    h[q * 4 + 0] = hv.x; h[q * 4 + 1] = hv.y;
    h[q * 4 + 2] = hv.z; h[q * 4 + 3] = hv.w;
  }
  #pragma unroll
  for (int s = 0; s < 16; ++s) An2[s] = -__expf(A_log[d * 16 + s]) * LOG2E;
  __syncthreads();

  const size_t xbase = ((size_t)b * 4096 + (size_t)c * CL) * 256 + d;
  unsigned short xu = xssm[xbase], zu = zb[xbase];
  for (int l = 0; l < CL; ++l) {
    unsigned short xun = 0, zun = 0;
    if (l + 1 < CL) {
      xun = xssm[xbase + (size_t)(l + 1) * 256];
      zun = zb[xbase + (size_t)(l + 1) * 256];
    }
    const float4* row = reinterpret_cast<const float4*>(sh[l]);
    float4 r0 = row[0], r1 = row[1];
    float acc = bdt;
    acc = fmaf(r0.x, w0.x, acc); acc = fmaf(r0.y, w0.y, acc);
    acc = fmaf(r0.z, w0.z, acc); acc = fmaf(r0.w, w0.w, acc);
    acc = fmaf(r1.x, w1.x, acc); acc = fmaf(r1.y, w1.y, acc);
    acc = fmaf(r1.z, w1.z, acc); acc = fmaf(r1.w, w1.w, acc);
    float dt = (acc > 20.f) ? acc : __logf(1.f + __expf(acc));
    float xv = bf2f(xu);
    float dtx = dt * xv;
    float yq[4] = {0.f, 0.f, 0.f, 0.f};
    #pragma unroll
    for (int q = 0; q < 4; ++q) {
      float4 Bq = row[2 + q], Cq = row[6 + q];
      float bb4[4] = {Bq.x, Bq.y, Bq.z, Bq.w};
      float cc4[4] = {Cq.x, Cq.y, Cq.z, Cq.w};
      #pragma unroll
      for (int j = 0; j < 4; ++j) {
        int s = q * 4 + j;
        float dA = __builtin_amdgcn_exp2f(dt * An2[s]);
        h[s] = fmaf(dA, h[s], dtx * bb4[j]);
        yq[q] = fmaf(h[s], cc4[j], yq[q]);
      }
    }
    float y = (yq[0] + yq[1]) + (yq[2] + yq[3]);
    y = (y + Dd * xv) * siluf(bf2f(zu));
    ybf[xbase + (size_t)l * 256] = f2bf(y);
    xu = xun; zu = zun;
  }
}

// ---------------- LayerNorm(128) + transpose to NCHW ------------------------
__global__ __launch_bounds__(256) void ln_transpose(
    const float* __restrict__ X,
    const float* __restrict__ g, const float* __restrict__ b,
    float* __restrict__ out)
{
  __shared__ float buf[64][129];
  const int t0 = blockIdx.x * 64;
  const int bb = t0 >> 12, l0 = t0 & 4095;
  const int tid = threadIdx.x;
  for (int idx = tid; idx < 64 * 128; idx += 256)
    buf[idx >> 7][idx & 127] = X[(size_t)t0 * 128 + idx];
  __syncthreads();
  const int tt = tid >> 2, q = tid & 3;
  float s = 0.f, sq = 0.f;
  #pragma unroll
  for (int i = 0; i < 32; ++i) {
    float v = buf[tt][q * 32 + i];
    s += v; sq += v * v;
  }
  s  += __shfl_xor(s, 1);  s  += __shfl_xor(s, 2);
  sq += __shfl_xor(sq, 1); sq += __shfl_xor(sq, 2);
  float mu = s * (1.f / 128.f);
  float var = sq * (1.f / 128.f) - mu * mu;
  float rstd = rsqrtf(fmaxf(var, 0.f) + 1e-5f);
  #pragma unroll
  for (int i = 0; i < 32; ++i) {
    int c = q * 32 + i;
    buf[tt][c] = (buf[tt][c] - mu) * rstd * g[c] + b[c];
  }
  __syncthreads();
  for (int idx = tid; idx < 64 * 128; idx += 256) {
    int c = idx >> 6, t2 = idx & 63;
    out[((size_t)bb * 128 + c) * 4096 + l0 + t2] = buf[t2][c];
  }
}

// ---------------------------------------------------------------------------
extern "C" void kernel_launch(void* const* d_in, const int* in_sizes, int n_in,
                              void* d_out, int out_size, void* d_ws, size_t ws_size,
                              hipStream_t stream) {
  const float* x        = (const float*)d_in[0];
  const float* conv1_w  = (const float*)d_in[1];
  const float* conv1_b  = (const float*)d_in[2];
  const float* bn1_g    = (const float*)d_in[3];
  const float* bn1_b    = (const float*)d_in[4];
  const float* bn1_m    = (const float*)d_in[5];
  const float* bn1_v    = (const float*)d_in[6];
  const float* conv2_w  = (const float*)d_in[7];
  const float* conv2_b  = (const float*)d_in[8];
  const float* bn2_g    = (const float*)d_in[9];
  const float* bn2_b    = (const float*)d_in[10];
  const float* bn2_m    = (const float*)d_in[11];
  const float* bn2_v    = (const float*)d_in[12];
  const float* in_proj_w  = (const float*)d_in[13];  // (512,128)
  const float* conv1d_w   = (const float*)d_in[14];  // (256,1,4)
  const float* conv1d_b   = (const float*)d_in[15];
  const float* x_proj_w   = (const float*)d_in[16];  // (40,256)
  const float* dt_proj_w  = (const float*)d_in[17];  // (256,8)
  const float* dt_proj_b  = (const float*)d_in[18];
  const float* A_log      = (const float*)d_in[19];  // (256,16)
  const float* Dp         = (const float*)d_in[20];  // (256)
  const float* out_proj_w = (const float*)d_in[21];  // (128,256)
  const float* ln_g       = (const float*)d_in[22];
  const float* ln_b       = (const float*)d_in[23];
  float* out = (float*)d_out;

  float* ws_f = (float*)d_ws;
  // workspace (float units), lifetime-reuse; peak ~118.7 MB
  unsigned short* xbp  = (unsigned short*)ws_f;          // [8][66][66][64] bf16
  float*          xm   = ws_f;                           // T*256 f32
  unsigned short* ybf  = (unsigned short*)ws_f;          // T*256 bf16 [0,4194304)
  float*          xdb  = ws_f + 4194304;                 // T*40 f
  float*          Sbuf = ws_f + 5505024;                 // B*NC*256 f
  float*          outs = ws_f + 4194304;                 // T*128 f (after xdb dead)
  unsigned short* zbu  = (unsigned short*)(ws_f + 8388608);   // T*256 bf16
  unsigned short* xsu  = (unsigned short*)(ws_f + 16777216);  // T*256 bf16
  unsigned short* h1p  = (unsigned short*)(ws_f + 25165824);  // [8][66][66][128]
  unsigned short* seqb = (unsigned short*)(ws_f + 27396096);  // [T][128]
  float*          Qbuf = ws_f + 25165824;                     // B*NC*256*16 f
  unsigned short* wb1  = (unsigned short*)(ws_f + 29493248);
  unsigned short* wb2  = (unsigned short*)(ws_f + 29530112);
  unsigned short* win  = (unsigned short*)(ws_f + 29603840);
  unsigned short* wout = (unsigned short*)(ws_f + 29636608);
  unsigned short* xpwb = (unsigned short*)(ws_f + 29652992);  // [128][256] bf16

  // zero padded borders (whole buffers; interior overwritten next)
  hipMemsetAsync(xbp, 0, (size_t)8 * 66 * 66 * 64 * 2, stream);
  hipMemsetAsync(h1p, 0, (size_t)8 * 66 * 66 * 128 * 2, stream);

  // pre-passes
  nchw2nhwc_bf16<<<512, 256, 0, stream>>>(x, xbp);
  convw_prep<64><<<(73728 + 255) / 256, 256, 0, stream>>>(conv1_w, wb1);
  convw_prep<128><<<(147456 + 255) / 256, 256, 0, stream>>>(conv2_w, wb2);
  f32_to_bf16<<<256, 256, 0, stream>>>(in_proj_w, win, 65536);
  f32_to_bf16<<<128, 256, 0, stream>>>(out_proj_w, wout, 32768);
  xprojw_prep<<<128, 256, 0, stream>>>(x_proj_w, xpwb);

  // convs (LDS-staged MFMA implicit GEMM on padded NHWC)
  conv_mfma<64, 1><<<dim3(64, 8), 256, 0, stream>>>(
      xbp, wb1, conv1_b, bn1_g, bn1_b, bn1_m, bn1_v, h1p);
  conv_mfma<128, 0><<<dim3(64, 8), 256, 0, stream>>>(
      h1p, wb2, conv2_b, bn2_g, bn2_b, bn2_m, bn2_v, seqb);

  // in_proj (one GEMM, N=512 -> xm fp32 | z bf16)
  gemm_mfma<128, 0><<<dim3(512, 4), 256, 0, stream>>>(seqb, win, xm, zbu);

  // conv1d + silu -> xssm bf16
  conv1d_silu<<<2048, 256, 0, stream>>>(xm, conv1d_w, conv1d_b, xsu);

  // x_proj (MFMA, padded N=128, mask n<40) -> xdb fp32
  gemm_mfma<256, 2><<<dim3(512, 1), 256, 0, stream>>>(xsu, xpwb, xdb, nullptr);

  scan_pass1<<<dim3(NC, 8), 256, 0, stream>>>(
      xsu, xdb, dt_proj_w, dt_proj_b, A_log, Qbuf, Sbuf);
  scan_combine<<<128, 256, 0, stream>>>(Qbuf, Sbuf, A_log);
  scan_pass2<<<dim3(NC, 8), 256, 0, stream>>>(
      xsu, xdb, zbu, dt_proj_w, dt_proj_b, A_log, Dp, Qbuf, ybf);

  // out_proj (MFMA) + LN/transpose
  gemm_mfma<256, 1><<<dim3(512, 1), 256, 0, stream>>>(ybf, wout, outs, nullptr);
  ln_transpose<<<512, 256, 0, stream>>>(outs, ln_g, ln_b, out);
}

// Round 9
// 218.487 us; speedup vs baseline: 1.3696x; 1.0020x over previous
//
#include <hip/hip_runtime.h>
#include <hip/hip_bf16.h>

// ---------------------------------------------------------------------------
// MambaConvBlock fused pipeline. Round 9: scan NC=256/CL=16 (8 blk/CU),
// bf16 Q + xm, An2 table, merged prep, prefetched combine.
// Sizes: B=8, CIN=64, COUT=128, H=W=64, L=4096, T=32768,
//        DINNER=256, DSTATE=16, DTRANK=8, DCONV=4.
// ---------------------------------------------------------------------------

typedef __attribute__((ext_vector_type(8))) short bf16x8;
typedef __attribute__((ext_vector_type(4))) float f32x4;

#define DEV __device__ __forceinline__

constexpr float LOG2E = 1.44269504088896f;

DEV float siluf(float v) {
  return v * __builtin_amdgcn_rcpf(1.f + __expf(-v));
}

DEV unsigned short f2bf(float f) {
  __hip_bfloat16 h = __float2bfloat16(f);
  return *reinterpret_cast<unsigned short*>(&h);
}

DEV float bf2f(unsigned short u) {
  unsigned int x = (unsigned int)u << 16;
  return __builtin_bit_cast(float, x);
}

// async global->LDS, 16B per lane; lds dest = uniform base + lane*16
DEV void gll16(const void* g, void* l) {
  __builtin_amdgcn_global_load_lds(
      (const __attribute__((address_space(1))) void*)g,
      (__attribute__((address_space(3))) void*)l, 16, 0, 0);
}

constexpr int NC = 256;  // scan chunks per batch
constexpr int CL = 16;   // scan chunk length

// ---------------- pre-pass: NCHW fp32 -> padded NHWC bf16 -------------------
__global__ __launch_bounds__(256) void nchw2nhwc_bf16(
    const float* __restrict__ X, unsigned short* __restrict__ Xb)
{
  __shared__ float t[64][65];
  const int by = blockIdx.x;            // b*64 + y
  const int b = by >> 6, y = by & 63;
  const int tid = threadIdx.x;
  for (int i = tid; i < 4096; i += 256) {
    int c = i >> 6, xx = i & 63;
    t[c][xx] = X[(((size_t)b * 64 + c) * 64 + y) * 64 + xx];
  }
  __syncthreads();
  for (int i = tid; i < 4096; i += 256) {
    int xx = i >> 6, c = i & 63;
    Xb[(((size_t)(b * 66 + y + 1) * 66) + xx + 1) * 64 + c] = f2bf(t[c][xx]);
  }
}

// ---------------- merged prep: all weights + An2 table ----------------------
__global__ __launch_bounds__(256) void prep_all(
    const float* __restrict__ conv1_w, const float* __restrict__ conv2_w,
    const float* __restrict__ in_proj_w, const float* __restrict__ out_proj_w,
    const float* __restrict__ x_proj_w, const float* __restrict__ A_log,
    unsigned short* __restrict__ wb1, unsigned short* __restrict__ wb2,
    unsigned short* __restrict__ win, unsigned short* __restrict__ wout,
    unsigned short* __restrict__ xpwb, float* __restrict__ An2f)
{
  int idx = blockIdx.x * 256 + threadIdx.x;
  if (idx < 73728) {                       // conv1 w: [co][tap][ci], CI=64
    int co = idx / 576, r = idx % 576, t = r >> 6, ci = r & 63;
    wb1[idx] = f2bf(conv1_w[((size_t)co * 64 + ci) * 9 + t]);
  } else if (idx < 221184) {               // conv2 w: CI=128
    int i = idx - 73728;
    int co = i / 1152, r = i % 1152, t = r >> 7, ci = r & 127;
    wb2[i] = f2bf(conv2_w[((size_t)co * 128 + ci) * 9 + t]);
  } else if (idx < 286720) {               // in_proj (512,128)
    int i = idx - 221184; win[i] = f2bf(in_proj_w[i]);
  } else if (idx < 319488) {               // out_proj (128,256)
    int i = idx - 286720; wout[i] = f2bf(out_proj_w[i]);
  } else if (idx < 352256) {               // x_proj padded (128,256)
    int i = idx - 319488; int r = i >> 8, c = i & 255;
    xpwb[i] = (r < 40) ? f2bf(x_proj_w[r * 256 + c]) : (unsigned short)0;
  } else if (idx < 356352) {               // An2 = -exp(A_log)*log2e
    int i = idx - 352256;
    An2f[i] = -__expf(A_log[i]) * LOG2E;
  }
}

// ---------------- conv3x3 + BN + ReLU: LDS-staged implicit GEMM -------------
template<int CI, int PADOUT>
__global__ __launch_bounds__(256) void conv_mfma(
    const unsigned short* __restrict__ Xp,   // [b][66][66][CI] bf16 padded
    const unsigned short* __restrict__ Wb,   // [128][9*CI]     bf16
    const float* __restrict__ bc,
    const float* __restrict__ bg, const float* __restrict__ bb,
    const float* __restrict__ bm, const float* __restrict__ bv,
    unsigned short* __restrict__ Y)
{
  constexpr int KC  = 3 * CI / 64;   // chunks per dy
  constexpr int NCH = 3 * KC;        // total chunks
  __shared__ bf16x8 ldsA[2][512];    // 2 x 8KB

  const int lane = threadIdx.x & 63;
  const int wid  = threadIdx.x >> 6;
  const int n0 = wid * 32;
  const int y = blockIdx.x, b = blockIdx.y;
  const int lr = lane & 15, kq = lane >> 4, lk = kq * 8;

  auto stage = [&](int buf, int c) {
    const int dy = c / KC, kc = c - dy * KC;
    const unsigned short* g = Xp
        + (size_t)((b * 66 + y + dy) * 66) * CI
        + (size_t)lane * CI + kc * 64 + wid * 16;
    gll16(g,     &ldsA[buf][(wid * 2) * 64]);
    gll16(g + 8, &ldsA[buf][(wid * 2 + 1) * 64]);
  };

  f32x4 acc[4][2];
  #pragma unroll
  for (int i = 0; i < 4; ++i)
    #pragma unroll
    for (int j = 0; j < 2; ++j) acc[i][j] = f32x4{0.f, 0.f, 0.f, 0.f};

  stage(0, 0);
  __syncthreads();

  #pragma unroll
  for (int c = 0; c < NCH; ++c) {
    if (c + 1 < NCH) stage((c + 1) & 1, c + 1);
    const int dy = c / KC, kc = c - dy * KC;
    bf16x8 bw[2][2];
    #pragma unroll
    for (int t = 0; t < 2; ++t)
      #pragma unroll
      for (int nf = 0; nf < 2; ++nf)
        bw[t][nf] = *reinterpret_cast<const bf16x8*>(
            Wb + (size_t)(n0 + nf * 16 + lr) * (9 * CI)
               + dy * 3 * CI + kc * 64 + t * 32 + lk);
    const bf16x8* Ab = ldsA[c & 1];
    #pragma unroll
    for (int t = 0; t < 2; ++t)
      #pragma unroll
      for (int mf = 0; mf < 4; ++mf) {
        bf16x8 afr = Ab[(t * 4 + kq) * 64 + mf * 16 + lr];
        #pragma unroll
        for (int nf = 0; nf < 2; ++nf)
          acc[mf][nf] = __builtin_amdgcn_mfma_f32_16x16x32_bf16(
              afr, bw[t][nf], acc[mf][nf], 0, 0, 0);
      }
    __syncthreads();
  }

  #pragma unroll
  for (int nf = 0; nf < 2; ++nf) {
    int n = n0 + nf * 16 + lr;
    float aS = bg[n] * rsqrtf(bv[n] + 1e-5f);
    float aB = (bc[n] - bm[n]) * aS + bb[n];
    #pragma unroll
    for (int mf = 0; mf < 4; ++mf)
      #pragma unroll
      for (int i = 0; i < 4; ++i) {
        int m = mf * 16 + kq * 4 + i;
        float v = fmaxf(acc[mf][nf][i] * aS + aB, 0.f);
        if (PADOUT)
          Y[((size_t)(b * 66 + y + 1) * 66 + m + 1) * 128 + n] = f2bf(v);
        else
          Y[((size_t)(b * 4096 + y * 64 + m)) * 128 + n] = f2bf(v);
      }
  }
}

// ---------------- bf16 MFMA GEMM, LDS-staged A ------------------------------
// EPI 0: in_proj  -> Cb0 bf16 [m][256] (xm), Cb1 bf16 [m][256] (z)
// EPI 1: out_proj -> C0 fp32 [m][128]
// EPI 2: x_proj   -> C0 fp32 [m][40], mask n<40
template<int KDIM, int EPI>
__global__ __launch_bounds__(256) void gemm_mfma(
    const unsigned short* __restrict__ A,   // [M][KDIM] bf16
    const unsigned short* __restrict__ Wn,  // [N][KDIM] bf16
    float* __restrict__ C0,
    unsigned short* __restrict__ Cb0, unsigned short* __restrict__ Cb1)
{
  constexpr int NCH = KDIM / 64;
  __shared__ bf16x8 ldsA[2][512];

  const int lane = threadIdx.x & 63;
  const int wid  = threadIdx.x >> 6;
  const int m0 = blockIdx.x * 64;
  const int n0 = blockIdx.y * 128 + wid * 32;
  const int lr = lane & 15, kq = lane >> 4, lk = kq * 8;

  bf16x8 bw[NCH][2][2];
  #pragma unroll
  for (int c = 0; c < NCH; ++c)
    #pragma unroll
    for (int t = 0; t < 2; ++t)
      #pragma unroll
      for (int nf = 0; nf < 2; ++nf)
        bw[c][t][nf] = *reinterpret_cast<const bf16x8*>(
            Wn + (size_t)(n0 + nf * 16 + lr) * KDIM + c * 64 + t * 32 + lk);

  auto stage = [&](int buf, int c) {
    const unsigned short* g = A + (size_t)(m0 + lane) * KDIM + c * 64 + wid * 16;
    gll16(g,     &ldsA[buf][(wid * 2) * 64]);
    gll16(g + 8, &ldsA[buf][(wid * 2 + 1) * 64]);
  };

  f32x4 acc[4][2];
  #pragma unroll
  for (int i = 0; i < 4; ++i)
    #pragma unroll
    for (int j = 0; j < 2; ++j) acc[i][j] = f32x4{0.f, 0.f, 0.f, 0.f};

  stage(0, 0);
  __syncthreads();

  #pragma unroll
  for (int c = 0; c < NCH; ++c) {
    if (c + 1 < NCH) stage((c + 1) & 1, c + 1);
    const bf16x8* Ab = ldsA[c & 1];
    #pragma unroll
    for (int t = 0; t < 2; ++t)
      #pragma unroll
      for (int mf = 0; mf < 4; ++mf) {
        bf16x8 afr = Ab[(t * 4 + kq) * 64 + mf * 16 + lr];
        #pragma unroll
        for (int nf = 0; nf < 2; ++nf)
          acc[mf][nf] = __builtin_amdgcn_mfma_f32_16x16x32_bf16(
              afr, bw[c][t][nf], acc[mf][nf], 0, 0, 0);
      }
    __syncthreads();
  }

  #pragma unroll
  for (int nf = 0; nf < 2; ++nf) {
    int n = n0 + nf * 16 + lr;
    #pragma unroll
    for (int mf = 0; mf < 4; ++mf)
      #pragma unroll
      for (int i = 0; i < 4; ++i) {
        int m = m0 + mf * 16 + kq * 4 + i;
        float v = acc[mf][nf][i];
        if (EPI == 0) {
          if (n < 256) Cb0[(size_t)m * 256 + n] = f2bf(v);
          else         Cb1[(size_t)m * 256 + (n - 256)] = f2bf(v);
        } else if (EPI == 1) {
          C0[(size_t)m * 128 + n] = v;
        } else {
          if (n < 40) C0[(size_t)m * 40 + n] = v;
        }
      }
  }
}

// ---------------- depthwise causal conv1d (DCONV=4) + silu, bf16 ------------
__global__ __launch_bounds__(256) void conv1d_silu(
    const unsigned short* __restrict__ xm,   // (T,256) bf16
    const float* __restrict__ w,             // (256,4)
    const float* __restrict__ bias,          // (256)
    unsigned short* __restrict__ out)        // (T,256) bf16
{
  __shared__ float ws4[4][256];
  __shared__ float bsh[256];
  for (int i = threadIdx.x; i < 1024; i += 256)
    ws4[i >> 8][i & 255] = w[(i & 255) * 4 + (i >> 8)];
  bsh[threadIdx.x] = bias[threadIdx.x];
  __syncthreads();
  const int total = 32768 * 32;   // 8 channels per thread
  for (int idx = blockIdx.x * 256 + threadIdx.x; idx < total;
       idx += gridDim.x * 256) {
    int d8 = idx & 31, t = idx >> 5, l = t & 4095;
    int d = d8 * 8;
    float acc[8];
    #pragma unroll
    for (int k = 0; k < 8; ++k) acc[k] = bsh[d + k];
    #pragma unroll
    for (int j = 0; j < 4; ++j) {
      if (l - 3 + j >= 0) {
        uint4 xv = *reinterpret_cast<const uint4*>(
            &xm[(size_t)(t - 3 + j) * 256 + d]);
        const unsigned short* xs = reinterpret_cast<const unsigned short*>(&xv);
        #pragma unroll
        for (int k = 0; k < 8; ++k)
          acc[k] = fmaf(bf2f(xs[k]), ws4[j][d + k], acc[k]);
      }
    }
    unsigned int pk[4];
    #pragma unroll
    for (int k = 0; k < 4; ++k) {
      unsigned short lo = f2bf(siluf(acc[2 * k]));
      unsigned short hi = f2bf(siluf(acc[2 * k + 1]));
      pk[k] = (unsigned int)lo | ((unsigned int)hi << 16);
    }
    *reinterpret_cast<uint4*>(&out[(size_t)t * 256 + d]) =
        *reinterpret_cast<uint4*>(pk);
  }
}

// ---------------- chunked selective scan ------------------------------------
__global__ __launch_bounds__(256) void scan_pass1(
    const unsigned short* __restrict__ xssm, const float* __restrict__ xdb,
    const float* __restrict__ dtw, const float* __restrict__ dtb,
    const float* __restrict__ An2f,
    unsigned short* __restrict__ Qb, float* __restrict__ S)
{
  __shared__ __align__(16) float sh[CL][40];
  const int c = blockIdx.x, b = blockIdx.y;
  const int d = threadIdx.x;
  if (threadIdx.x < CL * 10) {
    const float4* src = reinterpret_cast<const float4*>(
        &xdb[((size_t)b * 4096 + c * CL) * 40]);
    reinterpret_cast<float4*>(&sh[0][0])[threadIdx.x] = src[threadIdx.x];
  }
  float4 w0 = *reinterpret_cast<const float4*>(&dtw[d * 8]);
  float4 w1 = *reinterpret_cast<const float4*>(&dtw[d * 8 + 4]);
  const float bdt = dtb[d];
  float An2[16], h[16];
  {
    const f32x4* a2 = reinterpret_cast<const f32x4*>(&An2f[d * 16]);
    #pragma unroll
    for (int q = 0; q < 4; ++q) {
      f32x4 v = a2[q];
      An2[q * 4 + 0] = v[0]; An2[q * 4 + 1] = v[1];
      An2[q * 4 + 2] = v[2]; An2[q * 4 + 3] = v[3];
    }
  }
  #pragma unroll
  for (int s = 0; s < 16; ++s) h[s] = 0.f;
  __syncthreads();

  float sdt = 0.f;
  const size_t xbase = ((size_t)b * 4096 + (size_t)c * CL) * 256 + d;
  unsigned short xu = xssm[xbase];
  for (int l = 0; l < CL; ++l) {
    unsigned short xun = (l + 1 < CL) ? xssm[xbase + (size_t)(l + 1) * 256]
                                      : (unsigned short)0;
    const float4* row = reinterpret_cast<const float4*>(sh[l]);
    float4 r0 = row[0], r1 = row[1];
    float acc = bdt;
    acc = fmaf(r0.x, w0.x, acc); acc = fmaf(r0.y, w0.y, acc);
    acc = fmaf(r0.z, w0.z, acc); acc = fmaf(r0.w, w0.w, acc);
    acc = fmaf(r1.x, w1.x, acc); acc = fmaf(r1.y, w1.y, acc);
    acc = fmaf(r1.z, w1.z, acc); acc = fmaf(r1.w, w1.w, acc);
    float dt = (acc > 20.f) ? acc : __logf(1.f + __expf(acc));
    sdt += dt;
    float dtx = dt * bf2f(xu);
    #pragma unroll
    for (int q = 0; q < 4; ++q) {
      float4 Bq = row[2 + q];
      float bb4[4] = {Bq.x, Bq.y, Bq.z, Bq.w};
      #pragma unroll
      for (int j = 0; j < 4; ++j) {
        int s = q * 4 + j;
        float dA = __builtin_amdgcn_exp2f(dt * An2[s]);
        h[s] = fmaf(dA, h[s], dtx * bb4[j]);
      }
    }
    xu = xun;
  }
  unsigned int pk[8];
  #pragma unroll
  for (int k = 0; k < 8; ++k)
    pk[k] = (unsigned int)f2bf(h[2 * k]) | ((unsigned int)f2bf(h[2 * k + 1]) << 16);
  uint4* qp = reinterpret_cast<uint4*>(
      &Qb[(((size_t)b * NC + c) * 256 + d) * 16]);
  qp[0] = *reinterpret_cast<uint4*>(pk);
  qp[1] = *reinterpret_cast<uint4*>(pk + 4);
  S[((size_t)b * NC + c) * 256 + d] = sdt;
}

__global__ __launch_bounds__(256) void scan_combine(
    unsigned short* __restrict__ Qb, const float* __restrict__ S,
    const float* __restrict__ An2f)
{
  int g = blockIdx.x * 256 + threadIdx.x;   // 32768 total
  int b = g >> 12, d = (g >> 4) & 255, s = g & 15;
  float An2 = An2f[d * 16 + s];
  const size_t qbase = (size_t)b * NC * 4096 + d * 16 + s;
  const size_t sbase = (size_t)b * NC * 256 + d;
  float h = 0.f;
  unsigned short qn = Qb[qbase];
  float sn = S[sbase];
  for (int c = 0; c < NC; ++c) {
    float q = bf2f(qn), sd = sn;
    if (c + 1 < NC) {
      qn = Qb[qbase + (size_t)(c + 1) * 4096];
      sn = S[sbase + (size_t)(c + 1) * 256];
    }
    Qb[qbase + (size_t)c * 4096] = f2bf(h);
    h = fmaf(__builtin_amdgcn_exp2f(An2 * sd), h, q);
  }
}

__global__ __launch_bounds__(256) void scan_pass2(
    const unsigned short* __restrict__ xssm, const float* __restrict__ xdb,
    const unsigned short* __restrict__ zb,
    const float* __restrict__ dtw, const float* __restrict__ dtb,
    const float* __restrict__ An2f, const float* __restrict__ Dp,
    const unsigned short* __restrict__ Hstart, unsigned short* __restrict__ ybf)
{
  __shared__ __align__(16) float sh[CL][40];
  const int c = blockIdx.x, b = blockIdx.y;
  const int d = threadIdx.x;
  if (threadIdx.x < CL * 10) {
    const float4* src = reinterpret_cast<const float4*>(
        &xdb[((size_t)b * 4096 + c * CL) * 40]);
    reinterpret_cast<float4*>(&sh[0][0])[threadIdx.x] = src[threadIdx.x];
  }
  float4 w0 = *reinterpret_cast<const float4*>(&dtw[d * 8]);
  float4 w1 = *reinterpret_cast<const float4*>(&dtw[d * 8 + 4]);
  const float bdt = dtb[d];
  const float Dd = Dp[d];
  float An2[16], h[16];
  {
    const f32x4* a2 = reinterpret_cast<const f32x4*>(&An2f[d * 16]);
    #pragma unroll
    for (int q = 0; q < 4; ++q) {
      f32x4 v = a2[q];
      An2[q * 4 + 0] = v[0]; An2[q * 4 + 1] = v[1];
      An2[q * 4 + 2] = v[2]; An2[q * 4 + 3] = v[3];
    }
  }
  {
    const uint4* hp = reinterpret_cast<const uint4*>(
        &Hstart[(((size_t)b * NC + c) * 256 + d) * 16]);
    uint4 h0 = hp[0], h1 = hp[1];
    const unsigned short* hs = reinterpret_cast<const unsigned short*>(&h0);
    #pragma unroll
    for (int s = 0; s < 8; ++s) h[s] = bf2f(hs[s]);
    const unsigned short* hs2 = reinterpret_cast<const unsigned short*>(&h1);
    #pragma unroll
    for (int s = 0; s < 8; ++s) h[8 + s] = bf2f(hs2[s]);
  }
  __syncthreads();

  const size_t xbase = ((size_t)b * 4096 + (size_t)c * CL) * 256 + d;
  unsigned short xu = xssm[xbase], zu = zb[xbase];
  for (int l = 0; l < CL; ++l) {
    unsigned short xun = 0, zun = 0;
    if (l + 1 < CL) {
      xun = xssm[xbase + (size_t)(l + 1) * 256];
      zun = zb[xbase + (size_t)(l + 1) * 256];
    }
    const float4* row = reinterpret_cast<const float4*>(sh[l]);
    float4 r0 = row[0], r1 = row[1];
    float acc = bdt;
    acc = fmaf(r0.x, w0.x, acc); acc = fmaf(r0.y, w0.y, acc);
    acc = fmaf(r0.z, w0.z, acc); acc = fmaf(r0.w, w0.w, acc);
    acc = fmaf(r1.x, w1.x, acc); acc = fmaf(r1.y, w1.y, acc);
    acc = fmaf(r1.z, w1.z, acc); acc = fmaf(r1.w, w1.w, acc);
    float dt = (acc > 20.f) ? acc : __logf(1.f + __expf(acc));
    float xv = bf2f(xu);
    float dtx = dt * xv;
    float yq[4] = {0.f, 0.f, 0.f, 0.f};
    #pragma unroll
    for (int q = 0; q < 4; ++q) {
      float4 Bq = row[2 + q], Cq = row[6 + q];
      float bb4[4] = {Bq.x, Bq.y, Bq.z, Bq.w};
      float cc4[4] = {Cq.x, Cq.y, Cq.z, Cq.w};
      #pragma unroll
      for (int j = 0; j < 4; ++j) {
        int s = q * 4 + j;
        float dA = __builtin_amdgcn_exp2f(dt * An2[s]);
        h[s] = fmaf(dA, h[s], dtx * bb4[j]);
        yq[q] = fmaf(h[s], cc4[j], yq[q]);
      }
    }
    float y = (yq[0] + yq[1]) + (yq[2] + yq[3]);
    y = (y + Dd * xv) * siluf(bf2f(zu));
    ybf[xbase + (size_t)l * 256] = f2bf(y);
    xu = xun; zu = zun;
  }
}

// ---------------- LayerNorm(128) + transpose to NCHW ------------------------
__global__ __launch_bounds__(256) void ln_transpose(
    const float* __restrict__ X,
    const float* __restrict__ g, const float* __restrict__ b,
    float* __restrict__ out)
{
  __shared__ float buf[64][129];
  const int t0 = blockIdx.x * 64;
  const int bb = t0 >> 12, l0 = t0 & 4095;
  const int tid = threadIdx.x;
  for (int idx = tid; idx < 64 * 128; idx += 256)
    buf[idx >> 7][idx & 127] = X[(size_t)t0 * 128 + idx];
  __syncthreads();
  const int tt = tid >> 2, q = tid & 3;
  float s = 0.f, sq = 0.f;
  #pragma unroll
  for (int i = 0; i < 32; ++i) {
    float v = buf[tt][q * 32 + i];
    s += v; sq += v * v;
  }
  s  += __shfl_xor(s, 1);  s  += __shfl_xor(s, 2);
  sq += __shfl_xor(sq, 1); sq += __shfl_xor(sq, 2);
  float mu = s * (1.f / 128.f);
  float var = sq * (1.f / 128.f) - mu * mu;
  float rstd = rsqrtf(fmaxf(var, 0.f) + 1e-5f);
  #pragma unroll
  for (int i = 0; i < 32; ++i) {
    int c = q * 32 + i;
    buf[tt][c] = (buf[tt][c] - mu) * rstd * g[c] + b[c];
  }
  __syncthreads();
  for (int idx = tid; idx < 64 * 128; idx += 256) {
    int c = idx >> 6, t2 = idx & 63;
    out[((size_t)bb * 128 + c) * 4096 + l0 + t2] = buf[t2][c];
  }
}

// ---------------------------------------------------------------------------
extern "C" void kernel_launch(void* const* d_in, const int* in_sizes, int n_in,
                              void* d_out, int out_size, void* d_ws, size_t ws_size,
                              hipStream_t stream) {
  const float* x        = (const float*)d_in[0];
  const float* conv1_w  = (const float*)d_in[1];
  const float* conv1_b  = (const float*)d_in[2];
  const float* bn1_g    = (const float*)d_in[3];
  const float* bn1_b    = (const float*)d_in[4];
  const float* bn1_m    = (const float*)d_in[5];
  const float* bn1_v    = (const float*)d_in[6];
  const float* conv2_w  = (const float*)d_in[7];
  const float* conv2_b  = (const float*)d_in[8];
  const float* bn2_g    = (const float*)d_in[9];
  const float* bn2_b    = (const float*)d_in[10];
  const float* bn2_m    = (const float*)d_in[11];
  const float* bn2_v    = (const float*)d_in[12];
  const float* in_proj_w  = (const float*)d_in[13];  // (512,128)
  const float* conv1d_w   = (const float*)d_in[14];  // (256,1,4)
  const float* conv1d_b   = (const float*)d_in[15];
  const float* x_proj_w   = (const float*)d_in[16];  // (40,256)
  const float* dt_proj_w  = (const float*)d_in[17];  // (256,8)
  const float* dt_proj_b  = (const float*)d_in[18];
  const float* A_log      = (const float*)d_in[19];  // (256,16)
  const float* Dp         = (const float*)d_in[20];  // (256)
  const float* out_proj_w = (const float*)d_in[21];  // (128,256)
  const float* ln_g       = (const float*)d_in[22];
  const float* ln_b       = (const float*)d_in[23];
  float* out = (float*)d_out;

  float* ws_f = (float*)d_ws;
  // workspace (float units), lifetime-reuse; peak ~101.4 MB
  // R1 [0, 8388608):
  unsigned short* xbp  = (unsigned short*)ws_f;          // [8][66][66][64] bf16 (pre)
  unsigned short* xmb  = (unsigned short*)ws_f;          // T*256 bf16 (in_proj->conv1d)
  unsigned short* ybf  = (unsigned short*)ws_f;          // T*256 bf16 (pass2->out_proj)
  float*          xdb  = ws_f + 4194304;                 // T*40 f32
  float*          Sbuf = ws_f + 5505024;                 // B*NC*256 f32 (524288)
  float*          outs = ws_f + 4194304;                 // T*128 f32 (after xdb dead)
  // R2, R3:
  unsigned short* zbu  = (unsigned short*)(ws_f + 8388608);   // T*256 bf16
  unsigned short* xsu  = (unsigned short*)(ws_f + 12582912);  // T*256 bf16
  // R4 [16777216, 25165824): h1p+seqb (conv phase) -> Qb (scan phase)
  unsigned short* h1p  = (unsigned short*)(ws_f + 16777216);  // [8][66][66][128]
  unsigned short* seqb = (unsigned short*)(ws_f + 19007488);  // [T][128]
  unsigned short* Qb   = (unsigned short*)(ws_f + 16777216);  // B*NC*256*16 bf16
  // weights / tables:
  unsigned short* wb1  = (unsigned short*)(ws_f + 25165824);  // 73728 u
  unsigned short* wb2  = (unsigned short*)(ws_f + 25202688);  // 147456 u
  unsigned short* win  = (unsigned short*)(ws_f + 25276416);  // 65536 u
  unsigned short* wout = (unsigned short*)(ws_f + 25309184);  // 32768 u
  unsigned short* xpwb = (unsigned short*)(ws_f + 25325568);  // 32768 u
  float*          An2f = ws_f + 25341952;                     // 4096 f

  // zero padded borders (whole buffers; interior overwritten next)
  hipMemsetAsync(xbp, 0, (size_t)8 * 66 * 66 * 64 * 2, stream);
  hipMemsetAsync(h1p, 0, (size_t)8 * 66 * 66 * 128 * 2, stream);

  // pre-passes
  nchw2nhwc_bf16<<<512, 256, 0, stream>>>(x, xbp);
  prep_all<<<1392, 256, 0, stream>>>(conv1_w, conv2_w, in_proj_w, out_proj_w,
                                     x_proj_w, A_log,
                                     wb1, wb2, win, wout, xpwb, An2f);

  // convs (LDS-staged MFMA implicit GEMM on padded NHWC)
  conv_mfma<64, 1><<<dim3(64, 8), 256, 0, stream>>>(
      xbp, wb1, conv1_b, bn1_g, bn1_b, bn1_m, bn1_v, h1p);
  conv_mfma<128, 0><<<dim3(64, 8), 256, 0, stream>>>(
      h1p, wb2, conv2_b, bn2_g, bn2_b, bn2_m, bn2_v, seqb);

  // in_proj (one GEMM, N=512 -> xm bf16 | z bf16)
  gemm_mfma<128, 0><<<dim3(512, 4), 256, 0, stream>>>(
      seqb, win, nullptr, xmb, zbu);

  // conv1d + silu -> xssm bf16
  conv1d_silu<<<2048, 256, 0, stream>>>(xmb, conv1d_w, conv1d_b, xsu);

  // x_proj (MFMA, padded N=128, mask n<40) -> xdb fp32
  gemm_mfma<256, 2><<<dim3(512, 1), 256, 0, stream>>>(
      xsu, xpwb, xdb, nullptr, nullptr);

  scan_pass1<<<dim3(NC, 8), 256, 0, stream>>>(
      xsu, xdb, dt_proj_w, dt_proj_b, An2f, Qb, Sbuf);
  scan_combine<<<128, 256, 0, stream>>>(Qb, Sbuf, An2f);
  scan_pass2<<<dim3(NC, 8), 256, 0, stream>>>(
      xsu, xdb, zbu, dt_proj_w, dt_proj_b, An2f, Dp, Qb, ybf);

  // out_proj (MFMA) + LN/transpose
  gemm_mfma<256, 1><<<dim3(512, 1), 256, 0, stream>>>(
      ybf, wout, outs, nullptr, nullptr);
  ln_transpose<<<512, 256, 0, stream>>>(outs, ln_g, ln_b, out);
}

// Round 10
// 216.111 us; speedup vs baseline: 1.3847x; 1.0110x over previous
//
#include <hip/hip_runtime.h>
#include <hip/hip_bf16.h>

// ---------------------------------------------------------------------------
// MambaConvBlock fused pipeline. Round 10: kill slow runtime memset
// (custom fill kernel); otherwise identical to Round 9.
// Sizes: B=8, CIN=64, COUT=128, H=W=64, L=4096, T=32768,
//        DINNER=256, DSTATE=16, DTRANK=8, DCONV=4.
// ---------------------------------------------------------------------------

typedef __attribute__((ext_vector_type(8))) short bf16x8;
typedef __attribute__((ext_vector_type(4))) float f32x4;

#define DEV __device__ __forceinline__

constexpr float LOG2E = 1.44269504088896f;

DEV float siluf(float v) {
  return v * __builtin_amdgcn_rcpf(1.f + __expf(-v));
}

DEV unsigned short f2bf(float f) {
  __hip_bfloat16 h = __float2bfloat16(f);
  return *reinterpret_cast<unsigned short*>(&h);
}

DEV float bf2f(unsigned short u) {
  unsigned int x = (unsigned int)u << 16;
  return __builtin_bit_cast(float, x);
}

// async global->LDS, 16B per lane; lds dest = uniform base + lane*16
DEV void gll16(const void* g, void* l) {
  __builtin_amdgcn_global_load_lds(
      (const __attribute__((address_space(1))) void*)g,
      (__attribute__((address_space(3))) void*)l, 16, 0, 0);
}

constexpr int NC = 256;  // scan chunks per batch
constexpr int CL = 16;   // scan chunk length

// ---------------- fast zero-fill for the two padded conv buffers ------------
__global__ __launch_bounds__(256) void fill_zero2(
    uint4* __restrict__ p1, int n1, uint4* __restrict__ p2, int n2)
{
  const uint4 z = uint4{0u, 0u, 0u, 0u};
  const int stride = gridDim.x * 256;
  for (int k = blockIdx.x * 256 + threadIdx.x; k < n1; k += stride) p1[k] = z;
  for (int k = blockIdx.x * 256 + threadIdx.x; k < n2; k += stride) p2[k] = z;
}

// ---------------- pre-pass: NCHW fp32 -> padded NHWC bf16 -------------------
__global__ __launch_bounds__(256) void nchw2nhwc_bf16(
    const float* __restrict__ X, unsigned short* __restrict__ Xb)
{
  __shared__ float t[64][65];
  const int by = blockIdx.x;            // b*64 + y
  const int b = by >> 6, y = by & 63;
  const int tid = threadIdx.x;
  for (int i = tid; i < 4096; i += 256) {
    int c = i >> 6, xx = i & 63;
    t[c][xx] = X[(((size_t)b * 64 + c) * 64 + y) * 64 + xx];
  }
  __syncthreads();
  for (int i = tid; i < 4096; i += 256) {
    int xx = i >> 6, c = i & 63;
    Xb[(((size_t)(b * 66 + y + 1) * 66) + xx + 1) * 64 + c] = f2bf(t[c][xx]);
  }
}

// ---------------- merged prep: all weights + An2 table ----------------------
__global__ __launch_bounds__(256) void prep_all(
    const float* __restrict__ conv1_w, const float* __restrict__ conv2_w,
    const float* __restrict__ in_proj_w, const float* __restrict__ out_proj_w,
    const float* __restrict__ x_proj_w, const float* __restrict__ A_log,
    unsigned short* __restrict__ wb1, unsigned short* __restrict__ wb2,
    unsigned short* __restrict__ win, unsigned short* __restrict__ wout,
    unsigned short* __restrict__ xpwb, float* __restrict__ An2f)
{
  int idx = blockIdx.x * 256 + threadIdx.x;
  if (idx < 73728) {                       // conv1 w: [co][tap][ci], CI=64
    int co = idx / 576, r = idx % 576, t = r >> 6, ci = r & 63;
    wb1[idx] = f2bf(conv1_w[((size_t)co * 64 + ci) * 9 + t]);
  } else if (idx < 221184) {               // conv2 w: CI=128
    int i = idx - 73728;
    int co = i / 1152, r = i % 1152, t = r >> 7, ci = r & 127;
    wb2[i] = f2bf(conv2_w[((size_t)co * 128 + ci) * 9 + t]);
  } else if (idx < 286720) {               // in_proj (512,128)
    int i = idx - 221184; win[i] = f2bf(in_proj_w[i]);
  } else if (idx < 319488) {               // out_proj (128,256)
    int i = idx - 286720; wout[i] = f2bf(out_proj_w[i]);
  } else if (idx < 352256) {               // x_proj padded (128,256)
    int i = idx - 319488; int r = i >> 8, c = i & 255;
    xpwb[i] = (r < 40) ? f2bf(x_proj_w[r * 256 + c]) : (unsigned short)0;
  } else if (idx < 356352) {               // An2 = -exp(A_log)*log2e
    int i = idx - 352256;
    An2f[i] = -__expf(A_log[i]) * LOG2E;
  }
}

// ---------------- conv3x3 + BN + ReLU: LDS-staged implicit GEMM -------------
template<int CI, int PADOUT>
__global__ __launch_bounds__(256) void conv_mfma(
    const unsigned short* __restrict__ Xp,   // [b][66][66][CI] bf16 padded
    const unsigned short* __restrict__ Wb,   // [128][9*CI]     bf16
    const float* __restrict__ bc,
    const float* __restrict__ bg, const float* __restrict__ bb,
    const float* __restrict__ bm, const float* __restrict__ bv,
    unsigned short* __restrict__ Y)
{
  constexpr int KC  = 3 * CI / 64;   // chunks per dy
  constexpr int NCH = 3 * KC;        // total chunks
  __shared__ bf16x8 ldsA[2][512];    // 2 x 8KB

  const int lane = threadIdx.x & 63;
  const int wid  = threadIdx.x >> 6;
  const int n0 = wid * 32;
  const int y = blockIdx.x, b = blockIdx.y;
  const int lr = lane & 15, kq = lane >> 4, lk = kq * 8;

  auto stage = [&](int buf, int c) {
    const int dy = c / KC, kc = c - dy * KC;
    const unsigned short* g = Xp
        + (size_t)((b * 66 + y + dy) * 66) * CI
        + (size_t)lane * CI + kc * 64 + wid * 16;
    gll16(g,     &ldsA[buf][(wid * 2) * 64]);
    gll16(g + 8, &ldsA[buf][(wid * 2 + 1) * 64]);
  };

  f32x4 acc[4][2];
  #pragma unroll
  for (int i = 0; i < 4; ++i)
    #pragma unroll
    for (int j = 0; j < 2; ++j) acc[i][j] = f32x4{0.f, 0.f, 0.f, 0.f};

  stage(0, 0);
  __syncthreads();

  #pragma unroll
  for (int c = 0; c < NCH; ++c) {
    if (c + 1 < NCH) stage((c + 1) & 1, c + 1);
    const int dy = c / KC, kc = c - dy * KC;
    bf16x8 bw[2][2];
    #pragma unroll
    for (int t = 0; t < 2; ++t)
      #pragma unroll
      for (int nf = 0; nf < 2; ++nf)
        bw[t][nf] = *reinterpret_cast<const bf16x8*>(
            Wb + (size_t)(n0 + nf * 16 + lr) * (9 * CI)
               + dy * 3 * CI + kc * 64 + t * 32 + lk);
    const bf16x8* Ab = ldsA[c & 1];
    #pragma unroll
    for (int t = 0; t < 2; ++t)
      #pragma unroll
      for (int mf = 0; mf < 4; ++mf) {
        bf16x8 afr = Ab[(t * 4 + kq) * 64 + mf * 16 + lr];
        #pragma unroll
        for (int nf = 0; nf < 2; ++nf)
          acc[mf][nf] = __builtin_amdgcn_mfma_f32_16x16x32_bf16(
              afr, bw[t][nf], acc[mf][nf], 0, 0, 0);
      }
    __syncthreads();
  }

  #pragma unroll
  for (int nf = 0; nf < 2; ++nf) {
    int n = n0 + nf * 16 + lr;
    float aS = bg[n] * rsqrtf(bv[n] + 1e-5f);
    float aB = (bc[n] - bm[n]) * aS + bb[n];
    #pragma unroll
    for (int mf = 0; mf < 4; ++mf)
      #pragma unroll
      for (int i = 0; i < 4; ++i) {
        int m = mf * 16 + kq * 4 + i;
        float v = fmaxf(acc[mf][nf][i] * aS + aB, 0.f);
        if (PADOUT)
          Y[((size_t)(b * 66 + y + 1) * 66 + m + 1) * 128 + n] = f2bf(v);
        else
          Y[((size_t)(b * 4096 + y * 64 + m)) * 128 + n] = f2bf(v);
      }
  }
}

// ---------------- bf16 MFMA GEMM, LDS-staged A ------------------------------
// EPI 0: in_proj  -> Cb0 bf16 [m][256] (xm), Cb1 bf16 [m][256] (z)
// EPI 1: out_proj -> C0 fp32 [m][128]
// EPI 2: x_proj   -> C0 fp32 [m][40], mask n<40
template<int KDIM, int EPI>
__global__ __launch_bounds__(256) void gemm_mfma(
    const unsigned short* __restrict__ A,   // [M][KDIM] bf16
    const unsigned short* __restrict__ Wn,  // [N][KDIM] bf16
    float* __restrict__ C0,
    unsigned short* __restrict__ Cb0, unsigned short* __restrict__ Cb1)
{
  constexpr int NCH = KDIM / 64;
  __shared__ bf16x8 ldsA[2][512];

  const int lane = threadIdx.x & 63;
  const int wid  = threadIdx.x >> 6;
  const int m0 = blockIdx.x * 64;
  const int n0 = blockIdx.y * 128 + wid * 32;
  const int lr = lane & 15, kq = lane >> 4, lk = kq * 8;

  bf16x8 bw[NCH][2][2];
  #pragma unroll
  for (int c = 0; c < NCH; ++c)
    #pragma unroll
    for (int t = 0; t < 2; ++t)
      #pragma unroll
      for (int nf = 0; nf < 2; ++nf)
        bw[c][t][nf] = *reinterpret_cast<const bf16x8*>(
            Wn + (size_t)(n0 + nf * 16 + lr) * KDIM + c * 64 + t * 32 + lk);

  auto stage = [&](int buf, int c) {
    const unsigned short* g = A + (size_t)(m0 + lane) * KDIM + c * 64 + wid * 16;
    gll16(g,     &ldsA[buf][(wid * 2) * 64]);
    gll16(g + 8, &ldsA[buf][(wid * 2 + 1) * 64]);
  };

  f32x4 acc[4][2];
  #pragma unroll
  for (int i = 0; i < 4; ++i)
    #pragma unroll
    for (int j = 0; j < 2; ++j) acc[i][j] = f32x4{0.f, 0.f, 0.f, 0.f};

  stage(0, 0);
  __syncthreads();

  #pragma unroll
  for (int c = 0; c < NCH; ++c) {
    if (c + 1 < NCH) stage((c + 1) & 1, c + 1);
    const bf16x8* Ab = ldsA[c & 1];
    #pragma unroll
    for (int t = 0; t < 2; ++t)
      #pragma unroll
      for (int mf = 0; mf < 4; ++mf) {
        bf16x8 afr = Ab[(t * 4 + kq) * 64 + mf * 16 + lr];
        #pragma unroll
        for (int nf = 0; nf < 2; ++nf)
          acc[mf][nf] = __builtin_amdgcn_mfma_f32_16x16x32_bf16(
              afr, bw[c][t][nf], acc[mf][nf], 0, 0, 0);
      }
    __syncthreads();
  }

  #pragma unroll
  for (int nf = 0; nf < 2; ++nf) {
    int n = n0 + nf * 16 + lr;
    #pragma unroll
    for (int mf = 0; mf < 4; ++mf)
      #pragma unroll
      for (int i = 0; i < 4; ++i) {
        int m = m0 + mf * 16 + kq * 4 + i;
        float v = acc[mf][nf][i];
        if (EPI == 0) {
          if (n < 256) Cb0[(size_t)m * 256 + n] = f2bf(v);
          else         Cb1[(size_t)m * 256 + (n - 256)] = f2bf(v);
        } else if (EPI == 1) {
          C0[(size_t)m * 128 + n] = v;
        } else {
          if (n < 40) C0[(size_t)m * 40 + n] = v;
        }
      }
  }
}

// ---------------- depthwise causal conv1d (DCONV=4) + silu, bf16 ------------
__global__ __launch_bounds__(256) void conv1d_silu(
    const unsigned short* __restrict__ xm,   // (T,256) bf16
    const float* __restrict__ w,             // (256,4)
    const float* __restrict__ bias,          // (256)
    unsigned short* __restrict__ out)        // (T,256) bf16
{
  __shared__ float ws4[4][256];
  __shared__ float bsh[256];
  for (int i = threadIdx.x; i < 1024; i += 256)
    ws4[i >> 8][i & 255] = w[(i & 255) * 4 + (i >> 8)];
  bsh[threadIdx.x] = bias[threadIdx.x];
  __syncthreads();
  const int total = 32768 * 32;   // 8 channels per thread
  for (int idx = blockIdx.x * 256 + threadIdx.x; idx < total;
       idx += gridDim.x * 256) {
    int d8 = idx & 31, t = idx >> 5, l = t & 4095;
    int d = d8 * 8;
    float acc[8];
    #pragma unroll
    for (int k = 0; k < 8; ++k) acc[k] = bsh[d + k];
    #pragma unroll
    for (int j = 0; j < 4; ++j) {
      if (l - 3 + j >= 0) {
        uint4 xv = *reinterpret_cast<const uint4*>(
            &xm[(size_t)(t - 3 + j) * 256 + d]);
        const unsigned short* xs = reinterpret_cast<const unsigned short*>(&xv);
        #pragma unroll
        for (int k = 0; k < 8; ++k)
          acc[k] = fmaf(bf2f(xs[k]), ws4[j][d + k], acc[k]);
      }
    }
    unsigned int pk[4];
    #pragma unroll
    for (int k = 0; k < 4; ++k) {
      unsigned short lo = f2bf(siluf(acc[2 * k]));
      unsigned short hi = f2bf(siluf(acc[2 * k + 1]));
      pk[k] = (unsigned int)lo | ((unsigned int)hi << 16);
    }
    *reinterpret_cast<uint4*>(&out[(size_t)t * 256 + d]) =
        *reinterpret_cast<uint4*>(pk);
  }
}

// ---------------- chunked selective scan ------------------------------------
__global__ __launch_bounds__(256) void scan_pass1(
    const unsigned short* __restrict__ xssm, const float* __restrict__ xdb,
    const float* __restrict__ dtw, const float* __restrict__ dtb,
    const float* __restrict__ An2f,
    unsigned short* __restrict__ Qb, float* __restrict__ S)
{
  __shared__ __align__(16) float sh[CL][40];
  const int c = blockIdx.x, b = blockIdx.y;
  const int d = threadIdx.x;
  if (threadIdx.x < CL * 10) {
    const float4* src = reinterpret_cast<const float4*>(
        &xdb[((size_t)b * 4096 + c * CL) * 40]);
    reinterpret_cast<float4*>(&sh[0][0])[threadIdx.x] = src[threadIdx.x];
  }
  float4 w0 = *reinterpret_cast<const float4*>(&dtw[d * 8]);
  float4 w1 = *reinterpret_cast<const float4*>(&dtw[d * 8 + 4]);
  const float bdt = dtb[d];
  float An2[16], h[16];
  {
    const f32x4* a2 = reinterpret_cast<const f32x4*>(&An2f[d * 16]);
    #pragma unroll
    for (int q = 0; q < 4; ++q) {
      f32x4 v = a2[q];
      An2[q * 4 + 0] = v[0]; An2[q * 4 + 1] = v[1];
      An2[q * 4 + 2] = v[2]; An2[q * 4 + 3] = v[3];
    }
  }
  #pragma unroll
  for (int s = 0; s < 16; ++s) h[s] = 0.f;
  __syncthreads();

  float sdt = 0.f;
  const size_t xbase = ((size_t)b * 4096 + (size_t)c * CL) * 256 + d;
  unsigned short xu = xssm[xbase];
  for (int l = 0; l < CL; ++l) {
    unsigned short xun = (l + 1 < CL) ? xssm[xbase + (size_t)(l + 1) * 256]
                                      : (unsigned short)0;
    const float4* row = reinterpret_cast<const float4*>(sh[l]);
    float4 r0 = row[0], r1 = row[1];
    float acc = bdt;
    acc = fmaf(r0.x, w0.x, acc); acc = fmaf(r0.y, w0.y, acc);
    acc = fmaf(r0.z, w0.z, acc); acc = fmaf(r0.w, w0.w, acc);
    acc = fmaf(r1.x, w1.x, acc); acc = fmaf(r1.y, w1.y, acc);
    acc = fmaf(r1.z, w1.z, acc); acc = fmaf(r1.w, w1.w, acc);
    float dt = (acc > 20.f) ? acc : __logf(1.f + __expf(acc));
    sdt += dt;
    float dtx = dt * bf2f(xu);
    #pragma unroll
    for (int q = 0; q < 4; ++q) {
      float4 Bq = row[2 + q];
      float bb4[4] = {Bq.x, Bq.y, Bq.z, Bq.w};
      #pragma unroll
      for (int j = 0; j < 4; ++j) {
        int s = q * 4 + j;
        float dA = __builtin_amdgcn_exp2f(dt * An2[s]);
        h[s] = fmaf(dA, h[s], dtx * bb4[j]);
      }
    }
    xu = xun;
  }
  unsigned int pk[8];
  #pragma unroll
  for (int k = 0; k < 8; ++k)
    pk[k] = (unsigned int)f2bf(h[2 * k]) | ((unsigned int)f2bf(h[2 * k + 1]) << 16);
  uint4* qp = reinterpret_cast<uint4*>(
      &Qb[(((size_t)b * NC + c) * 256 + d) * 16]);
  qp[0] = *reinterpret_cast<uint4*>(pk);
  qp[1] = *reinterpret_cast<uint4*>(pk + 4);
  S[((size_t)b * NC + c) * 256 + d] = sdt;
}

__global__ __launch_bounds__(256) void scan_combine(
    unsigned short* __restrict__ Qb, const float* __restrict__ S,
    const float* __restrict__ An2f)
{
  int g = blockIdx.x * 256 + threadIdx.x;   // 32768 total
  int b = g >> 12, d = (g >> 4) & 255, s = g & 15;
  float An2 = An2f[d * 16 + s];
  const size_t qbase = (size_t)b * NC * 4096 + d * 16 + s;
  const size_t sbase = (size_t)b * NC * 256 + d;
  float h = 0.f;
  unsigned short qn = Qb[qbase];
  float sn = S[sbase];
  for (int c = 0; c < NC; ++c) {
    float q = bf2f(qn), sd = sn;
    if (c + 1 < NC) {
      qn = Qb[qbase + (size_t)(c + 1) * 4096];
      sn = S[sbase + (size_t)(c + 1) * 256];
    }
    Qb[qbase + (size_t)c * 4096] = f2bf(h);
    h = fmaf(__builtin_amdgcn_exp2f(An2 * sd), h, q);
  }
}

__global__ __launch_bounds__(256) void scan_pass2(
    const unsigned short* __restrict__ xssm, const float* __restrict__ xdb,
    const unsigned short* __restrict__ zb,
    const float* __restrict__ dtw, const float* __restrict__ dtb,
    const float* __restrict__ An2f, const float* __restrict__ Dp,
    const unsigned short* __restrict__ Hstart, unsigned short* __restrict__ ybf)
{
  __shared__ __align__(16) float sh[CL][40];
  const int c = blockIdx.x, b = blockIdx.y;
  const int d = threadIdx.x;
  if (threadIdx.x < CL * 10) {
    const float4* src = reinterpret_cast<const float4*>(
        &xdb[((size_t)b * 4096 + c * CL) * 40]);
    reinterpret_cast<float4*>(&sh[0][0])[threadIdx.x] = src[threadIdx.x];
  }
  float4 w0 = *reinterpret_cast<const float4*>(&dtw[d * 8]);
  float4 w1 = *reinterpret_cast<const float4*>(&dtw[d * 8 + 4]);
  const float bdt = dtb[d];
  const float Dd = Dp[d];
  float An2[16], h[16];
  {
    const f32x4* a2 = reinterpret_cast<const f32x4*>(&An2f[d * 16]);
    #pragma unroll
    for (int q = 0; q < 4; ++q) {
      f32x4 v = a2[q];
      An2[q * 4 + 0] = v[0]; An2[q * 4 + 1] = v[1];
      An2[q * 4 + 2] = v[2]; An2[q * 4 + 3] = v[3];
    }
  }
  {
    const uint4* hp = reinterpret_cast<const uint4*>(
        &Hstart[(((size_t)b * NC + c) * 256 + d) * 16]);
    uint4 h0 = hp[0], h1 = hp[1];
    const unsigned short* hs = reinterpret_cast<const unsigned short*>(&h0);
    #pragma unroll
    for (int s = 0; s < 8; ++s) h[s] = bf2f(hs[s]);
    const unsigned short* hs2 = reinterpret_cast<const unsigned short*>(&h1);
    #pragma unroll
    for (int s = 0; s < 8; ++s) h[8 + s] = bf2f(hs2[s]);
  }
  __syncthreads();

  const size_t xbase = ((size_t)b * 4096 + (size_t)c * CL) * 256 + d;
  unsigned short xu = xssm[xbase], zu = zb[xbase];
  for (int l = 0; l < CL; ++l) {
    unsigned short xun = 0, zun = 0;
    if (l + 1 < CL) {
      xun = xssm[xbase + (size_t)(l + 1) * 256];
      zun = zb[xbase + (size_t)(l + 1) * 256];
    }
    const float4* row = reinterpret_cast<const float4*>(sh[l]);
    float4 r0 = row[0], r1 = row[1];
    float acc = bdt;
    acc = fmaf(r0.x, w0.x, acc); acc = fmaf(r0.y, w0.y, acc);
    acc = fmaf(r0.z, w0.z, acc); acc = fmaf(r0.w, w0.w, acc);
    acc = fmaf(r1.x, w1.x, acc); acc = fmaf(r1.y, w1.y, acc);
    acc = fmaf(r1.z, w1.z, acc); acc = fmaf(r1.w, w1.w, acc);
    float dt = (acc > 20.f) ? acc : __logf(1.f + __expf(acc));
    float xv = bf2f(xu);
    float dtx = dt * xv;
    float yq[4] = {0.f, 0.f, 0.f, 0.f};
    #pragma unroll
    for (int q = 0; q < 4; ++q) {
      float4 Bq = row[2 + q], Cq = row[6 + q];
      float bb4[4] = {Bq.x, Bq.y, Bq.z, Bq.w};
      float cc4[4] = {Cq.x, Cq.y, Cq.z, Cq.w};
      #pragma unroll
      for (int j = 0; j < 4; ++j) {
        int s = q * 4 + j;
        float dA = __builtin_amdgcn_exp2f(dt * An2[s]);
        h[s] = fmaf(dA, h[s], dtx * bb4[j]);
        yq[q] = fmaf(h[s], cc4[j], yq[q]);
      }
    }
    float y = (yq[0] + yq[1]) + (yq[2] + yq[3]);
    y = (y + Dd * xv) * siluf(bf2f(zu));
    ybf[xbase + (size_t)l * 256] = f2bf(y);
    xu = xun; zu = zun;
  }
}

// ---------------- LayerNorm(128) + transpose to NCHW ------------------------
__global__ __launch_bounds__(256) void ln_transpose(
    const float* __restrict__ X,
    const float* __restrict__ g, const float* __restrict__ b,
    float* __restrict__ out)
{
  __shared__ float buf[64][129];
  const int t0 = blockIdx.x * 64;
  const int bb = t0 >> 12, l0 = t0 & 4095;
  const int tid = threadIdx.x;
  for (int idx = tid; idx < 64 * 128; idx += 256)
    buf[idx >> 7][idx & 127] = X[(size_t)t0 * 128 + idx];
  __syncthreads();
  const int tt = tid >> 2, q = tid & 3;
  float s = 0.f, sq = 0.f;
  #pragma unroll
  for (int i = 0; i < 32; ++i) {
    float v = buf[tt][q * 32 + i];
    s += v; sq += v * v;
  }
  s  += __shfl_xor(s, 1);  s  += __shfl_xor(s, 2);
  sq += __shfl_xor(sq, 1); sq += __shfl_xor(sq, 2);
  float mu = s * (1.f / 128.f);
  float var = sq * (1.f / 128.f) - mu * mu;
  float rstd = rsqrtf(fmaxf(var, 0.f) + 1e-5f);
  #pragma unroll
  for (int i = 0; i < 32; ++i) {
    int c = q * 32 + i;
    buf[tt][c] = (buf[tt][c] - mu) * rstd * g[c] + b[c];
  }
  __syncthreads();
  for (int idx = tid; idx < 64 * 128; idx += 256) {
    int c = idx >> 6, t2 = idx & 63;
    out[((size_t)bb * 128 + c) * 4096 + l0 + t2] = buf[t2][c];
  }
}

// ---------------------------------------------------------------------------
extern "C" void kernel_launch(void* const* d_in, const int* in_sizes, int n_in,
                              void* d_out, int out_size, void* d_ws, size_t ws_size,
                              hipStream_t stream) {
  const float* x        = (const float*)d_in[0];
  const float* conv1_w  = (const float*)d_in[1];
  const float* conv1_b  = (const float*)d_in[2];
  const float* bn1_g    = (const float*)d_in[3];
  const float* bn1_b    = (const float*)d_in[4];
  const float* bn1_m    = (const float*)d_in[5];
  const float* bn1_v    = (const float*)d_in[6];
  const float* conv2_w  = (const float*)d_in[7];
  const float* conv2_b  = (const float*)d_in[8];
  const float* bn2_g    = (const float*)d_in[9];
  const float* bn2_b    = (const float*)d_in[10];
  const float* bn2_m    = (const float*)d_in[11];
  const float* bn2_v    = (const float*)d_in[12];
  const float* in_proj_w  = (const float*)d_in[13];  // (512,128)
  const float* conv1d_w   = (const float*)d_in[14];  // (256,1,4)
  const float* conv1d_b   = (const float*)d_in[15];
  const float* x_proj_w   = (const float*)d_in[16];  // (40,256)
  const float* dt_proj_w  = (const float*)d_in[17];  // (256,8)
  const float* dt_proj_b  = (const float*)d_in[18];
  const float* A_log      = (const float*)d_in[19];  // (256,16)
  const float* Dp         = (const float*)d_in[20];  // (256)
  const float* out_proj_w = (const float*)d_in[21];  // (128,256)
  const float* ln_g       = (const float*)d_in[22];
  const float* ln_b       = (const float*)d_in[23];
  float* out = (float*)d_out;

  float* ws_f = (float*)d_ws;
  // workspace (float units), lifetime-reuse; peak ~101.4 MB
  // R1 [0, 8388608):
  unsigned short* xbp  = (unsigned short*)ws_f;          // [8][66][66][64] bf16 (pre)
  unsigned short* xmb  = (unsigned short*)ws_f;          // T*256 bf16 (in_proj->conv1d)
  unsigned short* ybf  = (unsigned short*)ws_f;          // T*256 bf16 (pass2->out_proj)
  float*          xdb  = ws_f + 4194304;                 // T*40 f32
  float*          Sbuf = ws_f + 5505024;                 // B*NC*256 f32 (524288)
  float*          outs = ws_f + 4194304;                 // T*128 f32 (after xdb dead)
  // R2, R3:
  unsigned short* zbu  = (unsigned short*)(ws_f + 8388608);   // T*256 bf16
  unsigned short* xsu  = (unsigned short*)(ws_f + 12582912);  // T*256 bf16
  // R4 [16777216, 25165824): h1p+seqb (conv phase) -> Qb (scan phase)
  unsigned short* h1p  = (unsigned short*)(ws_f + 16777216);  // [8][66][66][128]
  unsigned short* seqb = (unsigned short*)(ws_f + 19007488);  // [T][128]
  unsigned short* Qb   = (unsigned short*)(ws_f + 16777216);  // B*NC*256*16 bf16
  // weights / tables:
  unsigned short* wb1  = (unsigned short*)(ws_f + 25165824);  // 73728 u
  unsigned short* wb2  = (unsigned short*)(ws_f + 25202688);  // 147456 u
  unsigned short* win  = (unsigned short*)(ws_f + 25276416);  // 65536 u
  unsigned short* wout = (unsigned short*)(ws_f + 25309184);  // 32768 u
  unsigned short* xpwb = (unsigned short*)(ws_f + 25325568);  // 32768 u
  float*          An2f = ws_f + 25341952;                     // 4096 f

  // zero padded conv buffers with a FAST custom fill (runtime memset kernel
  // was 212 GB/s -> ~63 us in the graph; this is ~4 us)
  fill_zero2<<<2048, 256, 0, stream>>>(
      (uint4*)xbp, (int)((size_t)8 * 66 * 66 * 64 * 2 / 16),
      (uint4*)h1p, (int)((size_t)8 * 66 * 66 * 128 * 2 / 16));

  // pre-passes
  nchw2nhwc_bf16<<<512, 256, 0, stream>>>(x, xbp);
  prep_all<<<1392, 256, 0, stream>>>(conv1_w, conv2_w, in_proj_w, out_proj_w,
                                     x_proj_w, A_log,
                                     wb1, wb2, win, wout, xpwb, An2f);

  // convs (LDS-staged MFMA implicit GEMM on padded NHWC)
  conv_mfma<64, 1><<<dim3(64, 8), 256, 0, stream>>>(
      xbp, wb1, conv1_b, bn1_g, bn1_b, bn1_m, bn1_v, h1p);
  conv_mfma<128, 0><<<dim3(64, 8), 256, 0, stream>>>(
      h1p, wb2, conv2_b, bn2_g, bn2_b, bn2_m, bn2_v, seqb);

  // in_proj (one GEMM, N=512 -> xm bf16 | z bf16)
  gemm_mfma<128, 0><<<dim3(512, 4), 256, 0, stream>>>(
      seqb, win, nullptr, xmb, zbu);

  // conv1d + silu -> xssm bf16
  conv1d_silu<<<2048, 256, 0, stream>>>(xmb, conv1d_w, conv1d_b, xsu);

  // x_proj (MFMA, padded N=128, mask n<40) -> xdb fp32
  gemm_mfma<256, 2><<<dim3(512, 1), 256, 0, stream>>>(
      xsu, xpwb, xdb, nullptr, nullptr);

  scan_pass1<<<dim3(NC, 8), 256, 0, stream>>>(
      xsu, xdb, dt_proj_w, dt_proj_b, An2f, Qb, Sbuf);
  scan_combine<<<128, 256, 0, stream>>>(Qb, Sbuf, An2f);
  scan_pass2<<<dim3(NC, 8), 256, 0, stream>>>(
      xsu, xdb, zbu, dt_proj_w, dt_proj_b, An2f, Dp, Qb, ybf);

  // out_proj (MFMA) + LN/transpose
  gemm_mfma<256, 1><<<dim3(512, 1), 256, 0, stream>>>(
      ybf, wout, outs, nullptr, nullptr);
  ln_transpose<<<512, 256, 0, stream>>>(outs, ln_g, ln_b, out);
}

// Round 11
// 207.183 us; speedup vs baseline: 1.4443x; 1.0431x over previous
//
#include <hip/hip_runtime.h>
#include <hip/hip_bf16.h>

// ---------------------------------------------------------------------------
// MambaConvBlock fused pipeline. Round 11: fuse out_proj+LN+transpose;
// merged prologue (nchw + weight prep + border-only zero fill).
// Sizes: B=8, CIN=64, COUT=128, H=W=64, L=4096, T=32768,
//        DINNER=256, DSTATE=16, DTRANK=8, DCONV=4.
// ---------------------------------------------------------------------------

typedef __attribute__((ext_vector_type(8))) short bf16x8;
typedef __attribute__((ext_vector_type(4))) float f32x4;

#define DEV __device__ __forceinline__

constexpr float LOG2E = 1.44269504088896f;

DEV float siluf(float v) {
  return v * __builtin_amdgcn_rcpf(1.f + __expf(-v));
}

DEV unsigned short f2bf(float f) {
  __hip_bfloat16 h = __float2bfloat16(f);
  return *reinterpret_cast<unsigned short*>(&h);
}

DEV float bf2f(unsigned short u) {
  unsigned int x = (unsigned int)u << 16;
  return __builtin_bit_cast(float, x);
}

// async global->LDS, 16B per lane; lds dest = uniform base + lane*16
DEV void gll16(const void* g, void* l) {
  __builtin_amdgcn_global_load_lds(
      (const __attribute__((address_space(1))) void*)g,
      (__attribute__((address_space(3))) void*)l, 16, 0, 0);
}

constexpr int NC = 256;  // scan chunks per batch
constexpr int CL = 16;   // scan chunk length

// ---------------- prologue: nchw->NHWC bf16 + weight prep + border zero -----
// blocks [0,512): nchw transpose; [512,1904): weight prep; [1904,1920): border
DEV void zero_border(unsigned short* buf, int CI, int tid0, int nthreads) {
  for (int w = tid0; w < 8 * 260; w += nthreads) {
    int b = w / 260, e = w % 260;
    int y, x;
    if (e < 132) { y = (e < 66) ? 0 : 65; x = (e < 66) ? e : e - 66; }
    else { int e2 = e - 132; y = 1 + (e2 >> 1); x = (e2 & 1) ? 65 : 0; }
    uint4* p = reinterpret_cast<uint4*>(buf + ((size_t)((b * 66 + y) * 66 + x)) * CI);
    for (int k = 0; k < CI / 8; ++k) p[k] = uint4{0u, 0u, 0u, 0u};
  }
}

__global__ __launch_bounds__(256) void prologue(
    const float* __restrict__ X, unsigned short* __restrict__ Xb,
    const float* __restrict__ conv1_w, const float* __restrict__ conv2_w,
    const float* __restrict__ in_proj_w, const float* __restrict__ out_proj_w,
    const float* __restrict__ x_proj_w, const float* __restrict__ A_log,
    unsigned short* __restrict__ wb1, unsigned short* __restrict__ wb2,
    unsigned short* __restrict__ win, unsigned short* __restrict__ wout,
    unsigned short* __restrict__ xpwb, float* __restrict__ An2f,
    unsigned short* __restrict__ h1p)
{
  __shared__ float t[64][65];
  const int blk = blockIdx.x;
  const int tid = threadIdx.x;
  if (blk < 512) {
    // NCHW fp32 -> padded NHWC bf16 (interior)
    const int b = blk >> 6, y = blk & 63;
    for (int i = tid; i < 4096; i += 256) {
      int c = i >> 6, xx = i & 63;
      t[c][xx] = X[(((size_t)b * 64 + c) * 64 + y) * 64 + xx];
    }
    __syncthreads();
    for (int i = tid; i < 4096; i += 256) {
      int xx = i >> 6, c = i & 63;
      Xb[(((size_t)(b * 66 + y + 1) * 66) + xx + 1) * 64 + c] = f2bf(t[c][xx]);
    }
  } else if (blk < 1904) {
    int idx = (blk - 512) * 256 + tid;
    if (idx < 73728) {                       // conv1 w: [co][tap][ci], CI=64
      int co = idx / 576, r = idx % 576, tp = r >> 6, ci = r & 63;
      wb1[idx] = f2bf(conv1_w[((size_t)co * 64 + ci) * 9 + tp]);
    } else if (idx < 221184) {               // conv2 w: CI=128
      int i = idx - 73728;
      int co = i / 1152, r = i % 1152, tp = r >> 7, ci = r & 127;
      wb2[i] = f2bf(conv2_w[((size_t)co * 128 + ci) * 9 + tp]);
    } else if (idx < 286720) {               // in_proj (512,128)
      int i = idx - 221184; win[i] = f2bf(in_proj_w[i]);
    } else if (idx < 319488) {               // out_proj (128,256)
      int i = idx - 286720; wout[i] = f2bf(out_proj_w[i]);
    } else if (idx < 352256) {               // x_proj padded (128,256)
      int i = idx - 319488; int r = i >> 8, c = i & 255;
      xpwb[i] = (r < 40) ? f2bf(x_proj_w[r * 256 + c]) : (unsigned short)0;
    } else if (idx < 356352) {               // An2 = -exp(A_log)*log2e
      int i = idx - 352256;
      An2f[i] = -__expf(A_log[i]) * LOG2E;
    }
  } else {
    // border zero for both padded buffers
    int tid0 = (blk - 1904) * 256 + tid;
    zero_border(Xb, 64, tid0, 16 * 256);
    zero_border(h1p, 128, tid0, 16 * 256);
  }
}

// ---------------- conv3x3 + BN + ReLU: LDS-staged implicit GEMM -------------
template<int CI, int PADOUT>
__global__ __launch_bounds__(256) void conv_mfma(
    const unsigned short* __restrict__ Xp,   // [b][66][66][CI] bf16 padded
    const unsigned short* __restrict__ Wb,   // [128][9*CI]     bf16
    const float* __restrict__ bc,
    const float* __restrict__ bg, const float* __restrict__ bb,
    const float* __restrict__ bm, const float* __restrict__ bv,
    unsigned short* __restrict__ Y)
{
  constexpr int KC  = 3 * CI / 64;   // chunks per dy
  constexpr int NCH = 3 * KC;        // total chunks
  __shared__ bf16x8 ldsA[2][512];    // 2 x 8KB

  const int lane = threadIdx.x & 63;
  const int wid  = threadIdx.x >> 6;
  const int n0 = wid * 32;
  const int y = blockIdx.x, b = blockIdx.y;
  const int lr = lane & 15, kq = lane >> 4, lk = kq * 8;

  auto stage = [&](int buf, int c) {
    const int dy = c / KC, kc = c - dy * KC;
    const unsigned short* g = Xp
        + (size_t)((b * 66 + y + dy) * 66) * CI
        + (size_t)lane * CI + kc * 64 + wid * 16;
    gll16(g,     &ldsA[buf][(wid * 2) * 64]);
    gll16(g + 8, &ldsA[buf][(wid * 2 + 1) * 64]);
  };

  f32x4 acc[4][2];
  #pragma unroll
  for (int i = 0; i < 4; ++i)
    #pragma unroll
    for (int j = 0; j < 2; ++j) acc[i][j] = f32x4{0.f, 0.f, 0.f, 0.f};

  stage(0, 0);
  __syncthreads();

  #pragma unroll
  for (int c = 0; c < NCH; ++c) {
    if (c + 1 < NCH) stage((c + 1) & 1, c + 1);
    const int dy = c / KC, kc = c - dy * KC;
    bf16x8 bw[2][2];
    #pragma unroll
    for (int t = 0; t < 2; ++t)
      #pragma unroll
      for (int nf = 0; nf < 2; ++nf)
        bw[t][nf] = *reinterpret_cast<const bf16x8*>(
            Wb + (size_t)(n0 + nf * 16 + lr) * (9 * CI)
               + dy * 3 * CI + kc * 64 + t * 32 + lk);
    const bf16x8* Ab = ldsA[c & 1];
    #pragma unroll
    for (int t = 0; t < 2; ++t)
      #pragma unroll
      for (int mf = 0; mf < 4; ++mf) {
        bf16x8 afr = Ab[(t * 4 + kq) * 64 + mf * 16 + lr];
        #pragma unroll
        for (int nf = 0; nf < 2; ++nf)
          acc[mf][nf] = __builtin_amdgcn_mfma_f32_16x16x32_bf16(
              afr, bw[t][nf], acc[mf][nf], 0, 0, 0);
      }
    __syncthreads();
  }

  #pragma unroll
  for (int nf = 0; nf < 2; ++nf) {
    int n = n0 + nf * 16 + lr;
    float aS = bg[n] * rsqrtf(bv[n] + 1e-5f);
    float aB = (bc[n] - bm[n]) * aS + bb[n];
    #pragma unroll
    for (int mf = 0; mf < 4; ++mf)
      #pragma unroll
      for (int i = 0; i < 4; ++i) {
        int m = mf * 16 + kq * 4 + i;
        float v = fmaxf(acc[mf][nf][i] * aS + aB, 0.f);
        if (PADOUT)
          Y[((size_t)(b * 66 + y + 1) * 66 + m + 1) * 128 + n] = f2bf(v);
        else
          Y[((size_t)(b * 4096 + y * 64 + m)) * 128 + n] = f2bf(v);
      }
  }
}

// ---------------- bf16 MFMA GEMM, LDS-staged A ------------------------------
// EPI 0: in_proj  -> Cb0 bf16 [m][256] (xm), Cb1 bf16 [m][256] (z)
// EPI 2: x_proj   -> C0 fp32 [m][40], mask n<40
template<int KDIM, int EPI>
__global__ __launch_bounds__(256) void gemm_mfma(
    const unsigned short* __restrict__ A,   // [M][KDIM] bf16
    const unsigned short* __restrict__ Wn,  // [N][KDIM] bf16
    float* __restrict__ C0,
    unsigned short* __restrict__ Cb0, unsigned short* __restrict__ Cb1)
{
  constexpr int NCH = KDIM / 64;
  __shared__ bf16x8 ldsA[2][512];

  const int lane = threadIdx.x & 63;
  const int wid  = threadIdx.x >> 6;
  const int m0 = blockIdx.x * 64;
  const int n0 = blockIdx.y * 128 + wid * 32;
  const int lr = lane & 15, kq = lane >> 4, lk = kq * 8;

  bf16x8 bw[NCH][2][2];
  #pragma unroll
  for (int c = 0; c < NCH; ++c)
    #pragma unroll
    for (int t = 0; t < 2; ++t)
      #pragma unroll
      for (int nf = 0; nf < 2; ++nf)
        bw[c][t][nf] = *reinterpret_cast<const bf16x8*>(
            Wn + (size_t)(n0 + nf * 16 + lr) * KDIM + c * 64 + t * 32 + lk);

  auto stage = [&](int buf, int c) {
    const unsigned short* g = A + (size_t)(m0 + lane) * KDIM + c * 64 + wid * 16;
    gll16(g,     &ldsA[buf][(wid * 2) * 64]);
    gll16(g + 8, &ldsA[buf][(wid * 2 + 1) * 64]);
  };

  f32x4 acc[4][2];
  #pragma unroll
  for (int i = 0; i < 4; ++i)
    #pragma unroll
    for (int j = 0; j < 2; ++j) acc[i][j] = f32x4{0.f, 0.f, 0.f, 0.f};

  stage(0, 0);
  __syncthreads();

  #pragma unroll
  for (int c = 0; c < NCH; ++c) {
    if (c + 1 < NCH) stage((c + 1) & 1, c + 1);
    const bf16x8* Ab = ldsA[c & 1];
    #pragma unroll
    for (int t = 0; t < 2; ++t)
      #pragma unroll
      for (int mf = 0; mf < 4; ++mf) {
        bf16x8 afr = Ab[(t * 4 + kq) * 64 + mf * 16 + lr];
        #pragma unroll
        for (int nf = 0; nf < 2; ++nf)
          acc[mf][nf] = __builtin_amdgcn_mfma_f32_16x16x32_bf16(
              afr, bw[c][t][nf], acc[mf][nf], 0, 0, 0);
      }
    __syncthreads();
  }

  #pragma unroll
  for (int nf = 0; nf < 2; ++nf) {
    int n = n0 + nf * 16 + lr;
    #pragma unroll
    for (int mf = 0; mf < 4; ++mf)
      #pragma unroll
      for (int i = 0; i < 4; ++i) {
        int m = m0 + mf * 16 + kq * 4 + i;
        float v = acc[mf][nf][i];
        if (EPI == 0) {
          if (n < 256) Cb0[(size_t)m * 256 + n] = f2bf(v);
          else         Cb1[(size_t)m * 256 + (n - 256)] = f2bf(v);
        } else {
          if (n < 40) C0[(size_t)m * 40 + n] = v;
        }
      }
  }
}

// ---------------- out_proj GEMM + LayerNorm + NCHW transpose, fused ---------
// Block: 64 tokens x N=128 (full row) -> LN in LDS -> NCHW write.
__global__ __launch_bounds__(256) void outproj_ln(
    const unsigned short* __restrict__ A,   // [T][256] bf16 (y)
    const unsigned short* __restrict__ Wn,  // [128][256] bf16
    const float* __restrict__ lg, const float* __restrict__ lb,
    float* __restrict__ out)                // [8][128][64][64]
{
  constexpr int KDIM = 256;
  constexpr int NCH = KDIM / 64;
  __shared__ bf16x8 ldsA[2][512];
  __shared__ float buf[64][129];

  const int lane = threadIdx.x & 63;
  const int wid  = threadIdx.x >> 6;
  const int m0 = blockIdx.x * 64;
  const int n0 = wid * 32;
  const int lr = lane & 15, kq = lane >> 4, lk = kq * 8;

  bf16x8 bw[NCH][2][2];
  #pragma unroll
  for (int c = 0; c < NCH; ++c)
    #pragma unroll
    for (int t = 0; t < 2; ++t)
      #pragma unroll
      for (int nf = 0; nf < 2; ++nf)
        bw[c][t][nf] = *reinterpret_cast<const bf16x8*>(
            Wn + (size_t)(n0 + nf * 16 + lr) * KDIM + c * 64 + t * 32 + lk);

  auto stage = [&](int buf2, int c) {
    const unsigned short* g = A + (size_t)(m0 + lane) * KDIM + c * 64 + wid * 16;
    gll16(g,     &ldsA[buf2][(wid * 2) * 64]);
    gll16(g + 8, &ldsA[buf2][(wid * 2 + 1) * 64]);
  };

  f32x4 acc[4][2];
  #pragma unroll
  for (int i = 0; i < 4; ++i)
    #pragma unroll
    for (int j = 0; j < 2; ++j) acc[i][j] = f32x4{0.f, 0.f, 0.f, 0.f};

  stage(0, 0);
  __syncthreads();

  #pragma unroll
  for (int c = 0; c < NCH; ++c) {
    if (c + 1 < NCH) stage((c + 1) & 1, c + 1);
    const bf16x8* Ab = ldsA[c & 1];
    #pragma unroll
    for (int t = 0; t < 2; ++t)
      #pragma unroll
      for (int mf = 0; mf < 4; ++mf) {
        bf16x8 afr = Ab[(t * 4 + kq) * 64 + mf * 16 + lr];
        #pragma unroll
        for (int nf = 0; nf < 2; ++nf)
          acc[mf][nf] = __builtin_amdgcn_mfma_f32_16x16x32_bf16(
              afr, bw[c][t][nf], acc[mf][nf], 0, 0, 0);
      }
    __syncthreads();
  }

  // scatter GEMM result to LDS [token][channel]
  #pragma unroll
  for (int nf = 0; nf < 2; ++nf) {
    int n = n0 + nf * 16 + lr;
    #pragma unroll
    for (int mf = 0; mf < 4; ++mf)
      #pragma unroll
      for (int i = 0; i < 4; ++i)
        buf[mf * 16 + kq * 4 + i][n] = acc[mf][nf][i];
  }
  __syncthreads();

  // LayerNorm per token (4 threads x 32 channels each)
  const int tid = threadIdx.x;
  const int tt = tid >> 2, q = tid & 3;
  float s = 0.f, sq = 0.f;
  #pragma unroll
  for (int i = 0; i < 32; ++i) {
    float v = buf[tt][q * 32 + i];
    s += v; sq += v * v;
  }
  s  += __shfl_xor(s, 1);  s  += __shfl_xor(s, 2);
  sq += __shfl_xor(sq, 1); sq += __shfl_xor(sq, 2);
  float mu = s * (1.f / 128.f);
  float var = sq * (1.f / 128.f) - mu * mu;
  float rstd = rsqrtf(fmaxf(var, 0.f) + 1e-5f);
  #pragma unroll
  for (int i = 0; i < 32; ++i) {
    int c = q * 32 + i;
    buf[tt][c] = (buf[tt][c] - mu) * rstd * lg[c] + lb[c];
  }
  __syncthreads();

  // NCHW write (coalesced over 64 consecutive l)
  const int bb = m0 >> 12, l0 = m0 & 4095;
  for (int idx = tid; idx < 64 * 128; idx += 256) {
    int c = idx >> 6, t2 = idx & 63;
    out[((size_t)bb * 128 + c) * 4096 + l0 + t2] = buf[t2][c];
  }
}

// ---------------- depthwise causal conv1d (DCONV=4) + silu, bf16 ------------
__global__ __launch_bounds__(256) void conv1d_silu(
    const unsigned short* __restrict__ xm,   // (T,256) bf16
    const float* __restrict__ w,             // (256,4)
    const float* __restrict__ bias,          // (256)
    unsigned short* __restrict__ out)        // (T,256) bf16
{
  __shared__ float ws4[4][256];
  __shared__ float bsh[256];
  for (int i = threadIdx.x; i < 1024; i += 256)
    ws4[i >> 8][i & 255] = w[(i & 255) * 4 + (i >> 8)];
  bsh[threadIdx.x] = bias[threadIdx.x];
  __syncthreads();
  const int total = 32768 * 32;   // 8 channels per thread
  for (int idx = blockIdx.x * 256 + threadIdx.x; idx < total;
       idx += gridDim.x * 256) {
    int d8 = idx & 31, t = idx >> 5, l = t & 4095;
    int d = d8 * 8;
    float acc[8];
    #pragma unroll
    for (int k = 0; k < 8; ++k) acc[k] = bsh[d + k];
    #pragma unroll
    for (int j = 0; j < 4; ++j) {
      if (l - 3 + j >= 0) {
        uint4 xv = *reinterpret_cast<const uint4*>(
            &xm[(size_t)(t - 3 + j) * 256 + d]);
        const unsigned short* xs = reinterpret_cast<const unsigned short*>(&xv);
        #pragma unroll
        for (int k = 0; k < 8; ++k)
          acc[k] = fmaf(bf2f(xs[k]), ws4[j][d + k], acc[k]);
      }
    }
    unsigned int pk[4];
    #pragma unroll
    for (int k = 0; k < 4; ++k) {
      unsigned short lo = f2bf(siluf(acc[2 * k]));
      unsigned short hi = f2bf(siluf(acc[2 * k + 1]));
      pk[k] = (unsigned int)lo | ((unsigned int)hi << 16);
    }
    *reinterpret_cast<uint4*>(&out[(size_t)t * 256 + d]) =
        *reinterpret_cast<uint4*>(pk);
  }
}

// ---------------- chunked selective scan ------------------------------------
__global__ __launch_bounds__(256) void scan_pass1(
    const unsigned short* __restrict__ xssm, const float* __restrict__ xdb,
    const float* __restrict__ dtw, const float* __restrict__ dtb,
    const float* __restrict__ An2f,
    unsigned short* __restrict__ Qb, float* __restrict__ S)
{
  __shared__ __align__(16) float sh[CL][40];
  const int c = blockIdx.x, b = blockIdx.y;
  const int d = threadIdx.x;
  if (threadIdx.x < CL * 10) {
    const float4* src = reinterpret_cast<const float4*>(
        &xdb[((size_t)b * 4096 + c * CL) * 40]);
    reinterpret_cast<float4*>(&sh[0][0])[threadIdx.x] = src[threadIdx.x];
  }
  float4 w0 = *reinterpret_cast<const float4*>(&dtw[d * 8]);
  float4 w1 = *reinterpret_cast<const float4*>(&dtw[d * 8 + 4]);
  const float bdt = dtb[d];
  float An2[16], h[16];
  {
    const f32x4* a2 = reinterpret_cast<const f32x4*>(&An2f[d * 16]);
    #pragma unroll
    for (int q = 0; q < 4; ++q) {
      f32x4 v = a2[q];
      An2[q * 4 + 0] = v[0]; An2[q * 4 + 1] = v[1];
      An2[q * 4 + 2] = v[2]; An2[q * 4 + 3] = v[3];
    }
  }
  #pragma unroll
  for (int s = 0; s < 16; ++s) h[s] = 0.f;
  __syncthreads();

  float sdt = 0.f;
  const size_t xbase = ((size_t)b * 4096 + (size_t)c * CL) * 256 + d;
  unsigned short xu = xssm[xbase];
  for (int l = 0; l < CL; ++l) {
    unsigned short xun = (l + 1 < CL) ? xssm[xbase + (size_t)(l + 1) * 256]
                                      : (unsigned short)0;
    const float4* row = reinterpret_cast<const float4*>(sh[l]);
    float4 r0 = row[0], r1 = row[1];
    float acc = bdt;
    acc = fmaf(r0.x, w0.x, acc); acc = fmaf(r0.y, w0.y, acc);
    acc = fmaf(r0.z, w0.z, acc); acc = fmaf(r0.w, w0.w, acc);
    acc = fmaf(r1.x, w1.x, acc); acc = fmaf(r1.y, w1.y, acc);
    acc = fmaf(r1.z, w1.z, acc); acc = fmaf(r1.w, w1.w, acc);
    float dt = (acc > 20.f) ? acc : __logf(1.f + __expf(acc));
    sdt += dt;
    float dtx = dt * bf2f(xu);
    #pragma unroll
    for (int q = 0; q < 4; ++q) {
      float4 Bq = row[2 + q];
      float bb4[4] = {Bq.x, Bq.y, Bq.z, Bq.w};
      #pragma unroll
      for (int j = 0; j < 4; ++j) {
        int s = q * 4 + j;
        float dA = __builtin_amdgcn_exp2f(dt * An2[s]);
        h[s] = fmaf(dA, h[s], dtx * bb4[j]);
      }
    }
    xu = xun;
  }
  unsigned int pk[8];
  #pragma unroll
  for (int k = 0; k < 8; ++k)
    pk[k] = (unsigned int)f2bf(h[2 * k]) | ((unsigned int)f2bf(h[2 * k + 1]) << 16);
  uint4* qp = reinterpret_cast<uint4*>(
      &Qb[(((size_t)b * NC + c) * 256 + d) * 16]);
  qp[0] = *reinterpret_cast<uint4*>(pk);
  qp[1] = *reinterpret_cast<uint4*>(pk + 4);
  S[((size_t)b * NC + c) * 256 + d] = sdt;
}

__global__ __launch_bounds__(256) void scan_combine(
    unsigned short* __restrict__ Qb, const float* __restrict__ S,
    const float* __restrict__ An2f)
{
  int g = blockIdx.x * 256 + threadIdx.x;   // 32768 total
  int b = g >> 12, d = (g >> 4) & 255, s = g & 15;
  float An2 = An2f[d * 16 + s];
  const size_t qbase = (size_t)b * NC * 4096 + d * 16 + s;
  const size_t sbase = (size_t)b * NC * 256 + d;
  float h = 0.f;
  unsigned short qn = Qb[qbase];
  float sn = S[sbase];
  for (int c = 0; c < NC; ++c) {
    float q = bf2f(qn), sd = sn;
    if (c + 1 < NC) {
      qn = Qb[qbase + (size_t)(c + 1) * 4096];
      sn = S[sbase + (size_t)(c + 1) * 256];
    }
    Qb[qbase + (size_t)c * 4096] = f2bf(h);
    h = fmaf(__builtin_amdgcn_exp2f(An2 * sd), h, q);
  }
}

__global__ __launch_bounds__(256) void scan_pass2(
    const unsigned short* __restrict__ xssm, const float* __restrict__ xdb,
    const unsigned short* __restrict__ zb,
    const float* __restrict__ dtw, const float* __restrict__ dtb,
    const float* __restrict__ An2f, const float* __restrict__ Dp,
    const unsigned short* __restrict__ Hstart, unsigned short* __restrict__ ybf)
{
  __shared__ __align__(16) float sh[CL][40];
  const int c = blockIdx.x, b = blockIdx.y;
  const int d = threadIdx.x;
  if (threadIdx.x < CL * 10) {
    const float4* src = reinterpret_cast<const float4*>(
        &xdb[((size_t)b * 4096 + c * CL) * 40]);
    reinterpret_cast<float4*>(&sh[0][0])[threadIdx.x] = src[threadIdx.x];
  }
  float4 w0 = *reinterpret_cast<const float4*>(&dtw[d * 8]);
  float4 w1 = *reinterpret_cast<const float4*>(&dtw[d * 8 + 4]);
  const float bdt = dtb[d];
  const float Dd = Dp[d];
  float An2[16], h[16];
  {
    const f32x4* a2 = reinterpret_cast<const f32x4*>(&An2f[d * 16]);
    #pragma unroll
    for (int q = 0; q < 4; ++q) {
      f32x4 v = a2[q];
      An2[q * 4 + 0] = v[0]; An2[q * 4 + 1] = v[1];
      An2[q * 4 + 2] = v[2]; An2[q * 4 + 3] = v[3];
    }
  }
  {
    const uint4* hp = reinterpret_cast<const uint4*>(
        &Hstart[(((size_t)b * NC + c) * 256 + d) * 16]);
    uint4 h0 = hp[0], h1 = hp[1];
    const unsigned short* hs = reinterpret_cast<const unsigned short*>(&h0);
    #pragma unroll
    for (int s = 0; s < 8; ++s) h[s] = bf2f(hs[s]);
    const unsigned short* hs2 = reinterpret_cast<const unsigned short*>(&h1);
    #pragma unroll
    for (int s = 0; s < 8; ++s) h[8 + s] = bf2f(hs2[s]);
  }
  __syncthreads();

  const size_t xbase = ((size_t)b * 4096 + (size_t)c * CL) * 256 + d;
  unsigned short xu = xssm[xbase], zu = zb[xbase];
  for (int l = 0; l < CL; ++l) {
    unsigned short xun = 0, zun = 0;
    if (l + 1 < CL) {
      xun = xssm[xbase + (size_t)(l + 1) * 256];
      zun = zb[xbase + (size_t)(l + 1) * 256];
    }
    const float4* row = reinterpret_cast<const float4*>(sh[l]);
    float4 r0 = row[0], r1 = row[1];
    float acc = bdt;
    acc = fmaf(r0.x, w0.x, acc); acc = fmaf(r0.y, w0.y, acc);
    acc = fmaf(r0.z, w0.z, acc); acc = fmaf(r0.w, w0.w, acc);
    acc = fmaf(r1.x, w1.x, acc); acc = fmaf(r1.y, w1.y, acc);
    acc = fmaf(r1.z, w1.z, acc); acc = fmaf(r1.w, w1.w, acc);
    float dt = (acc > 20.f) ? acc : __logf(1.f + __expf(acc));
    float xv = bf2f(xu);
    float dtx = dt * xv;
    float yq[4] = {0.f, 0.f, 0.f, 0.f};
    #pragma unroll
    for (int q = 0; q < 4; ++q) {
      float4 Bq = row[2 + q], Cq = row[6 + q];
      float bb4[4] = {Bq.x, Bq.y, Bq.z, Bq.w};
      float cc4[4] = {Cq.x, Cq.y, Cq.z, Cq.w};
      #pragma unroll
      for (int j = 0; j < 4; ++j) {
        int s = q * 4 + j;
        float dA = __builtin_amdgcn_exp2f(dt * An2[s]);
        h[s] = fmaf(dA, h[s], dtx * bb4[j]);
        yq[q] = fmaf(h[s], cc4[j], yq[q]);
      }
    }
    float y = (yq[0] + yq[1]) + (yq[2] + yq[3]);
    y = (y + Dd * xv) * siluf(bf2f(zu));
    ybf[xbase + (size_t)l * 256] = f2bf(y);
    xu = xun; zu = zun;
  }
}

// ---------------------------------------------------------------------------
extern "C" void kernel_launch(void* const* d_in, const int* in_sizes, int n_in,
                              void* d_out, int out_size, void* d_ws, size_t ws_size,
                              hipStream_t stream) {
  const float* x        = (const float*)d_in[0];
  const float* conv1_w  = (const float*)d_in[1];
  const float* conv1_b  = (const float*)d_in[2];
  const float* bn1_g    = (const float*)d_in[3];
  const float* bn1_b    = (const float*)d_in[4];
  const float* bn1_m    = (const float*)d_in[5];
  const float* bn1_v    = (const float*)d_in[6];
  const float* conv2_w  = (const float*)d_in[7];
  const float* conv2_b  = (const float*)d_in[8];
  const float* bn2_g    = (const float*)d_in[9];
  const float* bn2_b    = (const float*)d_in[10];
  const float* bn2_m    = (const float*)d_in[11];
  const float* bn2_v    = (const float*)d_in[12];
  const float* in_proj_w  = (const float*)d_in[13];  // (512,128)
  const float* conv1d_w   = (const float*)d_in[14];  // (256,1,4)
  const float* conv1d_b   = (const float*)d_in[15];
  const float* x_proj_w   = (const float*)d_in[16];  // (40,256)
  const float* dt_proj_w  = (const float*)d_in[17];  // (256,8)
  const float* dt_proj_b  = (const float*)d_in[18];
  const float* A_log      = (const float*)d_in[19];  // (256,16)
  const float* Dp         = (const float*)d_in[20];  // (256)
  const float* out_proj_w = (const float*)d_in[21];  // (128,256)
  const float* ln_g       = (const float*)d_in[22];
  const float* ln_b       = (const float*)d_in[23];
  float* out = (float*)d_out;

  float* ws_f = (float*)d_ws;
  // workspace (float units), lifetime-reuse; peak ~101.4 MB
  unsigned short* xbp  = (unsigned short*)ws_f;          // [8][66][66][64] bf16 (pre)
  unsigned short* xmb  = (unsigned short*)ws_f;          // T*256 bf16 (in_proj->conv1d)
  unsigned short* ybf  = (unsigned short*)ws_f;          // T*256 bf16 (pass2->out_proj)
  float*          xdb  = ws_f + 4194304;                 // T*40 f32
  float*          Sbuf = ws_f + 5505024;                 // B*NC*256 f32 (524288)
  unsigned short* zbu  = (unsigned short*)(ws_f + 8388608);   // T*256 bf16
  unsigned short* xsu  = (unsigned short*)(ws_f + 12582912);  // T*256 bf16
  unsigned short* h1p  = (unsigned short*)(ws_f + 16777216);  // [8][66][66][128]
  unsigned short* seqb = (unsigned short*)(ws_f + 19007488);  // [T][128]
  unsigned short* Qb   = (unsigned short*)(ws_f + 16777216);  // B*NC*256*16 bf16
  unsigned short* wb1  = (unsigned short*)(ws_f + 25165824);  // 73728 u
  unsigned short* wb2  = (unsigned short*)(ws_f + 25202688);  // 147456 u
  unsigned short* win  = (unsigned short*)(ws_f + 25276416);  // 65536 u
  unsigned short* wout = (unsigned short*)(ws_f + 25309184);  // 32768 u
  unsigned short* xpwb = (unsigned short*)(ws_f + 25325568);  // 32768 u
  float*          An2f = ws_f + 25341952;                     // 4096 f

  // prologue: nchw transpose + all weight prep + border-only zero fill
  prologue<<<1920, 256, 0, stream>>>(
      x, xbp, conv1_w, conv2_w, in_proj_w, out_proj_w, x_proj_w, A_log,
      wb1, wb2, win, wout, xpwb, An2f, h1p);

  // convs (LDS-staged MFMA implicit GEMM on padded NHWC)
  conv_mfma<64, 1><<<dim3(64, 8), 256, 0, stream>>>(
      xbp, wb1, conv1_b, bn1_g, bn1_b, bn1_m, bn1_v, h1p);
  conv_mfma<128, 0><<<dim3(64, 8), 256, 0, stream>>>(
      h1p, wb2, conv2_b, bn2_g, bn2_b, bn2_m, bn2_v, seqb);

  // in_proj (one GEMM, N=512 -> xm bf16 | z bf16)
  gemm_mfma<128, 0><<<dim3(512, 4), 256, 0, stream>>>(
      seqb, win, nullptr, xmb, zbu);

  // conv1d + silu -> xssm bf16
  conv1d_silu<<<2048, 256, 0, stream>>>(xmb, conv1d_w, conv1d_b, xsu);

  // x_proj (MFMA, padded N=128, mask n<40) -> xdb fp32
  gemm_mfma<256, 2><<<dim3(512, 1), 256, 0, stream>>>(
      xsu, xpwb, xdb, nullptr, nullptr);

  scan_pass1<<<dim3(NC, 8), 256, 0, stream>>>(
      xsu, xdb, dt_proj_w, dt_proj_b, An2f, Qb, Sbuf);
  scan_combine<<<128, 256, 0, stream>>>(Qb, Sbuf, An2f);
  scan_pass2<<<dim3(NC, 8), 256, 0, stream>>>(
      xsu, xdb, zbu, dt_proj_w, dt_proj_b, An2f, Dp, Qb, ybf);

  // out_proj + LayerNorm + NCHW transpose (fused)
  outproj_ln<<<512, 256, 0, stream>>>(ybf, wout, ln_g, ln_b, out);
}